// Round 10
// baseline (1485.671 us; speedup 1.0000x reference)
//
#include <hip/hip_runtime.h>
#include <hip/hip_bf16.h>
#include <cstdint>
#include <cstddef>

#define B_  4
#define S_  512
#define T_  1023
#define D_  1024
#define H_  16
#define DH_ 64
#define F_  4096
#define L_  4

typedef float f32x4 __attribute__((ext_vector_type(4)));
typedef __bf16 bf16x8 __attribute__((ext_vector_type(8)));

__device__ inline unsigned pack_bf2(float a, float b) {
    union { __hip_bfloat16 h; unsigned short u; } ua, ub;
    ua.h = __float2bfloat16(a); ub.h = __float2bfloat16(b);
    return (unsigned)ua.u | ((unsigned)ub.u << 16);
}

// ---------------------------------------------------------------------------
// bf16 MFMA GEMM, 128x128 tile (wave = 64x64: FLOP/LDS-byte 32 vs 21 for
// 64x32 — round-9 diagnosis: LDS-BW-bound) + 3-buffer counted-vmcnt pipeline
// (round-9 validated) + split-K via blockIdx.z. Partial slices z<2 go to
// Cf + z*M*N, z>=2 to Cf2 + (z-2)*M*N (dual-region: avoids big contiguous
// scratch, round-6 lesson).
// ---------------------------------------------------------------------------
__global__ __launch_bounds__(256) void gemm_bf16(
    const __hip_bfloat16* __restrict__ A, const __hip_bfloat16* __restrict__ Wt,
    const float* __restrict__ bias,
    float* __restrict__ Cf, float* __restrict__ Cf2,
    __hip_bfloat16* __restrict__ Cb,
    int M, int K, int N, int relu, int ksplit)
{
    __shared__ __align__(16) __hip_bfloat16 AsmB[3][128 * 32];   // 24 KB
    __shared__ __align__(16) __hip_bfloat16 BsmB[3][128 * 32];   // 24 KB
    const int tid  = threadIdx.x;
    const int lane = tid & 63;
    const int w    = tid >> 6;
    const int wr   = w >> 1, wc = w & 1;          // wave grid 2x2: 64x64 each
    const int l15  = lane & 15, l4 = lane >> 4;

    // bijective XCD-aware swizzle (m204) on the x-y plane
    const int gx = gridDim.x;
    int bid = blockIdx.y * gx + blockIdx.x;
    {
        const int nwg = gx * gridDim.y;
        const int q = nwg >> 3, r = nwg & 7;
        const int xcd = bid & 7, idx = bid >> 3;
        bid = (xcd < r ? xcd * (q + 1) : r * (q + 1) + (xcd - r) * q) + idx;
    }
    const int row0 = (bid / gx) * 128;
    const int col0 = (bid % gx) * 128;
    const int z = blockIdx.z;
    const int kslice = K / ksplit;
    const int kbase = z * kslice;

    f32x4 acc[4][4] = {};

    auto stage = [&](__hip_bfloat16* As, __hip_bfloat16* Bs, int kt) {
        auto* ldsA = (__attribute__((address_space(3))) char*)As;
        auto* ldsB = (__attribute__((address_space(3))) char*)Bs;
        #pragma unroll
        for (int half = 0; half < 2; ++half) {
            const int ch = half * 256 + tid;            // 16B chunk id
            const int r  = ch >> 2;
            const int c  = (ch & 3) * 8;
            int gr = row0 + r; gr = (gr < M) ? gr : (M - 1);
            const __hip_bfloat16* srcA = A + (size_t)gr * K + kt + c;
            __builtin_amdgcn_global_load_lds(
                (const __attribute__((address_space(1))) unsigned*)srcA,
                (__attribute__((address_space(3))) unsigned*)(ldsA + (size_t)ch * 16),
                16, 0, 0);
            int gc = col0 + r; gc = (gc < N) ? gc : (N - 1);
            const __hip_bfloat16* srcB = Wt + (size_t)gc * K + kt + c;
            __builtin_amdgcn_global_load_lds(
                (const __attribute__((address_space(1))) unsigned*)srcB,
                (__attribute__((address_space(3))) unsigned*)(ldsB + (size_t)ch * 16),
                16, 0, 0);
        }
    };
    auto compute = [&](const __hip_bfloat16* As, const __hip_bfloat16* Bs) {
        const __hip_bfloat16* ab = As + (size_t)(wr * 64 + l15) * 32 + l4 * 8;
        const __hip_bfloat16* bb = Bs + (size_t)(wc * 64 + l15) * 32 + l4 * 8;
        bf16x8 af[4], bf[4];
        #pragma unroll
        for (int mi = 0; mi < 4; ++mi) af[mi] = *(const bf16x8*)(ab + mi * 16 * 32);
        #pragma unroll
        for (int nj = 0; nj < 4; ++nj) bf[nj] = *(const bf16x8*)(bb + nj * 16 * 32);
        #pragma unroll
        for (int mi = 0; mi < 4; ++mi)
            #pragma unroll
            for (int nj = 0; nj < 4; ++nj)
                acc[mi][nj] = __builtin_amdgcn_mfma_f32_16x16x32_bf16(
                    af[mi], bf[nj], acc[mi][nj], 0, 0, 0);
    };

    const int nk = kslice >> 5;
    __hip_bfloat16 *A0 = AsmB[0], *A1 = AsmB[1], *A2 = AsmB[2];
    __hip_bfloat16 *B0 = BsmB[0], *B1 = BsmB[1], *B2 = BsmB[2];
    stage(A0, B0, kbase);                       // 4 loads/thread
    if (nk > 1) stage(A1, B1, kbase + 32);      // +4 -> 8 outstanding
    for (int t = 0; t < nk; ++t) {
        if (t + 1 < nk) {
            asm volatile("s_waitcnt vmcnt(4)" ::: "memory");   // tile t done; t+1 in flight
        } else {
            asm volatile("s_waitcnt vmcnt(0)" ::: "memory");   // last tile
        }
        __builtin_amdgcn_s_barrier();           // raw: no vmcnt drain
        if (t + 2 < nk) stage(A2, B2, kbase + (t + 2) * 32);   // back to 8 in flight
        compute(A0, B0);
        __hip_bfloat16* ta = A0; A0 = A1; A1 = A2; A2 = ta;
        __hip_bfloat16* tb = B0; B0 = B1; B1 = B2; B2 = tb;
    }

    // epilogue: C/D layout col = lane&15, row = (lane>>4)*4 + i  [m89-verified]
    if (ksplit > 1) {
        const size_t MN = (size_t)M * N;
        float* dst = (z < 2) ? (Cf + (size_t)z * MN) : (Cf2 + (size_t)(z - 2) * MN);
        #pragma unroll
        for (int nj = 0; nj < 4; ++nj) {
            const int c = col0 + wc * 64 + nj * 16 + l15;
            if (c >= N) continue;
            #pragma unroll
            for (int mi = 0; mi < 4; ++mi)
                #pragma unroll
                for (int i = 0; i < 4; ++i) {
                    const int r = row0 + wr * 64 + mi * 16 + l4 * 4 + i;
                    if (r < M) dst[(size_t)r * N + c] = acc[mi][nj][i];
                }
        }
    } else {
        #pragma unroll
        for (int nj = 0; nj < 4; ++nj) {
            const int c = col0 + wc * 64 + nj * 16 + l15;
            if (c >= N) continue;
            const float bv = bias[c];
            #pragma unroll
            for (int mi = 0; mi < 4; ++mi)
                #pragma unroll
                for (int i = 0; i < 4; ++i) {
                    const int r = row0 + wr * 64 + mi * 16 + l4 * 4 + i;
                    if (r >= M) continue;
                    float v = acc[mi][nj][i] + bv;
                    if (relu) v = fmaxf(v, 0.f);
                    if (Cf) Cf[(size_t)r * N + c] = v;
                    if (Cb) Cb[(size_t)r * N + c] = __float2bfloat16(v);
                }
        }
    }
}

// ---------------------------------------------------------------------------
// Split-K reduction (dual-region): slices s<2 from part, s>=2 from part2.
// out = op(sum_s slice[s] + bias). Requires N power of 2.
// ---------------------------------------------------------------------------
__global__ __launch_bounds__(256) void reduce_split(
    const float* __restrict__ part, const float* __restrict__ part2,
    int SK, size_t pstride,
    const float* __restrict__ bias, int N, int total4, int relu,
    float* __restrict__ outf, __hip_bfloat16* __restrict__ outb)
{
    const int idx4 = blockIdx.x * 256 + threadIdx.x;
    if (idx4 >= total4) return;
    const size_t base = (size_t)idx4 * 4;
    const int c = (int)(base & (size_t)(N - 1));
    float4 v = *(const float4*)(part + base);
    for (int s = 1; s < SK; ++s) {
        const float* src = (s < 2) ? (part + (size_t)s * pstride)
                                   : (part2 + (size_t)(s - 2) * pstride);
        const float4 p = *(const float4*)(src + base);
        v.x += p.x; v.y += p.y; v.z += p.z; v.w += p.w;
    }
    const float4 bv = *(const float4*)(bias + c);
    v.x += bv.x; v.y += bv.y; v.z += bv.z; v.w += bv.w;
    if (relu) {
        v.x = fmaxf(v.x, 0.f); v.y = fmaxf(v.y, 0.f);
        v.z = fmaxf(v.z, 0.f); v.w = fmaxf(v.w, 0.f);
    }
    if (outf) *(float4*)(outf + base) = v;
    if (outb) {
        __hip_bfloat16* o = outb + base;
        o[0] = __float2bfloat16(v.x); o[1] = __float2bfloat16(v.y);
        o[2] = __float2bfloat16(v.z); o[3] = __float2bfloat16(v.w);
    }
}

// ---------------------------------------------------------------------------
// Weight transpose+convert (unchanged).
// ---------------------------------------------------------------------------
__global__ __launch_bounds__(256) void transpose_w(
    const float* __restrict__ W, __hip_bfloat16* __restrict__ Wt,
    int K, int N, int Kpad)
{
    __shared__ float t[32][33];
    W  += (size_t)blockIdx.z * K * N;
    Wt += (size_t)blockIdx.z * N * Kpad;
    const int n0 = blockIdx.x * 32, k0 = blockIdx.y * 32;
    const int tx = threadIdx.x & 31, ty = threadIdx.x >> 5;
    #pragma unroll
    for (int i = 0; i < 4; ++i) {
        int r = ty + i * 8;
        int k = k0 + r, n = n0 + tx;
        t[r][tx] = (k < K && n < N) ? W[(size_t)k * N + n] : 0.f;
    }
    __syncthreads();
    #pragma unroll
    for (int i = 0; i < 4; ++i) {
        int r = ty + i * 8;
        int n = n0 + r, k = k0 + tx;
        if (n < N && k < Kpad) Wt[(size_t)n * Kpad + k] = __float2bfloat16(t[tx][r]);
    }
}

__global__ __launch_bounds__(256) void convert_pad(
    const float* __restrict__ in, __hip_bfloat16* __restrict__ out,
    int M, int Kin, int Kout)
{
    int idx = blockIdx.x * 256 + threadIdx.x;
    if (idx >= M * Kout) return;
    int r = idx / Kout, c = idx - r * Kout;
    out[idx] = __float2bfloat16(c < Kin ? in[(size_t)r * Kin + c] : 0.f);
}

// ---------------------------------------------------------------------------
// V transpose (unchanged).
// ---------------------------------------------------------------------------
__global__ __launch_bounds__(256) void v_transpose(
    const __hip_bfloat16* __restrict__ qkvb, __hip_bfloat16* __restrict__ vt)
{
    __shared__ __hip_bfloat16 tile[32][33];
    const int b  = blockIdx.z;
    const int c0 = blockIdx.x * 32;
    const int t0 = blockIdx.y * 32;
    const int tx = threadIdx.x & 31, ty = threadIdx.x >> 5;
    const __hip_bfloat16 z = __float2bfloat16(0.f);
    #pragma unroll
    for (int i = 0; i < 4; ++i) {
        const int tl = ty + i * 8;
        const int t = t0 + tl;
        tile[tl][tx] = (t < T_) ? qkvb[(size_t)(b * T_ + t) * 3072 + 2048 + c0 + tx] : z;
    }
    __syncthreads();
    #pragma unroll
    for (int i = 0; i < 4; ++i) {
        const int cl = ty + i * 8;
        const int t = t0 + tx;
        vt[((size_t)(b * 1024 + c0 + cl)) * 1024 + t] = (t < T_) ? tile[tx][cl] : z;
    }
}

// ---------------------------------------------------------------------------
// MFMA flash attention (unchanged from round 3 — proven).
// ---------------------------------------------------------------------------
__global__ __launch_bounds__(256) void attn_mfma(
    const __hip_bfloat16* __restrict__ qkvb,
    const __hip_bfloat16* __restrict__ vt,
    __hip_bfloat16* __restrict__ out)
{
    __shared__ __align__(16) __hip_bfloat16 Qs[2][128][32];
    __shared__ __align__(16) __hip_bfloat16 Ks[2][64][32];
    __shared__ __align__(16) __hip_bfloat16 Vs[2][64][32];
    __shared__ __align__(16) __hip_bfloat16 Ps[4][2][32][32];
    __shared__ float Lw[4][2][16];

    const int bh = blockIdx.x;
    const int b = bh >> 4, h = bh & 15;
    const int q0 = blockIdx.y * 128;
    const int tid = threadIdx.x;
    const int w = tid >> 6, lane = tid & 63;
    const int l15 = lane & 15, l4 = lane >> 4;
    const size_t ldq = 3 * D_;

    {
        #pragma unroll
        for (int c = 0; c < 2; ++c)
            #pragma unroll
            for (int it = 0; it < 2; ++it) {
                const int ch = it * 256 + tid;
                const int r = ch >> 2, cp = ch & 3;
                int qr = q0 + r; qr = (qr < T_) ? qr : (T_ - 1);
                const __hip_bfloat16* src = qkvb + (size_t)(b * T_ + qr) * ldq + h * 64 + c * 32 + cp * 8;
                __builtin_amdgcn_global_load_lds(
                    (const __attribute__((address_space(1))) unsigned*)src,
                    (__attribute__((address_space(3))) unsigned*)((__attribute__((address_space(3))) char*)&Qs[c][0][0] + ch * 16),
                    16, 0, 0);
            }
    }
    __syncthreads();
    bf16x8 qreg[2][2];
    #pragma unroll
    for (int qf = 0; qf < 2; ++qf)
        #pragma unroll
        for (int c = 0; c < 2; ++c)
            qreg[qf][c] = *(const bf16x8*)&Qs[c][w * 32 + qf * 16 + l15][l4 * 8];

    f32x4 of[2][4] = {};
    float lp[2] = {0.f, 0.f};
    const int qmaxw = q0 + w * 32 + 31;
    const int kend = (q0 + 128 < T_) ? (q0 + 128) : T_;

    for (int k0 = 0; k0 < kend; k0 += 64) {
        __syncthreads();
        {
            const int r = tid >> 2, cp = tid & 3;
            #pragma unroll
            for (int c = 0; c < 2; ++c) {
                int kr = k0 + r; kr = (kr < T_) ? kr : (T_ - 1);
                const __hip_bfloat16* srcK = qkvb + (size_t)(b * T_ + kr) * ldq + D_ + h * 64 + c * 32 + cp * 8;
                __builtin_amdgcn_global_load_lds(
                    (const __attribute__((address_space(1))) unsigned*)srcK,
                    (__attribute__((address_space(3))) unsigned*)((__attribute__((address_space(3))) char*)&Ks[c][0][0] + tid * 16),
                    16, 0, 0);
                const __hip_bfloat16* srcV = vt + ((size_t)(b * 1024 + h * 64 + r)) * 1024 + k0 + c * 32 + cp * 8;
                __builtin_amdgcn_global_load_lds(
                    (const __attribute__((address_space(1))) unsigned*)srcV,
                    (__attribute__((address_space(3))) unsigned*)((__attribute__((address_space(3))) char*)&Vs[c][0][0] + tid * 16),
                    16, 0, 0);
            }
        }
        __syncthreads();

        if (k0 <= qmaxw) {
            f32x4 sf[4][2] = {};
            #pragma unroll
            for (int c = 0; c < 2; ++c) {
                bf16x8 kf[4];
                #pragma unroll
                for (int kfr = 0; kfr < 4; ++kfr)
                    kf[kfr] = *(const bf16x8*)&Ks[c][kfr * 16 + l15][l4 * 8];
                #pragma unroll
                for (int kfr = 0; kfr < 4; ++kfr)
                    #pragma unroll
                    for (int qf = 0; qf < 2; ++qf)
                        sf[kfr][qf] = __builtin_amdgcn_mfma_f32_16x16x32_bf16(
                            kf[kfr], qreg[qf][c], sf[kfr][qf], 0, 0, 0);
            }
            const bool needmask = (k0 + 63) > (q0 + w * 32);
            #pragma unroll
            for (int kfr = 0; kfr < 4; ++kfr) {
                #pragma unroll
                for (int qf = 0; qf < 2; ++qf) {
                    const int qg = q0 + w * 32 + qf * 16 + l15;
                    float p[4];
                    #pragma unroll
                    for (int i = 0; i < 4; ++i) {
                        const int kg = k0 + kfr * 16 + l4 * 4 + i;
                        float pv = __expf(sf[kfr][qf][i] * 0.125f);
                        if (needmask && kg > qg) pv = 0.f;
                        p[i] = pv;
                        lp[qf] += pv;
                    }
                    unsigned* dst = (unsigned*)&Ps[w][kfr >> 1][qf * 16 + l15][(kfr & 1) * 16 + l4 * 4];
                    dst[0] = pack_bf2(p[0], p[1]);
                    dst[1] = pack_bf2(p[2], p[3]);
                }
            }
            #pragma unroll
            for (int kc = 0; kc < 2; ++kc) {
                bf16x8 pa[2], vb[4];
                #pragma unroll
                for (int qf = 0; qf < 2; ++qf)
                    pa[qf] = *(const bf16x8*)&Ps[w][kc][qf * 16 + l15][l4 * 8];
                #pragma unroll
                for (int df = 0; df < 4; ++df)
                    vb[df] = *(const bf16x8*)&Vs[kc][df * 16 + l15][l4 * 8];
                #pragma unroll
                for (int qf = 0; qf < 2; ++qf)
                    #pragma unroll
                    for (int df = 0; df < 4; ++df)
                        of[qf][df] = __builtin_amdgcn_mfma_f32_16x16x32_bf16(
                            pa[qf], vb[df], of[qf][df], 0, 0, 0);
            }
        }
    }

    #pragma unroll
    for (int qf = 0; qf < 2; ++qf) {
        float v = lp[qf];
        v += __shfl_xor(v, 16);
        v += __shfl_xor(v, 32);
        if (l4 == 0) Lw[w][qf][l15] = v;
    }
    __syncthreads();
    #pragma unroll
    for (int qf = 0; qf < 2; ++qf) {
        float inv[4];
        #pragma unroll
        for (int i = 0; i < 4; ++i) inv[i] = 1.f / Lw[w][qf][l4 * 4 + i];
        #pragma unroll
        for (int df = 0; df < 4; ++df) {
            #pragma unroll
            for (int i = 0; i < 4; ++i) {
                const int qg = q0 + w * 32 + qf * 16 + l4 * 4 + i;
                if (qg < T_)
                    out[(size_t)(b * T_ + qg) * D_ + h * 64 + df * 16 + l15] =
                        __float2bfloat16(of[qf][df][i] * inv[i]);
            }
        }
    }
}

// ---------------------------------------------------------------------------
// LN helpers. Residual: SK slices (s<2 from p, s>=2 from p2) + optional bias.
// ---------------------------------------------------------------------------
__device__ inline void block_ln_stats(float4 v, float& mu, float& inv,
                                      float* ws, float* ws2, float* mu_s, float* inv_s)
{
    const int tid = threadIdx.x;
    float s  = v.x + v.y + v.z + v.w;
    float s2 = v.x * v.x + v.y * v.y + v.z * v.z + v.w * v.w;
    #pragma unroll
    for (int off = 32; off; off >>= 1) {
        s  += __shfl_down(s, off);
        s2 += __shfl_down(s2, off);
    }
    const int wid = tid >> 6;
    if ((tid & 63) == 0) { ws[wid] = s; ws2[wid] = s2; }
    __syncthreads();
    if (tid == 0) {
        float S  = ws[0] + ws[1] + ws[2] + ws[3];
        float S2 = ws2[0] + ws2[1] + ws2[2] + ws2[3];
        float m = S * (1.f / (float)D_);
        float var = S2 * (1.f / (float)D_) - m * m;
        *mu_s = m;
        *inv_s = rsqrtf(var + 1e-5f);
    }
    __syncthreads();
    mu = *mu_s; inv = *inv_s;
}

__global__ __launch_bounds__(256) void add_ln_kernel(
    float* __restrict__ x, const float* __restrict__ p, const float* __restrict__ p2,
    int SK, size_t pstride, const float* __restrict__ pbias,
    const float* __restrict__ g, const float* __restrict__ beta,
    __hip_bfloat16* __restrict__ xb)
{
    const int row = blockIdx.x;
    const int tid = threadIdx.x;
    __shared__ float ws[4], ws2[4], mu_s, inv_s;
    float4* xr = reinterpret_cast<float4*>(x + (size_t)row * D_);
    float4 v = xr[tid];
    if (p) {
        for (int s = 0; s < SK; ++s) {
            const float* src = (s < 2) ? (p + (size_t)s * pstride)
                                       : (p2 + (size_t)(s - 2) * pstride);
            const float4 wv = reinterpret_cast<const float4*>(src + (size_t)row * D_)[tid];
            v.x += wv.x; v.y += wv.y; v.z += wv.z; v.w += wv.w;
        }
        if (pbias) {
            const float4 bv = reinterpret_cast<const float4*>(pbias)[tid];
            v.x += bv.x; v.y += bv.y; v.z += bv.z; v.w += bv.w;
        }
    }
    float mu, inv;
    block_ln_stats(v, mu, inv, ws, ws2, &mu_s, &inv_s);
    const float4 gg = reinterpret_cast<const float4*>(g)[tid];
    const float4 bb = reinterpret_cast<const float4*>(beta)[tid];
    float4 o;
    o.x = (v.x - mu) * inv * gg.x + bb.x;
    o.y = (v.y - mu) * inv * gg.y + bb.y;
    o.z = (v.z - mu) * inv * gg.z + bb.z;
    o.w = (v.w - mu) * inv * gg.w + bb.w;
    xr[tid] = o;
    if (xb) {
        __hip_bfloat16* xo = xb + (size_t)row * D_ + tid * 4;
        xo[0] = __float2bfloat16(o.x);
        xo[1] = __float2bfloat16(o.y);
        xo[2] = __float2bfloat16(o.z);
        xo[3] = __float2bfloat16(o.w);
    }
}

__global__ __launch_bounds__(256) void add_ln2_kernel(
    float* __restrict__ x, const float* __restrict__ p, int SK, size_t pstride,
    const float* __restrict__ pbias, const float* __restrict__ cav,
    const float* __restrict__ g1, const float* __restrict__ b1,
    const float* __restrict__ g2, const float* __restrict__ b2,
    __hip_bfloat16* __restrict__ xb)
{
    const int row = blockIdx.x;
    const int tid = threadIdx.x;
    __shared__ float ws[4], ws2[4], mu_s, inv_s;
    float4* xr = reinterpret_cast<float4*>(x + (size_t)row * D_);
    float4 v = xr[tid];
    for (int s = 0; s < SK; ++s) {
        const float4 wv = reinterpret_cast<const float4*>(
            p + (size_t)s * pstride + (size_t)row * D_)[tid];
        v.x += wv.x; v.y += wv.y; v.z += wv.z; v.w += wv.w;
    }
    if (pbias) {
        const float4 bv = reinterpret_cast<const float4*>(pbias)[tid];
        v.x += bv.x; v.y += bv.y; v.z += bv.z; v.w += bv.w;
    }
    float mu, inv;
    block_ln_stats(v, mu, inv, ws, ws2, &mu_s, &inv_s);
    const float4 g1v = reinterpret_cast<const float4*>(g1)[tid];
    const float4 b1v = reinterpret_cast<const float4*>(b1)[tid];
    const float4 cv  = reinterpret_cast<const float4*>(cav)[tid];
    float4 u;
    u.x = (v.x - mu) * inv * g1v.x + b1v.x + cv.x;
    u.y = (v.y - mu) * inv * g1v.y + b1v.y + cv.y;
    u.z = (v.z - mu) * inv * g1v.z + b1v.z + cv.z;
    u.w = (v.w - mu) * inv * g1v.w + b1v.w + cv.w;
    __syncthreads();
    float mu2, inv2;
    block_ln_stats(u, mu2, inv2, ws, ws2, &mu_s, &inv_s);
    const float4 g2v = reinterpret_cast<const float4*>(g2)[tid];
    const float4 b2v = reinterpret_cast<const float4*>(b2)[tid];
    float4 o;
    o.x = (u.x - mu2) * inv2 * g2v.x + b2v.x;
    o.y = (u.y - mu2) * inv2 * g2v.y + b2v.y;
    o.z = (u.z - mu2) * inv2 * g2v.z + b2v.z;
    o.w = (u.w - mu2) * inv2 * g2v.w + b2v.w;
    xr[tid] = o;
    __hip_bfloat16* xo = xb + (size_t)row * D_ + tid * 4;
    xo[0] = __float2bfloat16(o.x);
    xo[1] = __float2bfloat16(o.y);
    xo[2] = __float2bfloat16(o.z);
    xo[3] = __float2bfloat16(o.w);
}

__global__ __launch_bounds__(256) void interleave_pe_kernel(
    const float* __restrict__ obs_tok, const float* __restrict__ act_tok,
    float* __restrict__ x, __hip_bfloat16* __restrict__ xb)
{
    const int row = blockIdx.x;
    const int b = row / T_;
    const int t = row - b * T_;
    const float* src = (t & 1)
        ? (act_tok + (size_t)(b * (S_ - 1) + (t >> 1)) * D_)
        : (obs_tok + (size_t)(b * S_ + (t >> 1)) * D_);
    float* xr = x + (size_t)row * D_;
    __hip_bfloat16* xo = xb + (size_t)row * D_;
    #pragma unroll
    for (int k = 0; k < 4; ++k) {
        int d = threadIdx.x + k * 256;
        float ang = (float)b * expf(-(float)(d & ~1) * (9.210340371976184f / 1024.0f));
        float pe = (d & 1) ? cosf(ang) : sinf(ang);
        float v = src[d] + pe;
        xr[d] = v;
        xo[d] = __float2bfloat16(v);
    }
}

__global__ __launch_bounds__(256) void ca_part_kernel(
    const float* __restrict__ ca_b_in, const float* __restrict__ ca_w_out,
    float* __restrict__ part)
{
    const int idx = blockIdx.x * 256 + threadIdx.x;
    const int ks = blockIdx.y;
    const int l = idx >> 10, d = idx & 1023;
    const float* bv = ca_b_in + (size_t)l * 3 * D_ + 2 * D_ + ks * 64;
    const float* wp = ca_w_out + (size_t)l * D_ * D_ + (size_t)(ks * 64) * D_ + d;
    float s = 0.f;
    #pragma unroll 8
    for (int k = 0; k < 64; ++k) s = fmaf(bv[k], wp[(size_t)k * D_], s);
    part[(size_t)ks * (L_ * D_) + idx] = s;
}

__global__ __launch_bounds__(256) void ca_reduce_kernel(
    const float* __restrict__ part, const float* __restrict__ ca_b_out,
    float* __restrict__ out)
{
    const int idx = blockIdx.x * 256 + threadIdx.x;
    float s = ca_b_out[idx];
    #pragma unroll
    for (int ks = 0; ks < 16; ++ks) s += part[(size_t)ks * (L_ * D_) + idx];
    out[idx] = s;
}

// ---------------------------------------------------------------------------
extern "C" void kernel_launch(void* const* d_in, const int* in_sizes, int n_in,
                              void* d_out, int out_size, void* d_ws, size_t ws_size,
                              hipStream_t stream)
{
    const float* obs     = (const float*)d_in[0];
    const float* act     = (const float*)d_in[1];
    const float* in_w1   = (const float*)d_in[2];
    const float* in_b1   = (const float*)d_in[3];
    const float* in_w2   = (const float*)d_in[4];
    const float* in_b2   = (const float*)d_in[5];
    const float* in_w3   = (const float*)d_in[6];
    const float* in_b3   = (const float*)d_in[7];
    const float* act_w1  = (const float*)d_in[8];
    const float* act_b1  = (const float*)d_in[9];
    const float* act_w2  = (const float*)d_in[10];
    const float* act_b2  = (const float*)d_in[11];
    const float* act_w3  = (const float*)d_in[12];
    const float* act_b3  = (const float*)d_in[13];
    const float* out_w1  = (const float*)d_in[14];
    const float* out_b1  = (const float*)d_in[15];
    const float* out_w2  = (const float*)d_in[16];
    const float* out_b2  = (const float*)d_in[17];
    const float* out_w3  = (const float*)d_in[18];
    const float* out_b3  = (const float*)d_in[19];
    const float* sa_w_in = (const float*)d_in[20];
    const float* sa_b_in = (const float*)d_in[21];
    const float* sa_w_out= (const float*)d_in[22];
    const float* sa_b_out= (const float*)d_in[23];
    const float* ca_b_in = (const float*)d_in[25];
    const float* ca_w_out= (const float*)d_in[26];
    const float* ca_b_out= (const float*)d_in[27];
    const float* ff_w1   = (const float*)d_in[28];
    const float* ff_b1   = (const float*)d_in[29];
    const float* ff_w2   = (const float*)d_in[30];
    const float* ff_b2   = (const float*)d_in[31];
    const float* ln1_g   = (const float*)d_in[32];
    const float* ln1_b   = (const float*)d_in[33];
    const float* ln2_g   = (const float*)d_in[34];
    const float* ln2_b   = (const float*)d_in[35];
    const float* ln3_g   = (const float*)d_in[36];
    const float* ln3_b   = (const float*)d_in[37];
    const float* lnf_g   = (const float*)d_in[38];
    const float* lnf_b   = (const float*)d_in[39];

    const int MT = B_ * T_;          // 4092
    const int Mo = B_ * S_;          // 2048
    const int Ma = B_ * (S_ - 1);    // 2044

    char* base = (char*)d_ws;
    size_t used = 0;
    auto alloc = [&](size_t bytes) -> char* {
        char* r = base + used;
        used += (bytes + 255) & ~(size_t)255;
        return r;
    };
    typedef __hip_bfloat16 bf;
    bf* wi1  = (bf*)alloc((size_t)1024 * 64 * 2);
    bf* wi2  = (bf*)alloc((size_t)1024 * 1024 * 2);
    bf* wi3  = (bf*)alloc((size_t)1024 * 1024 * 2);
    bf* wa1  = (bf*)alloc((size_t)1024 * 32 * 2);
    bf* wa2  = (bf*)alloc((size_t)1024 * 1024 * 2);
    bf* wa3  = (bf*)alloc((size_t)1024 * 1024 * 2);
    bf* wo1  = (bf*)alloc((size_t)1024 * 1024 * 2);
    bf* wo2  = (bf*)alloc((size_t)1024 * 1024 * 2);
    bf* wo3  = (bf*)alloc((size_t)16 * 1024 * 2);
    bf* wsin = (bf*)alloc((size_t)L_ * 3072 * 1024 * 2);
    bf* wsout= (bf*)alloc((size_t)L_ * 1024 * 1024 * 2);
    bf* wf1  = (bf*)alloc((size_t)L_ * 4096 * 1024 * 2);
    bf* wf2  = (bf*)alloc((size_t)L_ * 1024 * 4096 * 2);
    bf* obs_bf = (bf*)alloc((size_t)Mo * 64 * 2);
    bf* act_bf = (bf*)alloc((size_t)Ma * 32 * 2);
    bf* x_bf   = (bf*)alloc((size_t)MT * D_ * 2);
    bf* attnb  = (bf*)alloc((size_t)MT * D_ * 2);
    bf* h1b    = (bf*)alloc((size_t)MT * D_ * 2);
    bf* h2b    = (bf*)alloc((size_t)MT * D_ * 2);
    char* shared_rg = alloc((size_t)MT * F_ * 2);   // qkvb | ffh | out-MLP partials
    bf* qkvb = (bf*)shared_rg;
    bf* ffh  = (bf*)shared_rg;
    bf* vt   = (bf*)alloc((size_t)B_ * 1024 * 1024 * 2);
    float* x       = (float*)alloc((size_t)MT * D_ * 4);
    // [y, obs_tok, act_tok] = contiguous 33,521,664 B = exactly 2*MT*D_*4:
    // reused as in-loop split-K partial slices 0,1.
    float* y       = (float*)alloc((size_t)MT * D_ * 4);
    float* obs_tok = (float*)alloc((size_t)Mo * D_ * 4);
    float* act_tok = (float*)alloc((size_t)Ma * D_ * 4);
    float* ca      = (float*)alloc((size_t)L_ * D_ * 4);
    float* ca_part = (float*)alloc((size_t)16 * L_ * D_ * 4);
    if (used > ws_size) return;                       // baseline must fit (it did r7-9)
    float* part_loop = y;                 // slices 0,1 (2*MT*D fp32)
    float* part_pre  = (float*)shared_rg; // pre-loop SK<=4 on Mo (41.9MB span)
    float* part_post = (float*)shared_rg; // post-loop, 2*MT*D exact fit
    // optional extra 2 slices for FFN-down SK=4 (guarded; fallback SK=2)
    float* part_extra = (float*)(base + used);
    const size_t extra_bytes = (size_t)2 * MT * D_ * 4;   // 33.5 MB
    const int ES4 = (used + extra_bytes <= ws_size) ? 1 : 0;

    auto tw = [&](const float* W, bf* Wt, int K, int N, int Kpad, int batch) {
        dim3 g((N + 31) / 32, (Kpad + 31) / 32, batch);
        transpose_w<<<g, 256, 0, stream>>>(W, Wt, K, N, Kpad);
    };
    auto gemm = [&](const bf* A, const bf* Wt, const float* bias,
                    float* Cf, float* Cf2, bf* Cb,
                    int M, int K, int N, int relu, int sk) {
        dim3 g((N + 127) / 128, (M + 127) / 128, sk);
        gemm_bf16<<<g, 256, 0, stream>>>(A, Wt, bias, Cf, Cf2, Cb, M, K, N, relu, sk);
    };
    auto gemm_red = [&](const bf* A, const bf* Wt, const float* bias,
                        float* Cf, bf* Cb, int M, int K, int N, int relu, int sk,
                        float* part) {
        if (sk <= 1) { gemm(A, Wt, bias, Cf, nullptr, Cb, M, K, N, relu, 1); return; }
        const size_t MN = (size_t)M * N;
        gemm(A, Wt, nullptr, part, part + 2 * MN, nullptr, M, K, N, 0, sk);
        const int total4 = (int)(MN / 4);
        reduce_split<<<(total4 + 255) / 256, 256, 0, stream>>>(
            part, part + 2 * MN, sk, MN, bias, N, total4, relu, Cf, Cb);
    };

    tw(in_w1,  wi1, 64,   1024, 64,   1);
    tw(in_w2,  wi2, 1024, 1024, 1024, 1);
    tw(in_w3,  wi3, 1024, 1024, 1024, 1);
    tw(act_w1, wa1, 16,   1024, 32,   1);
    tw(act_w2, wa2, 1024, 1024, 1024, 1);
    tw(act_w3, wa3, 1024, 1024, 1024, 1);
    tw(out_w1, wo1, 1024, 1024, 1024, 1);
    tw(out_w2, wo2, 1024, 1024, 1024, 1);
    tw(out_w3, wo3, 1024, 16,   1024, 1);
    tw(sa_w_in,  wsin,  1024, 3072, 1024, L_);
    tw(sa_w_out, wsout, 1024, 1024, 1024, L_);
    tw(ff_w1,    wf1,   1024, 4096, 1024, L_);
    tw(ff_w2,    wf2,   4096, 1024, 4096, L_);

    convert_pad<<<(Mo * 64 + 255) / 256, 256, 0, stream>>>(obs, obs_bf, Mo, 64, 64);
    convert_pad<<<(Ma * 32 + 255) / 256, 256, 0, stream>>>(act, act_bf, Ma, 16, 32);
    ca_part_kernel<<<dim3((L_ * D_) / 256, 16), 256, 0, stream>>>(ca_b_in, ca_w_out, ca_part);
    ca_reduce_kernel<<<(L_ * D_) / 256, 256, 0, stream>>>(ca_part, ca_b_out, ca);

    // ---- input MLPs (mid/out GEMMs SK=4 -> 512 blocks; partials in shared_rg+vt) ----
    gemm(obs_bf, wi1, in_b1, nullptr, nullptr, h1b, Mo, 64, D_, 1, 1);
    gemm_red(h1b, wi2, in_b2, nullptr, h2b, Mo, D_, D_, 1, 4, part_pre);
    gemm_red(h2b, wi3, in_b3, obs_tok, nullptr, Mo, D_, D_, 0, 4, part_pre);
    gemm(act_bf, wa1, act_b1, nullptr, nullptr, h1b, Ma, 32, D_, 1, 1);
    gemm_red(h1b, wa2, act_b2, nullptr, h2b, Ma, D_, D_, 1, 4, part_pre);
    gemm_red(h2b, wa3, act_b3, act_tok, nullptr, Ma, D_, D_, 0, 4, part_pre);

    interleave_pe_kernel<<<MT, 256, 0, stream>>>(obs_tok, act_tok, x, x_bf);
    // obs_tok/act_tok/y now dead -> part_loop region live.

    // ---- decoder layers ----
    for (int l = 0; l < L_; ++l) {
        gemm(x_bf, wsin + (size_t)l * 3072 * 1024, sa_b_in + (size_t)l * 3 * D_,
             nullptr, nullptr, qkvb, MT, D_, 3 * D_, 0, 1);       // 768 blk, 3/CU
        v_transpose<<<dim3(32, 32, B_), 256, 0, stream>>>(qkvb, vt);
        attn_mfma<<<dim3(B_ * H_, 8), 256, 0, stream>>>(qkvb, vt, attnb);
        // proj SK=2 -> 512 blk; partials consumed by fused double-LN
        gemm(attnb, wsout + (size_t)l * 1024 * 1024, nullptr,
             part_loop, nullptr, nullptr, MT, D_, D_, 0, 2);
        add_ln2_kernel<<<MT, 256, 0, stream>>>(x, part_loop, 2, (size_t)MT * D_,
             sa_b_out + (size_t)l * D_, ca + (size_t)l * D_,
             ln1_g + (size_t)l * D_, ln1_b + (size_t)l * D_,
             ln2_g + (size_t)l * D_, ln2_b + (size_t)l * D_, x_bf);
        gemm(x_bf, wf1 + (size_t)l * 4096 * 1024, ff_b1 + (size_t)l * F_,
             nullptr, nullptr, ffh, MT, D_, F_, 1, 1);            // 1024 blk, 3/CU
        // FFN-down: SK=4 (1024 blk) if extra region fits, else SK=2 (512 blk)
        if (ES4) {
            gemm(ffh, wf2 + (size_t)l * 1024 * 4096, nullptr,
                 part_loop, part_extra, nullptr, MT, F_, D_, 0, 4);
            add_ln_kernel<<<MT, 256, 0, stream>>>(x, part_loop, part_extra, 4,
                 (size_t)MT * D_, ff_b2 + (size_t)l * D_,
                 ln3_g + (size_t)l * D_, ln3_b + (size_t)l * D_, x_bf);
        } else {
            gemm(ffh, wf2 + (size_t)l * 1024 * 4096, nullptr,
                 part_loop, nullptr, nullptr, MT, F_, D_, 0, 2);
            add_ln_kernel<<<MT, 256, 0, stream>>>(x, part_loop, part_loop, 2,
                 (size_t)MT * D_, ff_b2 + (size_t)l * D_,
                 ln3_g + (size_t)l * D_, ln3_b + (size_t)l * D_, x_bf);
        }
    }

    // ---- final norm + output MLP (shared_rg free again; exact 2*MT*D fit) ----
    add_ln_kernel<<<MT, 256, 0, stream>>>(x, nullptr, nullptr, 0, 0, nullptr,
                                          lnf_g, lnf_b, x_bf);
    gemm_red(x_bf, wo1, out_b1, nullptr, h1b, MT, D_, D_, 1, 2, part_post);
    gemm_red(h1b,  wo2, out_b2, nullptr, h2b, MT, D_, D_, 1, 2, part_post);
    gemm_red(h2b,  wo3, out_b3, (float*)d_out, nullptr, MT, D_, 16, 0, 8, part_post);
}

// Round 11
// 1477.554 us; speedup vs baseline: 1.0055x; 1.0055x over previous
//
#include <hip/hip_runtime.h>
#include <hip/hip_bf16.h>
#include <cstdint>
#include <cstddef>

#define B_  4
#define S_  512
#define T_  1023
#define D_  1024
#define H_  16
#define DH_ 64
#define F_  4096
#define L_  4

typedef float f32x4 __attribute__((ext_vector_type(4)));
typedef __bf16 bf16x8 __attribute__((ext_vector_type(8)));

__device__ inline unsigned pack_bf2(float a, float b) {
    union { __hip_bfloat16 h; unsigned short u; } ua, ub;
    ua.h = __float2bfloat16(a); ub.h = __float2bfloat16(b);
    return (unsigned)ua.u | ((unsigned)ub.u << 16);
}

// ---------------------------------------------------------------------------
// bf16 MFMA GEMM, 128x64 tile (round-9 proven: best measured config) with
// 3-buffer counted-vmcnt pipeline. Split-K via blockIdx.z: slices z<2 ->
// Cf + z*M*N, z>=2 -> Cf2 + (z-2)*M*N (dual-region). Optional vtw mode
// (QKV only): columns c>=2048 are V — written transposed into vtp
// (vt[b*1024 + (c-2048)][t]) instead of Cb, fusing away v_transpose.
// ---------------------------------------------------------------------------
__global__ __launch_bounds__(256) void gemm_bf16(
    const __hip_bfloat16* __restrict__ A, const __hip_bfloat16* __restrict__ Wt,
    const float* __restrict__ bias,
    float* __restrict__ Cf, float* __restrict__ Cf2,
    __hip_bfloat16* __restrict__ Cb,
    int M, int K, int N, int relu, int ksplit,
    __hip_bfloat16* __restrict__ vtp, int vtw)
{
    __shared__ __align__(16) __hip_bfloat16 AsmB[3][128 * 32];   // 24 KB
    __shared__ __align__(16) __hip_bfloat16 BsmB[3][64 * 32];    // 12 KB
    const int tid  = threadIdx.x;
    const int lane = tid & 63;
    const int w    = tid >> 6;
    const int wr   = w >> 1, wc = w & 1;          // wave grid 2x2: 64 rows x 32 cols
    const int l15  = lane & 15, l4 = lane >> 4;

    // bijective XCD-aware swizzle (m204) on the x-y plane
    const int gx = gridDim.x;
    int bid = blockIdx.y * gx + blockIdx.x;
    {
        const int nwg = gx * gridDim.y;
        const int q = nwg >> 3, r = nwg & 7;
        const int xcd = bid & 7, idx = bid >> 3;
        bid = (xcd < r ? xcd * (q + 1) : r * (q + 1) + (xcd - r) * q) + idx;
    }
    const int row0 = (bid / gx) * 128;
    const int col0 = (bid % gx) * 64;
    const int z = blockIdx.z;
    const int kslice = K / ksplit;
    const int kbase = z * kslice;

    f32x4 acc[4][2] = {};

    auto stage = [&](__hip_bfloat16* As, __hip_bfloat16* Bs, int kt) {
        auto* ldsA = (__attribute__((address_space(3))) char*)As;
        auto* ldsB = (__attribute__((address_space(3))) char*)Bs;
        #pragma unroll
        for (int half = 0; half < 2; ++half) {     // A tile: 128x32 = 512 chunks
            const int ch = half * 256 + tid;
            const int r  = ch >> 2;
            const int c  = (ch & 3) * 8;
            int gr = row0 + r; gr = (gr < M) ? gr : (M - 1);
            const __hip_bfloat16* srcA = A + (size_t)gr * K + kt + c;
            __builtin_amdgcn_global_load_lds(
                (const __attribute__((address_space(1))) unsigned*)srcA,
                (__attribute__((address_space(3))) unsigned*)(ldsA + (size_t)ch * 16),
                16, 0, 0);
        }
        {                                          // B tile: 64x32 = 256 chunks
            const int r = tid >> 2;
            const int c = (tid & 3) * 8;
            int gc = col0 + r; gc = (gc < N) ? gc : (N - 1);
            const __hip_bfloat16* srcB = Wt + (size_t)gc * K + kt + c;
            __builtin_amdgcn_global_load_lds(
                (const __attribute__((address_space(1))) unsigned*)srcB,
                (__attribute__((address_space(3))) unsigned*)(ldsB + (size_t)tid * 16),
                16, 0, 0);
        }
    };
    auto compute = [&](const __hip_bfloat16* As, const __hip_bfloat16* Bs) {
        const __hip_bfloat16* ab = As + (size_t)(wr * 64 + l15) * 32 + l4 * 8;
        const __hip_bfloat16* bb = Bs + (size_t)(wc * 32 + l15) * 32 + l4 * 8;
        bf16x8 af[4], bf[2];
        #pragma unroll
        for (int mi = 0; mi < 4; ++mi) af[mi] = *(const bf16x8*)(ab + mi * 16 * 32);
        #pragma unroll
        for (int nj = 0; nj < 2; ++nj) bf[nj] = *(const bf16x8*)(bb + nj * 16 * 32);
        #pragma unroll
        for (int mi = 0; mi < 4; ++mi)
            #pragma unroll
            for (int nj = 0; nj < 2; ++nj)
                acc[mi][nj] = __builtin_amdgcn_mfma_f32_16x16x32_bf16(
                    af[mi], bf[nj], acc[mi][nj], 0, 0, 0);
    };

    const int nk = kslice >> 5;
    __hip_bfloat16 *A0 = AsmB[0], *A1 = AsmB[1], *A2 = AsmB[2];
    __hip_bfloat16 *B0 = BsmB[0], *B1 = BsmB[1], *B2 = BsmB[2];
    stage(A0, B0, kbase);                       // 3 loads/thread
    if (nk > 1) stage(A1, B1, kbase + 32);      // +3 -> 6 outstanding
    for (int t = 0; t < nk; ++t) {
        if (t + 1 < nk) {
            asm volatile("s_waitcnt vmcnt(3)" ::: "memory");   // tile t done; t+1 in flight
        } else {
            asm volatile("s_waitcnt vmcnt(0)" ::: "memory");   // last tile
        }
        __builtin_amdgcn_s_barrier();           // raw: no vmcnt drain
        if (t + 2 < nk) stage(A2, B2, kbase + (t + 2) * 32);   // back to 6 in flight
        compute(A0, B0);
        __hip_bfloat16* ta = A0; A0 = A1; A1 = A2; A2 = ta;
        __hip_bfloat16* tb = B0; B0 = B1; B1 = B2; B2 = tb;
    }

    // epilogue: C/D layout col = lane&15, row = (lane>>4)*4 + i  [m89-verified]
    if (ksplit > 1) {
        const size_t MN = (size_t)M * N;
        float* dst = (z < 2) ? (Cf + (size_t)z * MN) : (Cf2 + (size_t)(z - 2) * MN);
        #pragma unroll
        for (int nj = 0; nj < 2; ++nj) {
            const int c = col0 + wc * 32 + nj * 16 + l15;
            if (c >= N) continue;
            #pragma unroll
            for (int mi = 0; mi < 4; ++mi)
                #pragma unroll
                for (int i = 0; i < 4; ++i) {
                    const int r = row0 + wr * 64 + mi * 16 + l4 * 4 + i;
                    if (r < M) dst[(size_t)r * N + c] = acc[mi][nj][i];
                }
        }
    } else if (vtw) {
        // QKV mode: c<2048 (Q|K) -> Cb row-major; c>=2048 (V) -> transposed vt.
        // vt row t=1023 never written: V[1023] always has P=0 in attention.
        #pragma unroll
        for (int nj = 0; nj < 2; ++nj) {
            const int c = col0 + wc * 32 + nj * 16 + l15;
            const float bv = bias[c];
            #pragma unroll
            for (int mi = 0; mi < 4; ++mi)
                #pragma unroll
                for (int i = 0; i < 4; ++i) {
                    const int r = row0 + wr * 64 + mi * 16 + l4 * 4 + i;
                    if (r >= M) continue;
                    const float v = acc[mi][nj][i] + bv;
                    if (c < 2048) {
                        Cb[(size_t)r * N + c] = __float2bfloat16(v);
                    } else {
                        const int b = r / T_;
                        const int tl = r - b * T_;
                        vtp[((size_t)(b * 1024 + (c - 2048))) * 1024 + tl] =
                            __float2bfloat16(v);
                    }
                }
        }
    } else {
        #pragma unroll
        for (int nj = 0; nj < 2; ++nj) {
            const int c = col0 + wc * 32 + nj * 16 + l15;
            if (c >= N) continue;
            const float bv = bias[c];
            #pragma unroll
            for (int mi = 0; mi < 4; ++mi)
                #pragma unroll
                for (int i = 0; i < 4; ++i) {
                    const int r = row0 + wr * 64 + mi * 16 + l4 * 4 + i;
                    if (r >= M) continue;
                    float v = acc[mi][nj][i] + bv;
                    if (relu) v = fmaxf(v, 0.f);
                    if (Cf) Cf[(size_t)r * N + c] = v;
                    if (Cb) Cb[(size_t)r * N + c] = __float2bfloat16(v);
                }
        }
    }
}

// ---------------------------------------------------------------------------
// Split-K reduction (dual-region): slices s<2 from part, s>=2 from part2.
// out = op(sum_s slice[s] + bias). Requires N power of 2.
// ---------------------------------------------------------------------------
__global__ __launch_bounds__(256) void reduce_split(
    const float* __restrict__ part, const float* __restrict__ part2,
    int SK, size_t pstride,
    const float* __restrict__ bias, int N, int total4, int relu,
    float* __restrict__ outf, __hip_bfloat16* __restrict__ outb)
{
    const int idx4 = blockIdx.x * 256 + threadIdx.x;
    if (idx4 >= total4) return;
    const size_t base = (size_t)idx4 * 4;
    const int c = (int)(base & (size_t)(N - 1));
    float4 v = *(const float4*)(part + base);
    for (int s = 1; s < SK; ++s) {
        const float* src = (s < 2) ? (part + (size_t)s * pstride)
                                   : (part2 + (size_t)(s - 2) * pstride);
        const float4 p = *(const float4*)(src + base);
        v.x += p.x; v.y += p.y; v.z += p.z; v.w += p.w;
    }
    const float4 bv = *(const float4*)(bias + c);
    v.x += bv.x; v.y += bv.y; v.z += bv.z; v.w += bv.w;
    if (relu) {
        v.x = fmaxf(v.x, 0.f); v.y = fmaxf(v.y, 0.f);
        v.z = fmaxf(v.z, 0.f); v.w = fmaxf(v.w, 0.f);
    }
    if (outf) *(float4*)(outf + base) = v;
    if (outb) {
        __hip_bfloat16* o = outb + base;
        o[0] = __float2bfloat16(v.x); o[1] = __float2bfloat16(v.y);
        o[2] = __float2bfloat16(v.z); o[3] = __float2bfloat16(v.w);
    }
}

// ---------------------------------------------------------------------------
// Weight transpose+convert (unchanged).
// ---------------------------------------------------------------------------
__global__ __launch_bounds__(256) void transpose_w(
    const float* __restrict__ W, __hip_bfloat16* __restrict__ Wt,
    int K, int N, int Kpad)
{
    __shared__ float t[32][33];
    W  += (size_t)blockIdx.z * K * N;
    Wt += (size_t)blockIdx.z * N * Kpad;
    const int n0 = blockIdx.x * 32, k0 = blockIdx.y * 32;
    const int tx = threadIdx.x & 31, ty = threadIdx.x >> 5;
    #pragma unroll
    for (int i = 0; i < 4; ++i) {
        int r = ty + i * 8;
        int k = k0 + r, n = n0 + tx;
        t[r][tx] = (k < K && n < N) ? W[(size_t)k * N + n] : 0.f;
    }
    __syncthreads();
    #pragma unroll
    for (int i = 0; i < 4; ++i) {
        int r = ty + i * 8;
        int n = n0 + r, k = k0 + tx;
        if (n < N && k < Kpad) Wt[(size_t)n * Kpad + k] = __float2bfloat16(t[tx][r]);
    }
}

__global__ __launch_bounds__(256) void convert_pad(
    const float* __restrict__ in, __hip_bfloat16* __restrict__ out,
    int M, int Kin, int Kout)
{
    int idx = blockIdx.x * 256 + threadIdx.x;
    if (idx >= M * Kout) return;
    int r = idx / Kout, c = idx - r * Kout;
    out[idx] = __float2bfloat16(c < Kin ? in[(size_t)r * Kin + c] : 0.f);
}

// ---------------------------------------------------------------------------
// MFMA flash attention (unchanged from round 3 — proven).
// ---------------------------------------------------------------------------
__global__ __launch_bounds__(256) void attn_mfma(
    const __hip_bfloat16* __restrict__ qkvb,
    const __hip_bfloat16* __restrict__ vt,
    __hip_bfloat16* __restrict__ out)
{
    __shared__ __align__(16) __hip_bfloat16 Qs[2][128][32];
    __shared__ __align__(16) __hip_bfloat16 Ks[2][64][32];
    __shared__ __align__(16) __hip_bfloat16 Vs[2][64][32];
    __shared__ __align__(16) __hip_bfloat16 Ps[4][2][32][32];
    __shared__ float Lw[4][2][16];

    const int bh = blockIdx.x;
    const int b = bh >> 4, h = bh & 15;
    const int q0 = blockIdx.y * 128;
    const int tid = threadIdx.x;
    const int w = tid >> 6, lane = tid & 63;
    const int l15 = lane & 15, l4 = lane >> 4;
    const size_t ldq = 3 * D_;

    {
        #pragma unroll
        for (int c = 0; c < 2; ++c)
            #pragma unroll
            for (int it = 0; it < 2; ++it) {
                const int ch = it * 256 + tid;
                const int r = ch >> 2, cp = ch & 3;
                int qr = q0 + r; qr = (qr < T_) ? qr : (T_ - 1);
                const __hip_bfloat16* src = qkvb + (size_t)(b * T_ + qr) * ldq + h * 64 + c * 32 + cp * 8;
                __builtin_amdgcn_global_load_lds(
                    (const __attribute__((address_space(1))) unsigned*)src,
                    (__attribute__((address_space(3))) unsigned*)((__attribute__((address_space(3))) char*)&Qs[c][0][0] + ch * 16),
                    16, 0, 0);
            }
    }
    __syncthreads();
    bf16x8 qreg[2][2];
    #pragma unroll
    for (int qf = 0; qf < 2; ++qf)
        #pragma unroll
        for (int c = 0; c < 2; ++c)
            qreg[qf][c] = *(const bf16x8*)&Qs[c][w * 32 + qf * 16 + l15][l4 * 8];

    f32x4 of[2][4] = {};
    float lp[2] = {0.f, 0.f};
    const int qmaxw = q0 + w * 32 + 31;
    const int kend = (q0 + 128 < T_) ? (q0 + 128) : T_;

    for (int k0 = 0; k0 < kend; k0 += 64) {
        __syncthreads();
        {
            const int r = tid >> 2, cp = tid & 3;
            #pragma unroll
            for (int c = 0; c < 2; ++c) {
                int kr = k0 + r; kr = (kr < T_) ? kr : (T_ - 1);
                const __hip_bfloat16* srcK = qkvb + (size_t)(b * T_ + kr) * ldq + D_ + h * 64 + c * 32 + cp * 8;
                __builtin_amdgcn_global_load_lds(
                    (const __attribute__((address_space(1))) unsigned*)srcK,
                    (__attribute__((address_space(3))) unsigned*)((__attribute__((address_space(3))) char*)&Ks[c][0][0] + tid * 16),
                    16, 0, 0);
                const __hip_bfloat16* srcV = vt + ((size_t)(b * 1024 + h * 64 + r)) * 1024 + k0 + c * 32 + cp * 8;
                __builtin_amdgcn_global_load_lds(
                    (const __attribute__((address_space(1))) unsigned*)srcV,
                    (__attribute__((address_space(3))) unsigned*)((__attribute__((address_space(3))) char*)&Vs[c][0][0] + tid * 16),
                    16, 0, 0);
            }
        }
        __syncthreads();

        if (k0 <= qmaxw) {
            f32x4 sf[4][2] = {};
            #pragma unroll
            for (int c = 0; c < 2; ++c) {
                bf16x8 kf[4];
                #pragma unroll
                for (int kfr = 0; kfr < 4; ++kfr)
                    kf[kfr] = *(const bf16x8*)&Ks[c][kfr * 16 + l15][l4 * 8];
                #pragma unroll
                for (int kfr = 0; kfr < 4; ++kfr)
                    #pragma unroll
                    for (int qf = 0; qf < 2; ++qf)
                        sf[kfr][qf] = __builtin_amdgcn_mfma_f32_16x16x32_bf16(
                            kf[kfr], qreg[qf][c], sf[kfr][qf], 0, 0, 0);
            }
            const bool needmask = (k0 + 63) > (q0 + w * 32);
            #pragma unroll
            for (int kfr = 0; kfr < 4; ++kfr) {
                #pragma unroll
                for (int qf = 0; qf < 2; ++qf) {
                    const int qg = q0 + w * 32 + qf * 16 + l15;
                    float p[4];
                    #pragma unroll
                    for (int i = 0; i < 4; ++i) {
                        const int kg = k0 + kfr * 16 + l4 * 4 + i;
                        float pv = __expf(sf[kfr][qf][i] * 0.125f);
                        if (needmask && kg > qg) pv = 0.f;
                        p[i] = pv;
                        lp[qf] += pv;
                    }
                    unsigned* dst = (unsigned*)&Ps[w][kfr >> 1][qf * 16 + l15][(kfr & 1) * 16 + l4 * 4];
                    dst[0] = pack_bf2(p[0], p[1]);
                    dst[1] = pack_bf2(p[2], p[3]);
                }
            }
            #pragma unroll
            for (int kc = 0; kc < 2; ++kc) {
                bf16x8 pa[2], vb[4];
                #pragma unroll
                for (int qf = 0; qf < 2; ++qf)
                    pa[qf] = *(const bf16x8*)&Ps[w][kc][qf * 16 + l15][l4 * 8];
                #pragma unroll
                for (int df = 0; df < 4; ++df)
                    vb[df] = *(const bf16x8*)&Vs[kc][df * 16 + l15][l4 * 8];
                #pragma unroll
                for (int qf = 0; qf < 2; ++qf)
                    #pragma unroll
                    for (int df = 0; df < 4; ++df)
                        of[qf][df] = __builtin_amdgcn_mfma_f32_16x16x32_bf16(
                            pa[qf], vb[df], of[qf][df], 0, 0, 0);
            }
        }
    }

    #pragma unroll
    for (int qf = 0; qf < 2; ++qf) {
        float v = lp[qf];
        v += __shfl_xor(v, 16);
        v += __shfl_xor(v, 32);
        if (l4 == 0) Lw[w][qf][l15] = v;
    }
    __syncthreads();
    #pragma unroll
    for (int qf = 0; qf < 2; ++qf) {
        float inv[4];
        #pragma unroll
        for (int i = 0; i < 4; ++i) inv[i] = 1.f / Lw[w][qf][l4 * 4 + i];
        #pragma unroll
        for (int df = 0; df < 4; ++df) {
            #pragma unroll
            for (int i = 0; i < 4; ++i) {
                const int qg = q0 + w * 32 + qf * 16 + l4 * 4 + i;
                if (qg < T_)
                    out[(size_t)(b * T_ + qg) * D_ + h * 64 + df * 16 + l15] =
                        __float2bfloat16(of[qf][df][i] * inv[i]);
            }
        }
    }
}

// ---------------------------------------------------------------------------
// LN helpers. Residual: SK slices (s<2 from p, s>=2 from p2) + optional bias.
// ---------------------------------------------------------------------------
__device__ inline void block_ln_stats(float4 v, float& mu, float& inv,
                                      float* ws, float* ws2, float* mu_s, float* inv_s)
{
    const int tid = threadIdx.x;
    float s  = v.x + v.y + v.z + v.w;
    float s2 = v.x * v.x + v.y * v.y + v.z * v.z + v.w * v.w;
    #pragma unroll
    for (int off = 32; off; off >>= 1) {
        s  += __shfl_down(s, off);
        s2 += __shfl_down(s2, off);
    }
    const int wid = tid >> 6;
    if ((tid & 63) == 0) { ws[wid] = s; ws2[wid] = s2; }
    __syncthreads();
    if (tid == 0) {
        float S  = ws[0] + ws[1] + ws[2] + ws[3];
        float S2 = ws2[0] + ws2[1] + ws2[2] + ws2[3];
        float m = S * (1.f / (float)D_);
        float var = S2 * (1.f / (float)D_) - m * m;
        *mu_s = m;
        *inv_s = rsqrtf(var + 1e-5f);
    }
    __syncthreads();
    mu = *mu_s; inv = *inv_s;
}

__global__ __launch_bounds__(256) void add_ln_kernel(
    float* __restrict__ x, const float* __restrict__ p, const float* __restrict__ p2,
    int SK, size_t pstride, const float* __restrict__ pbias,
    const float* __restrict__ g, const float* __restrict__ beta,
    __hip_bfloat16* __restrict__ xb)
{
    const int row = blockIdx.x;
    const int tid = threadIdx.x;
    __shared__ float ws[4], ws2[4], mu_s, inv_s;
    float4* xr = reinterpret_cast<float4*>(x + (size_t)row * D_);
    float4 v = xr[tid];
    if (p) {
        for (int s = 0; s < SK; ++s) {
            const float* src = (s < 2) ? (p + (size_t)s * pstride)
                                       : (p2 + (size_t)(s - 2) * pstride);
            const float4 wv = reinterpret_cast<const float4*>(src + (size_t)row * D_)[tid];
            v.x += wv.x; v.y += wv.y; v.z += wv.z; v.w += wv.w;
        }
        if (pbias) {
            const float4 bv = reinterpret_cast<const float4*>(pbias)[tid];
            v.x += bv.x; v.y += bv.y; v.z += bv.z; v.w += bv.w;
        }
    }
    float mu, inv;
    block_ln_stats(v, mu, inv, ws, ws2, &mu_s, &inv_s);
    const float4 gg = reinterpret_cast<const float4*>(g)[tid];
    const float4 bb = reinterpret_cast<const float4*>(beta)[tid];
    float4 o;
    o.x = (v.x - mu) * inv * gg.x + bb.x;
    o.y = (v.y - mu) * inv * gg.y + bb.y;
    o.z = (v.z - mu) * inv * gg.z + bb.z;
    o.w = (v.w - mu) * inv * gg.w + bb.w;
    xr[tid] = o;
    if (xb) {
        __hip_bfloat16* xo = xb + (size_t)row * D_ + tid * 4;
        xo[0] = __float2bfloat16(o.x);
        xo[1] = __float2bfloat16(o.y);
        xo[2] = __float2bfloat16(o.z);
        xo[3] = __float2bfloat16(o.w);
    }
}

__global__ __launch_bounds__(256) void add_ln2_kernel(
    float* __restrict__ x, const float* __restrict__ p, int SK, size_t pstride,
    const float* __restrict__ pbias, const float* __restrict__ cav,
    const float* __restrict__ g1, const float* __restrict__ b1,
    const float* __restrict__ g2, const float* __restrict__ b2,
    __hip_bfloat16* __restrict__ xb)
{
    const int row = blockIdx.x;
    const int tid = threadIdx.x;
    __shared__ float ws[4], ws2[4], mu_s, inv_s;
    float4* xr = reinterpret_cast<float4*>(x + (size_t)row * D_);
    float4 v = xr[tid];
    for (int s = 0; s < SK; ++s) {
        const float4 wv = reinterpret_cast<const float4*>(
            p + (size_t)s * pstride + (size_t)row * D_)[tid];
        v.x += wv.x; v.y += wv.y; v.z += wv.z; v.w += wv.w;
    }
    if (pbias) {
        const float4 bv = reinterpret_cast<const float4*>(pbias)[tid];
        v.x += bv.x; v.y += bv.y; v.z += bv.z; v.w += bv.w;
    }
    float mu, inv;
    block_ln_stats(v, mu, inv, ws, ws2, &mu_s, &inv_s);
    const float4 g1v = reinterpret_cast<const float4*>(g1)[tid];
    const float4 b1v = reinterpret_cast<const float4*>(b1)[tid];
    const float4 cv  = reinterpret_cast<const float4*>(cav)[tid];
    float4 u;
    u.x = (v.x - mu) * inv * g1v.x + b1v.x + cv.x;
    u.y = (v.y - mu) * inv * g1v.y + b1v.y + cv.y;
    u.z = (v.z - mu) * inv * g1v.z + b1v.z + cv.z;
    u.w = (v.w - mu) * inv * g1v.w + b1v.w + cv.w;
    __syncthreads();
    float mu2, inv2;
    block_ln_stats(u, mu2, inv2, ws, ws2, &mu_s, &inv_s);
    const float4 g2v = reinterpret_cast<const float4*>(g2)[tid];
    const float4 b2v = reinterpret_cast<const float4*>(b2)[tid];
    float4 o;
    o.x = (u.x - mu2) * inv2 * g2v.x + b2v.x;
    o.y = (u.y - mu2) * inv2 * g2v.y + b2v.y;
    o.z = (u.z - mu2) * inv2 * g2v.z + b2v.z;
    o.w = (u.w - mu2) * inv2 * g2v.w + b2v.w;
    xr[tid] = o;
    __hip_bfloat16* xo = xb + (size_t)row * D_ + tid * 4;
    xo[0] = __float2bfloat16(o.x);
    xo[1] = __float2bfloat16(o.y);
    xo[2] = __float2bfloat16(o.z);
    xo[3] = __float2bfloat16(o.w);
}

__global__ __launch_bounds__(256) void interleave_pe_kernel(
    const float* __restrict__ obs_tok, const float* __restrict__ act_tok,
    float* __restrict__ x, __hip_bfloat16* __restrict__ xb)
{
    const int row = blockIdx.x;
    const int b = row / T_;
    const int t = row - b * T_;
    const float* src = (t & 1)
        ? (act_tok + (size_t)(b * (S_ - 1) + (t >> 1)) * D_)
        : (obs_tok + (size_t)(b * S_ + (t >> 1)) * D_);
    float* xr = x + (size_t)row * D_;
    __hip_bfloat16* xo = xb + (size_t)row * D_;
    #pragma unroll
    for (int k = 0; k < 4; ++k) {
        int d = threadIdx.x + k * 256;
        float ang = (float)b * expf(-(float)(d & ~1) * (9.210340371976184f / 1024.0f));
        float pe = (d & 1) ? cosf(ang) : sinf(ang);
        float v = src[d] + pe;
        xr[d] = v;
        xo[d] = __float2bfloat16(v);
    }
}

__global__ __launch_bounds__(256) void ca_part_kernel(
    const float* __restrict__ ca_b_in, const float* __restrict__ ca_w_out,
    float* __restrict__ part)
{
    const int idx = blockIdx.x * 256 + threadIdx.x;
    const int ks = blockIdx.y;
    const int l = idx >> 10, d = idx & 1023;
    const float* bv = ca_b_in + (size_t)l * 3 * D_ + 2 * D_ + ks * 64;
    const float* wp = ca_w_out + (size_t)l * D_ * D_ + (size_t)(ks * 64) * D_ + d;
    float s = 0.f;
    #pragma unroll 8
    for (int k = 0; k < 64; ++k) s = fmaf(bv[k], wp[(size_t)k * D_], s);
    part[(size_t)ks * (L_ * D_) + idx] = s;
}

__global__ __launch_bounds__(256) void ca_reduce_kernel(
    const float* __restrict__ part, const float* __restrict__ ca_b_out,
    float* __restrict__ out)
{
    const int idx = blockIdx.x * 256 + threadIdx.x;
    float s = ca_b_out[idx];
    #pragma unroll
    for (int ks = 0; ks < 16; ++ks) s += part[(size_t)ks * (L_ * D_) + idx];
    out[idx] = s;
}

// ---------------------------------------------------------------------------
extern "C" void kernel_launch(void* const* d_in, const int* in_sizes, int n_in,
                              void* d_out, int out_size, void* d_ws, size_t ws_size,
                              hipStream_t stream)
{
    const float* obs     = (const float*)d_in[0];
    const float* act     = (const float*)d_in[1];
    const float* in_w1   = (const float*)d_in[2];
    const float* in_b1   = (const float*)d_in[3];
    const float* in_w2   = (const float*)d_in[4];
    const float* in_b2   = (const float*)d_in[5];
    const float* in_w3   = (const float*)d_in[6];
    const float* in_b3   = (const float*)d_in[7];
    const float* act_w1  = (const float*)d_in[8];
    const float* act_b1  = (const float*)d_in[9];
    const float* act_w2  = (const float*)d_in[10];
    const float* act_b2  = (const float*)d_in[11];
    const float* act_w3  = (const float*)d_in[12];
    const float* act_b3  = (const float*)d_in[13];
    const float* out_w1  = (const float*)d_in[14];
    const float* out_b1  = (const float*)d_in[15];
    const float* out_w2  = (const float*)d_in[16];
    const float* out_b2  = (const float*)d_in[17];
    const float* out_w3  = (const float*)d_in[18];
    const float* out_b3  = (const float*)d_in[19];
    const float* sa_w_in = (const float*)d_in[20];
    const float* sa_b_in = (const float*)d_in[21];
    const float* sa_w_out= (const float*)d_in[22];
    const float* sa_b_out= (const float*)d_in[23];
    const float* ca_b_in = (const float*)d_in[25];
    const float* ca_w_out= (const float*)d_in[26];
    const float* ca_b_out= (const float*)d_in[27];
    const float* ff_w1   = (const float*)d_in[28];
    const float* ff_b1   = (const float*)d_in[29];
    const float* ff_w2   = (const float*)d_in[30];
    const float* ff_b2   = (const float*)d_in[31];
    const float* ln1_g   = (const float*)d_in[32];
    const float* ln1_b   = (const float*)d_in[33];
    const float* ln2_g   = (const float*)d_in[34];
    const float* ln2_b   = (const float*)d_in[35];
    const float* ln3_g   = (const float*)d_in[36];
    const float* ln3_b   = (const float*)d_in[37];
    const float* lnf_g   = (const float*)d_in[38];
    const float* lnf_b   = (const float*)d_in[39];

    const int MT = B_ * T_;          // 4092
    const int Mo = B_ * S_;          // 2048
    const int Ma = B_ * (S_ - 1);    // 2044

    char* base = (char*)d_ws;
    size_t used = 0;
    auto alloc = [&](size_t bytes) -> char* {
        char* r = base + used;
        used += (bytes + 255) & ~(size_t)255;
        return r;
    };
    typedef __hip_bfloat16 bf;
    bf* wi1  = (bf*)alloc((size_t)1024 * 64 * 2);
    bf* wi2  = (bf*)alloc((size_t)1024 * 1024 * 2);
    bf* wi3  = (bf*)alloc((size_t)1024 * 1024 * 2);
    bf* wa1  = (bf*)alloc((size_t)1024 * 32 * 2);
    bf* wa2  = (bf*)alloc((size_t)1024 * 1024 * 2);
    bf* wa3  = (bf*)alloc((size_t)1024 * 1024 * 2);
    bf* wo1  = (bf*)alloc((size_t)1024 * 1024 * 2);
    bf* wo2  = (bf*)alloc((size_t)1024 * 1024 * 2);
    bf* wo3  = (bf*)alloc((size_t)16 * 1024 * 2);
    bf* wsin = (bf*)alloc((size_t)L_ * 3072 * 1024 * 2);
    bf* wsout= (bf*)alloc((size_t)L_ * 1024 * 1024 * 2);
    bf* wf1  = (bf*)alloc((size_t)L_ * 4096 * 1024 * 2);
    bf* wf2  = (bf*)alloc((size_t)L_ * 1024 * 4096 * 2);
    bf* obs_bf = (bf*)alloc((size_t)Mo * 64 * 2);
    bf* act_bf = (bf*)alloc((size_t)Ma * 32 * 2);
    bf* x_bf   = (bf*)alloc((size_t)MT * D_ * 2);
    bf* attnb  = (bf*)alloc((size_t)MT * D_ * 2);
    bf* h1b    = (bf*)alloc((size_t)MT * D_ * 2);
    bf* h2b    = (bf*)alloc((size_t)MT * D_ * 2);
    char* shared_rg = alloc((size_t)MT * F_ * 2);   // qkvb | ffh | out-MLP partials
    bf* qkvb = (bf*)shared_rg;
    bf* ffh  = (bf*)shared_rg;
    bf* vt   = (bf*)alloc((size_t)B_ * 1024 * 1024 * 2);
    float* x       = (float*)alloc((size_t)MT * D_ * 4);
    // [y, obs_tok, act_tok] = contiguous 33,521,664 B = exactly 2*MT*D_*4:
    // reused as in-loop split-K partial slices 0,1.
    float* y       = (float*)alloc((size_t)MT * D_ * 4);
    float* obs_tok = (float*)alloc((size_t)Mo * D_ * 4);
    float* act_tok = (float*)alloc((size_t)Ma * D_ * 4);
    float* ca      = (float*)alloc((size_t)L_ * D_ * 4);
    float* ca_part = (float*)alloc((size_t)16 * L_ * D_ * 4);
    if (used > ws_size) return;                       // baseline must fit (it did r7-r10)
    float* part_loop = y;                 // slices 0,1 (2*MT*D fp32)
    float* part_pre  = (float*)shared_rg; // pre-loop SK<=4 on Mo (spans shared_rg+vt)
    float* part_post = (float*)shared_rg; // post-loop, 2*MT*D exact fit
    // optional extra 2 slices for FFN-down SK=4 (guarded; fallback SK=2)
    float* part_extra = (float*)(base + used);
    const size_t extra_bytes = (size_t)2 * MT * D_ * 4;   // 33.5 MB
    const int ES4 = (used + extra_bytes <= ws_size) ? 1 : 0;

    auto tw = [&](const float* W, bf* Wt, int K, int N, int Kpad, int batch) {
        dim3 g((N + 31) / 32, (Kpad + 31) / 32, batch);
        transpose_w<<<g, 256, 0, stream>>>(W, Wt, K, N, Kpad);
    };
    auto gemm = [&](const bf* A, const bf* Wt, const float* bias,
                    float* Cf, float* Cf2, bf* Cb,
                    int M, int K, int N, int relu, int sk,
                    bf* vtp = nullptr, int vtw = 0) {
        dim3 g((N + 63) / 64, (M + 127) / 128, sk);
        gemm_bf16<<<g, 256, 0, stream>>>(A, Wt, bias, Cf, Cf2, Cb,
                                          M, K, N, relu, sk, vtp, vtw);
    };
    auto gemm_red = [&](const bf* A, const bf* Wt, const float* bias,
                        float* Cf, bf* Cb, int M, int K, int N, int relu, int sk,
                        float* part) {
        if (sk <= 1) { gemm(A, Wt, bias, Cf, nullptr, Cb, M, K, N, relu, 1); return; }
        const size_t MN = (size_t)M * N;
        gemm(A, Wt, nullptr, part, part + 2 * MN, nullptr, M, K, N, 0, sk);
        const int total4 = (int)(MN / 4);
        reduce_split<<<(total4 + 255) / 256, 256, 0, stream>>>(
            part, part + 2 * MN, sk, MN, bias, N, total4, relu, Cf, Cb);
    };

    tw(in_w1,  wi1, 64,   1024, 64,   1);
    tw(in_w2,  wi2, 1024, 1024, 1024, 1);
    tw(in_w3,  wi3, 1024, 1024, 1024, 1);
    tw(act_w1, wa1, 16,   1024, 32,   1);
    tw(act_w2, wa2, 1024, 1024, 1024, 1);
    tw(act_w3, wa3, 1024, 1024, 1024, 1);
    tw(out_w1, wo1, 1024, 1024, 1024, 1);
    tw(out_w2, wo2, 1024, 1024, 1024, 1);
    tw(out_w3, wo3, 1024, 16,   1024, 1);
    tw(sa_w_in,  wsin,  1024, 3072, 1024, L_);
    tw(sa_w_out, wsout, 1024, 1024, 1024, L_);
    tw(ff_w1,    wf1,   1024, 4096, 1024, L_);
    tw(ff_w2,    wf2,   4096, 1024, 4096, L_);

    convert_pad<<<(Mo * 64 + 255) / 256, 256, 0, stream>>>(obs, obs_bf, Mo, 64, 64);
    convert_pad<<<(Ma * 32 + 255) / 256, 256, 0, stream>>>(act, act_bf, Ma, 16, 32);
    ca_part_kernel<<<dim3((L_ * D_) / 256, 16), 256, 0, stream>>>(ca_b_in, ca_w_out, ca_part);
    ca_reduce_kernel<<<(L_ * D_) / 256, 256, 0, stream>>>(ca_part, ca_b_out, ca);

    // ---- input MLPs (mid/out GEMMs SK=4 -> 1024 blocks; partials in shared_rg+vt) ----
    gemm(obs_bf, wi1, in_b1, nullptr, nullptr, h1b, Mo, 64, D_, 1, 1);
    gemm_red(h1b, wi2, in_b2, nullptr, h2b, Mo, D_, D_, 1, 4, part_pre);
    gemm_red(h2b, wi3, in_b3, obs_tok, nullptr, Mo, D_, D_, 0, 4, part_pre);
    gemm(act_bf, wa1, act_b1, nullptr, nullptr, h1b, Ma, 32, D_, 1, 1);
    gemm_red(h1b, wa2, act_b2, nullptr, h2b, Ma, D_, D_, 1, 4, part_pre);
    gemm_red(h2b, wa3, act_b3, act_tok, nullptr, Ma, D_, D_, 0, 4, part_pre);

    interleave_pe_kernel<<<MT, 256, 0, stream>>>(obs_tok, act_tok, x, x_bf);
    // obs_tok/act_tok/y now dead -> part_loop region live.

    // ---- decoder layers ----
    for (int l = 0; l < L_; ++l) {
        // QKV with fused V^T write (v_transpose eliminated)
        gemm(x_bf, wsin + (size_t)l * 3072 * 1024, sa_b_in + (size_t)l * 3 * D_,
             nullptr, nullptr, qkvb, MT, D_, 3 * D_, 0, 1, vt, 1);   // 1536 blk, 6/CU
        attn_mfma<<<dim3(B_ * H_, 8), 256, 0, stream>>>(qkvb, vt, attnb);
        // proj SK=2 -> 1024 blk; partials consumed by fused double-LN
        gemm(attnb, wsout + (size_t)l * 1024 * 1024, nullptr,
             part_loop, nullptr, nullptr, MT, D_, D_, 0, 2);
        add_ln2_kernel<<<MT, 256, 0, stream>>>(x, part_loop, 2, (size_t)MT * D_,
             sa_b_out + (size_t)l * D_, ca + (size_t)l * D_,
             ln1_g + (size_t)l * D_, ln1_b + (size_t)l * D_,
             ln2_g + (size_t)l * D_, ln2_b + (size_t)l * D_, x_bf);
        gemm(x_bf, wf1 + (size_t)l * 4096 * 1024, ff_b1 + (size_t)l * F_,
             nullptr, nullptr, ffh, MT, D_, F_, 1, 1);               // 2048 blk
        // FFN-down: SK=4 (2048 blk, 4 blk/CU) if extra region fits, else SK=2
        if (ES4) {
            gemm(ffh, wf2 + (size_t)l * 1024 * 4096, nullptr,
                 part_loop, part_extra, nullptr, MT, F_, D_, 0, 4);
            add_ln_kernel<<<MT, 256, 0, stream>>>(x, part_loop, part_extra, 4,
                 (size_t)MT * D_, ff_b2 + (size_t)l * D_,
                 ln3_g + (size_t)l * D_, ln3_b + (size_t)l * D_, x_bf);
        } else {
            gemm(ffh, wf2 + (size_t)l * 1024 * 4096, nullptr,
                 part_loop, nullptr, nullptr, MT, F_, D_, 0, 2);
            add_ln_kernel<<<MT, 256, 0, stream>>>(x, part_loop, part_loop, 2,
                 (size_t)MT * D_, ff_b2 + (size_t)l * D_,
                 ln3_g + (size_t)l * D_, ln3_b + (size_t)l * D_, x_bf);
        }
    }

    // ---- final norm + output MLP (shared_rg free again; exact 2*MT*D fit) ----
    add_ln_kernel<<<MT, 256, 0, stream>>>(x, nullptr, nullptr, 0, 0, nullptr,
                                          lnf_g, lnf_b, x_bf);
    gemm_red(x_bf, wo1, out_b1, nullptr, h1b, MT, D_, D_, 1, 2, part_post);
    gemm_red(h1b,  wo2, out_b2, nullptr, h2b, MT, D_, D_, 1, 2, part_post);
    gemm_red(h2b,  wo3, out_b3, (float*)d_out, nullptr, MT, D_, 16, 0, 8, part_post);
}

// Round 12
// 1427.456 us; speedup vs baseline: 1.0408x; 1.0351x over previous
//
#include <hip/hip_runtime.h>
#include <hip/hip_bf16.h>
#include <cstdint>
#include <cstddef>

#define B_  4
#define S_  512
#define T_  1023
#define D_  1024
#define H_  16
#define DH_ 64
#define F_  4096
#define L_  4

typedef float f32x4 __attribute__((ext_vector_type(4)));
typedef __bf16 bf16x8 __attribute__((ext_vector_type(8)));

__device__ inline unsigned pack_bf2(float a, float b) {
    union { __hip_bfloat16 h; unsigned short u; } ua, ub;
    ua.h = __float2bfloat16(a); ub.h = __float2bfloat16(b);
    return (unsigned)ua.u | ((unsigned)ub.u << 16);
}

// ---------------------------------------------------------------------------
// bf16 MFMA GEMM, 128x64 tile (wave = 64x32, acc[4][2]) + split-K via
// blockIdx.z (fp32 partials at Cf + z*M*N when ksplit > 1).
// K-loop: depth-2 counted-vmcnt pipeline: 3 LDS buffer pairs rotated by
// pointer swap, raw s_barrier, vmcnt(3) mid-loop (never 0) so the next
// tile's loads stay in flight ACROSS the barrier. (Round-9 proven optimum.)
// ---------------------------------------------------------------------------
__global__ __launch_bounds__(256) void gemm_bf16(
    const __hip_bfloat16* __restrict__ A, const __hip_bfloat16* __restrict__ Wt,
    const float* __restrict__ bias,
    float* __restrict__ Cf, __hip_bfloat16* __restrict__ Cb,
    int M, int K, int N, int relu, int ksplit)
{
    __shared__ __align__(16) __hip_bfloat16 AsmB[3][128 * 32];   // 24 KB
    __shared__ __align__(16) __hip_bfloat16 BsmB[3][64 * 32];    // 12 KB
    const int tid  = threadIdx.x;
    const int lane = tid & 63;
    const int w    = tid >> 6;
    const int wr   = w >> 1, wc = w & 1;          // wave grid 2x2: 64 rows x 32 cols
    const int l15  = lane & 15, l4 = lane >> 4;

    // bijective XCD-aware swizzle (m204) on the x-y plane
    const int gx = gridDim.x;
    int bid = blockIdx.y * gx + blockIdx.x;
    {
        const int nwg = gx * gridDim.y;
        const int q = nwg >> 3, r = nwg & 7;
        const int xcd = bid & 7, idx = bid >> 3;
        bid = (xcd < r ? xcd * (q + 1) : r * (q + 1) + (xcd - r) * q) + idx;
    }
    const int row0 = (bid / gx) * 128;
    const int col0 = (bid % gx) * 64;
    const int z = blockIdx.z;
    const int kslice = K / ksplit;
    const int kbase = z * kslice;

    f32x4 acc[4][2] = {};

    auto stage = [&](__hip_bfloat16* As, __hip_bfloat16* Bs, int kt) {
        auto* ldsA = (__attribute__((address_space(3))) char*)As;
        auto* ldsB = (__attribute__((address_space(3))) char*)Bs;
        #pragma unroll
        for (int half = 0; half < 2; ++half) {     // A tile: 128x32 = 512 chunks
            const int ch = half * 256 + tid;
            const int r  = ch >> 2;
            const int c  = (ch & 3) * 8;
            int gr = row0 + r; gr = (gr < M) ? gr : (M - 1);
            const __hip_bfloat16* srcA = A + (size_t)gr * K + kt + c;
            __builtin_amdgcn_global_load_lds(
                (const __attribute__((address_space(1))) unsigned*)srcA,
                (__attribute__((address_space(3))) unsigned*)(ldsA + (size_t)ch * 16),
                16, 0, 0);
        }
        {                                          // B tile: 64x32 = 256 chunks
            const int r = tid >> 2;
            const int c = (tid & 3) * 8;
            int gc = col0 + r; gc = (gc < N) ? gc : (N - 1);
            const __hip_bfloat16* srcB = Wt + (size_t)gc * K + kt + c;
            __builtin_amdgcn_global_load_lds(
                (const __attribute__((address_space(1))) unsigned*)srcB,
                (__attribute__((address_space(3))) unsigned*)(ldsB + (size_t)tid * 16),
                16, 0, 0);
        }
    };
    auto compute = [&](const __hip_bfloat16* As, const __hip_bfloat16* Bs) {
        const __hip_bfloat16* ab = As + (size_t)(wr * 64 + l15) * 32 + l4 * 8;
        const __hip_bfloat16* bb = Bs + (size_t)(wc * 32 + l15) * 32 + l4 * 8;
        bf16x8 af[4], bf[2];
        #pragma unroll
        for (int mi = 0; mi < 4; ++mi) af[mi] = *(const bf16x8*)(ab + mi * 16 * 32);
        #pragma unroll
        for (int nj = 0; nj < 2; ++nj) bf[nj] = *(const bf16x8*)(bb + nj * 16 * 32);
        #pragma unroll
        for (int mi = 0; mi < 4; ++mi)
            #pragma unroll
            for (int nj = 0; nj < 2; ++nj)
                acc[mi][nj] = __builtin_amdgcn_mfma_f32_16x16x32_bf16(
                    af[mi], bf[nj], acc[mi][nj], 0, 0, 0);
    };

    const int nk = kslice >> 5;
    __hip_bfloat16 *A0 = AsmB[0], *A1 = AsmB[1], *A2 = AsmB[2];
    __hip_bfloat16 *B0 = BsmB[0], *B1 = BsmB[1], *B2 = BsmB[2];
    stage(A0, B0, kbase);                       // 3 loads/thread
    if (nk > 1) stage(A1, B1, kbase + 32);      // +3 -> 6 outstanding
    for (int t = 0; t < nk; ++t) {
        if (t + 1 < nk) {
            asm volatile("s_waitcnt vmcnt(3)" ::: "memory");   // tile t done; t+1 in flight
        } else {
            asm volatile("s_waitcnt vmcnt(0)" ::: "memory");   // last tile
        }
        __builtin_amdgcn_s_barrier();           // raw: no vmcnt drain
        if (t + 2 < nk) stage(A2, B2, kbase + (t + 2) * 32);   // back to 6 in flight
        compute(A0, B0);
        __hip_bfloat16* ta = A0; A0 = A1; A1 = A2; A2 = ta;
        __hip_bfloat16* tb = B0; B0 = B1; B1 = B2; B2 = tb;
    }

    // epilogue: C/D layout col = lane&15, row = (lane>>4)*4 + i  [m89-verified]
    if (ksplit > 1) {
        float* dst = Cf + (size_t)z * M * N;
        #pragma unroll
        for (int nj = 0; nj < 2; ++nj) {
            const int c = col0 + wc * 32 + nj * 16 + l15;
            if (c >= N) continue;
            #pragma unroll
            for (int mi = 0; mi < 4; ++mi)
                #pragma unroll
                for (int i = 0; i < 4; ++i) {
                    const int r = row0 + wr * 64 + mi * 16 + l4 * 4 + i;
                    if (r < M) dst[(size_t)r * N + c] = acc[mi][nj][i];
                }
        }
    } else {
        #pragma unroll
        for (int nj = 0; nj < 2; ++nj) {
            const int c = col0 + wc * 32 + nj * 16 + l15;
            if (c >= N) continue;
            const float bv = bias[c];
            #pragma unroll
            for (int mi = 0; mi < 4; ++mi)
                #pragma unroll
                for (int i = 0; i < 4; ++i) {
                    const int r = row0 + wr * 64 + mi * 16 + l4 * 4 + i;
                    if (r >= M) continue;
                    float v = acc[mi][nj][i] + bv;
                    if (relu) v = fmaxf(v, 0.f);
                    if (Cf) Cf[(size_t)r * N + c] = v;
                    if (Cb) Cb[(size_t)r * N + c] = __float2bfloat16(v);
                }
        }
    }
}

// ---------------------------------------------------------------------------
// Split-K reduction: out = op(sum_s part[s] + bias). float4-vectorized.
// Requires N power of 2.
// ---------------------------------------------------------------------------
__global__ __launch_bounds__(256) void reduce_split(
    const float* __restrict__ part, int SK, size_t pstride,
    const float* __restrict__ bias, int N, int total4, int relu,
    float* __restrict__ outf, __hip_bfloat16* __restrict__ outb)
{
    const int idx4 = blockIdx.x * 256 + threadIdx.x;
    if (idx4 >= total4) return;
    const size_t base = (size_t)idx4 * 4;
    const int c = (int)(base & (size_t)(N - 1));
    float4 v = *(const float4*)(part + base);
    for (int s = 1; s < SK; ++s) {
        const float4 p = *(const float4*)(part + (size_t)s * pstride + base);
        v.x += p.x; v.y += p.y; v.z += p.z; v.w += p.w;
    }
    const float4 bv = *(const float4*)(bias + c);
    v.x += bv.x; v.y += bv.y; v.z += bv.z; v.w += bv.w;
    if (relu) {
        v.x = fmaxf(v.x, 0.f); v.y = fmaxf(v.y, 0.f);
        v.z = fmaxf(v.z, 0.f); v.w = fmaxf(v.w, 0.f);
    }
    if (outf) *(float4*)(outf + base) = v;
    if (outb) {
        __hip_bfloat16* o = outb + base;
        o[0] = __float2bfloat16(v.x); o[1] = __float2bfloat16(v.y);
        o[2] = __float2bfloat16(v.z); o[3] = __float2bfloat16(v.w);
    }
}

// ---------------------------------------------------------------------------
// Weight transpose+convert (unchanged).
// ---------------------------------------------------------------------------
__global__ __launch_bounds__(256) void transpose_w(
    const float* __restrict__ W, __hip_bfloat16* __restrict__ Wt,
    int K, int N, int Kpad)
{
    __shared__ float t[32][33];
    W  += (size_t)blockIdx.z * K * N;
    Wt += (size_t)blockIdx.z * N * Kpad;
    const int n0 = blockIdx.x * 32, k0 = blockIdx.y * 32;
    const int tx = threadIdx.x & 31, ty = threadIdx.x >> 5;
    #pragma unroll
    for (int i = 0; i < 4; ++i) {
        int r = ty + i * 8;
        int k = k0 + r, n = n0 + tx;
        t[r][tx] = (k < K && n < N) ? W[(size_t)k * N + n] : 0.f;
    }
    __syncthreads();
    #pragma unroll
    for (int i = 0; i < 4; ++i) {
        int r = ty + i * 8;
        int n = n0 + r, k = k0 + tx;
        if (n < N && k < Kpad) Wt[(size_t)n * Kpad + k] = __float2bfloat16(t[tx][r]);
    }
}

__global__ __launch_bounds__(256) void convert_pad(
    const float* __restrict__ in, __hip_bfloat16* __restrict__ out,
    int M, int Kin, int Kout)
{
    int idx = blockIdx.x * 256 + threadIdx.x;
    if (idx >= M * Kout) return;
    int r = idx / Kout, c = idx - r * Kout;
    out[idx] = __float2bfloat16(c < Kin ? in[(size_t)r * Kin + c] : 0.f);
}

// ---------------------------------------------------------------------------
// V transpose (unchanged).
// ---------------------------------------------------------------------------
__global__ __launch_bounds__(256) void v_transpose(
    const __hip_bfloat16* __restrict__ qkvb, __hip_bfloat16* __restrict__ vt)
{
    __shared__ __hip_bfloat16 tile[32][33];
    const int b  = blockIdx.z;
    const int c0 = blockIdx.x * 32;
    const int t0 = blockIdx.y * 32;
    const int tx = threadIdx.x & 31, ty = threadIdx.x >> 5;
    const __hip_bfloat16 z = __float2bfloat16(0.f);
    #pragma unroll
    for (int i = 0; i < 4; ++i) {
        const int tl = ty + i * 8;
        const int t = t0 + tl;
        tile[tl][tx] = (t < T_) ? qkvb[(size_t)(b * T_ + t) * 3072 + 2048 + c0 + tx] : z;
    }
    __syncthreads();
    #pragma unroll
    for (int i = 0; i < 4; ++i) {
        const int cl = ty + i * 8;
        const int t = t0 + tx;
        vt[((size_t)(b * 1024 + c0 + cl)) * 1024 + t] = (t < T_) ? tile[tx][cl] : z;
    }
}

// ---------------------------------------------------------------------------
// MFMA flash attention (unchanged from round 3 — proven).
// ---------------------------------------------------------------------------
__global__ __launch_bounds__(256) void attn_mfma(
    const __hip_bfloat16* __restrict__ qkvb,
    const __hip_bfloat16* __restrict__ vt,
    __hip_bfloat16* __restrict__ out)
{
    __shared__ __align__(16) __hip_bfloat16 Qs[2][128][32];
    __shared__ __align__(16) __hip_bfloat16 Ks[2][64][32];
    __shared__ __align__(16) __hip_bfloat16 Vs[2][64][32];
    __shared__ __align__(16) __hip_bfloat16 Ps[4][2][32][32];
    __shared__ float Lw[4][2][16];

    const int bh = blockIdx.x;
    const int b = bh >> 4, h = bh & 15;
    const int q0 = blockIdx.y * 128;
    const int tid = threadIdx.x;
    const int w = tid >> 6, lane = tid & 63;
    const int l15 = lane & 15, l4 = lane >> 4;
    const size_t ldq = 3 * D_;

    {
        #pragma unroll
        for (int c = 0; c < 2; ++c)
            #pragma unroll
            for (int it = 0; it < 2; ++it) {
                const int ch = it * 256 + tid;
                const int r = ch >> 2, cp = ch & 3;
                int qr = q0 + r; qr = (qr < T_) ? qr : (T_ - 1);
                const __hip_bfloat16* src = qkvb + (size_t)(b * T_ + qr) * ldq + h * 64 + c * 32 + cp * 8;
                __builtin_amdgcn_global_load_lds(
                    (const __attribute__((address_space(1))) unsigned*)src,
                    (__attribute__((address_space(3))) unsigned*)((__attribute__((address_space(3))) char*)&Qs[c][0][0] + ch * 16),
                    16, 0, 0);
            }
    }
    __syncthreads();
    bf16x8 qreg[2][2];
    #pragma unroll
    for (int qf = 0; qf < 2; ++qf)
        #pragma unroll
        for (int c = 0; c < 2; ++c)
            qreg[qf][c] = *(const bf16x8*)&Qs[c][w * 32 + qf * 16 + l15][l4 * 8];

    f32x4 of[2][4] = {};
    float lp[2] = {0.f, 0.f};
    const int qmaxw = q0 + w * 32 + 31;
    const int kend = (q0 + 128 < T_) ? (q0 + 128) : T_;

    for (int k0 = 0; k0 < kend; k0 += 64) {
        __syncthreads();
        {
            const int r = tid >> 2, cp = tid & 3;
            #pragma unroll
            for (int c = 0; c < 2; ++c) {
                int kr = k0 + r; kr = (kr < T_) ? kr : (T_ - 1);
                const __hip_bfloat16* srcK = qkvb + (size_t)(b * T_ + kr) * ldq + D_ + h * 64 + c * 32 + cp * 8;
                __builtin_amdgcn_global_load_lds(
                    (const __attribute__((address_space(1))) unsigned*)srcK,
                    (__attribute__((address_space(3))) unsigned*)((__attribute__((address_space(3))) char*)&Ks[c][0][0] + tid * 16),
                    16, 0, 0);
                const __hip_bfloat16* srcV = vt + ((size_t)(b * 1024 + h * 64 + r)) * 1024 + k0 + c * 32 + cp * 8;
                __builtin_amdgcn_global_load_lds(
                    (const __attribute__((address_space(1))) unsigned*)srcV,
                    (__attribute__((address_space(3))) unsigned*)((__attribute__((address_space(3))) char*)&Vs[c][0][0] + tid * 16),
                    16, 0, 0);
            }
        }
        __syncthreads();

        if (k0 <= qmaxw) {
            f32x4 sf[4][2] = {};
            #pragma unroll
            for (int c = 0; c < 2; ++c) {
                bf16x8 kf[4];
                #pragma unroll
                for (int kfr = 0; kfr < 4; ++kfr)
                    kf[kfr] = *(const bf16x8*)&Ks[c][kfr * 16 + l15][l4 * 8];
                #pragma unroll
                for (int kfr = 0; kfr < 4; ++kfr)
                    #pragma unroll
                    for (int qf = 0; qf < 2; ++qf)
                        sf[kfr][qf] = __builtin_amdgcn_mfma_f32_16x16x32_bf16(
                            kf[kfr], qreg[qf][c], sf[kfr][qf], 0, 0, 0);
            }
            const bool needmask = (k0 + 63) > (q0 + w * 32);
            #pragma unroll
            for (int kfr = 0; kfr < 4; ++kfr) {
                #pragma unroll
                for (int qf = 0; qf < 2; ++qf) {
                    const int qg = q0 + w * 32 + qf * 16 + l15;
                    float p[4];
                    #pragma unroll
                    for (int i = 0; i < 4; ++i) {
                        const int kg = k0 + kfr * 16 + l4 * 4 + i;
                        float pv = __expf(sf[kfr][qf][i] * 0.125f);
                        if (needmask && kg > qg) pv = 0.f;
                        p[i] = pv;
                        lp[qf] += pv;
                    }
                    unsigned* dst = (unsigned*)&Ps[w][kfr >> 1][qf * 16 + l15][(kfr & 1) * 16 + l4 * 4];
                    dst[0] = pack_bf2(p[0], p[1]);
                    dst[1] = pack_bf2(p[2], p[3]);
                }
            }
            #pragma unroll
            for (int kc = 0; kc < 2; ++kc) {
                bf16x8 pa[2], vb[4];
                #pragma unroll
                for (int qf = 0; qf < 2; ++qf)
                    pa[qf] = *(const bf16x8*)&Ps[w][kc][qf * 16 + l15][l4 * 8];
                #pragma unroll
                for (int df = 0; df < 4; ++df)
                    vb[df] = *(const bf16x8*)&Vs[kc][df * 16 + l15][l4 * 8];
                #pragma unroll
                for (int qf = 0; qf < 2; ++qf)
                    #pragma unroll
                    for (int df = 0; df < 4; ++df)
                        of[qf][df] = __builtin_amdgcn_mfma_f32_16x16x32_bf16(
                            pa[qf], vb[df], of[qf][df], 0, 0, 0);
            }
        }
    }

    #pragma unroll
    for (int qf = 0; qf < 2; ++qf) {
        float v = lp[qf];
        v += __shfl_xor(v, 16);
        v += __shfl_xor(v, 32);
        if (l4 == 0) Lw[w][qf][l15] = v;
    }
    __syncthreads();
    #pragma unroll
    for (int qf = 0; qf < 2; ++qf) {
        float inv[4];
        #pragma unroll
        for (int i = 0; i < 4; ++i) inv[i] = 1.f / Lw[w][qf][l4 * 4 + i];
        #pragma unroll
        for (int df = 0; df < 4; ++df) {
            #pragma unroll
            for (int i = 0; i < 4; ++i) {
                const int qg = q0 + w * 32 + qf * 16 + l4 * 4 + i;
                if (qg < T_)
                    out[(size_t)(b * T_ + qg) * D_ + h * 64 + df * 16 + l15] =
                        __float2bfloat16(of[qf][df][i] * inv[i]);
            }
        }
    }
}

// ---------------------------------------------------------------------------
// LN helpers. p = residual: SK partials at stride pstride + optional bias.
// ---------------------------------------------------------------------------
__device__ inline void block_ln_stats(float4 v, float& mu, float& inv,
                                      float* ws, float* ws2, float* mu_s, float* inv_s)
{
    const int tid = threadIdx.x;
    float s  = v.x + v.y + v.z + v.w;
    float s2 = v.x * v.x + v.y * v.y + v.z * v.z + v.w * v.w;
    #pragma unroll
    for (int off = 32; off; off >>= 1) {
        s  += __shfl_down(s, off);
        s2 += __shfl_down(s2, off);
    }
    const int wid = tid >> 6;
    if ((tid & 63) == 0) { ws[wid] = s; ws2[wid] = s2; }
    __syncthreads();
    if (tid == 0) {
        float S  = ws[0] + ws[1] + ws[2] + ws[3];
        float S2 = ws2[0] + ws2[1] + ws2[2] + ws2[3];
        float m = S * (1.f / (float)D_);
        float var = S2 * (1.f / (float)D_) - m * m;
        *mu_s = m;
        *inv_s = rsqrtf(var + 1e-5f);
    }
    __syncthreads();
    mu = *mu_s; inv = *inv_s;
}

__global__ __launch_bounds__(256) void add_ln_kernel(
    float* __restrict__ x, const float* __restrict__ p, int SK, size_t pstride,
    const float* __restrict__ pbias,
    const float* __restrict__ g, const float* __restrict__ beta,
    __hip_bfloat16* __restrict__ xb)
{
    const int row = blockIdx.x;
    const int tid = threadIdx.x;
    __shared__ float ws[4], ws2[4], mu_s, inv_s;
    float4* xr = reinterpret_cast<float4*>(x + (size_t)row * D_);
    float4 v = xr[tid];
    if (p) {
        for (int s = 0; s < SK; ++s) {
            const float4 wv = reinterpret_cast<const float4*>(
                p + (size_t)s * pstride + (size_t)row * D_)[tid];
            v.x += wv.x; v.y += wv.y; v.z += wv.z; v.w += wv.w;
        }
        if (pbias) {
            const float4 bv = reinterpret_cast<const float4*>(pbias)[tid];
            v.x += bv.x; v.y += bv.y; v.z += bv.z; v.w += bv.w;
        }
    }
    float mu, inv;
    block_ln_stats(v, mu, inv, ws, ws2, &mu_s, &inv_s);
    const float4 gg = reinterpret_cast<const float4*>(g)[tid];
    const float4 bb = reinterpret_cast<const float4*>(beta)[tid];
    float4 o;
    o.x = (v.x - mu) * inv * gg.x + bb.x;
    o.y = (v.y - mu) * inv * gg.y + bb.y;
    o.z = (v.z - mu) * inv * gg.z + bb.z;
    o.w = (v.w - mu) * inv * gg.w + bb.w;
    xr[tid] = o;
    if (xb) {
        __hip_bfloat16* xo = xb + (size_t)row * D_ + tid * 4;
        xo[0] = __float2bfloat16(o.x);
        xo[1] = __float2bfloat16(o.y);
        xo[2] = __float2bfloat16(o.z);
        xo[3] = __float2bfloat16(o.w);
    }
}

__global__ __launch_bounds__(256) void add_ln2_kernel(
    float* __restrict__ x, const float* __restrict__ p, int SK, size_t pstride,
    const float* __restrict__ pbias, const float* __restrict__ cav,
    const float* __restrict__ g1, const float* __restrict__ b1,
    const float* __restrict__ g2, const float* __restrict__ b2,
    __hip_bfloat16* __restrict__ xb)
{
    const int row = blockIdx.x;
    const int tid = threadIdx.x;
    __shared__ float ws[4], ws2[4], mu_s, inv_s;
    float4* xr = reinterpret_cast<float4*>(x + (size_t)row * D_);
    float4 v = xr[tid];
    for (int s = 0; s < SK; ++s) {
        const float4 wv = reinterpret_cast<const float4*>(
            p + (size_t)s * pstride + (size_t)row * D_)[tid];
        v.x += wv.x; v.y += wv.y; v.z += wv.z; v.w += wv.w;
    }
    if (pbias) {
        const float4 bv = reinterpret_cast<const float4*>(pbias)[tid];
        v.x += bv.x; v.y += bv.y; v.z += bv.z; v.w += bv.w;
    }
    float mu, inv;
    block_ln_stats(v, mu, inv, ws, ws2, &mu_s, &inv_s);
    const float4 g1v = reinterpret_cast<const float4*>(g1)[tid];
    const float4 b1v = reinterpret_cast<const float4*>(b1)[tid];
    const float4 cv  = reinterpret_cast<const float4*>(cav)[tid];
    float4 u;
    u.x = (v.x - mu) * inv * g1v.x + b1v.x + cv.x;
    u.y = (v.y - mu) * inv * g1v.y + b1v.y + cv.y;
    u.z = (v.z - mu) * inv * g1v.z + b1v.z + cv.z;
    u.w = (v.w - mu) * inv * g1v.w + b1v.w + cv.w;
    __syncthreads();
    float mu2, inv2;
    block_ln_stats(u, mu2, inv2, ws, ws2, &mu_s, &inv_s);
    const float4 g2v = reinterpret_cast<const float4*>(g2)[tid];
    const float4 b2v = reinterpret_cast<const float4*>(b2)[tid];
    float4 o;
    o.x = (u.x - mu2) * inv2 * g2v.x + b2v.x;
    o.y = (u.y - mu2) * inv2 * g2v.y + b2v.y;
    o.z = (u.z - mu2) * inv2 * g2v.z + b2v.z;
    o.w = (u.w - mu2) * inv2 * g2v.w + b2v.w;
    xr[tid] = o;
    __hip_bfloat16* xo = xb + (size_t)row * D_ + tid * 4;
    xo[0] = __float2bfloat16(o.x);
    xo[1] = __float2bfloat16(o.y);
    xo[2] = __float2bfloat16(o.z);
    xo[3] = __float2bfloat16(o.w);
}

__global__ __launch_bounds__(256) void interleave_pe_kernel(
    const float* __restrict__ obs_tok, const float* __restrict__ act_tok,
    float* __restrict__ x, __hip_bfloat16* __restrict__ xb)
{
    const int row = blockIdx.x;
    const int b = row / T_;
    const int t = row - b * T_;
    const float* src = (t & 1)
        ? (act_tok + (size_t)(b * (S_ - 1) + (t >> 1)) * D_)
        : (obs_tok + (size_t)(b * S_ + (t >> 1)) * D_);
    float* xr = x + (size_t)row * D_;
    __hip_bfloat16* xo = xb + (size_t)row * D_;
    #pragma unroll
    for (int k = 0; k < 4; ++k) {
        int d = threadIdx.x + k * 256;
        float ang = (float)b * expf(-(float)(d & ~1) * (9.210340371976184f / 1024.0f));
        float pe = (d & 1) ? cosf(ang) : sinf(ang);
        float v = src[d] + pe;
        xr[d] = v;
        xo[d] = __float2bfloat16(v);
    }
}

__global__ __launch_bounds__(256) void ca_part_kernel(
    const float* __restrict__ ca_b_in, const float* __restrict__ ca_w_out,
    float* __restrict__ part)
{
    const int idx = blockIdx.x * 256 + threadIdx.x;
    const int ks = blockIdx.y;
    const int l = idx >> 10, d = idx & 1023;
    const float* bv = ca_b_in + (size_t)l * 3 * D_ + 2 * D_ + ks * 64;
    const float* wp = ca_w_out + (size_t)l * D_ * D_ + (size_t)(ks * 64) * D_ + d;
    float s = 0.f;
    #pragma unroll 8
    for (int k = 0; k < 64; ++k) s = fmaf(bv[k], wp[(size_t)k * D_], s);
    part[(size_t)ks * (L_ * D_) + idx] = s;
}

__global__ __launch_bounds__(256) void ca_reduce_kernel(
    const float* __restrict__ part, const float* __restrict__ ca_b_out,
    float* __restrict__ out)
{
    const int idx = blockIdx.x * 256 + threadIdx.x;
    float s = ca_b_out[idx];
    #pragma unroll
    for (int ks = 0; ks < 16; ++ks) s += part[(size_t)ks * (L_ * D_) + idx];
    out[idx] = s;
}

// ---------------------------------------------------------------------------
extern "C" void kernel_launch(void* const* d_in, const int* in_sizes, int n_in,
                              void* d_out, int out_size, void* d_ws, size_t ws_size,
                              hipStream_t stream)
{
    const float* obs     = (const float*)d_in[0];
    const float* act     = (const float*)d_in[1];
    const float* in_w1   = (const float*)d_in[2];
    const float* in_b1   = (const float*)d_in[3];
    const float* in_w2   = (const float*)d_in[4];
    const float* in_b2   = (const float*)d_in[5];
    const float* in_w3   = (const float*)d_in[6];
    const float* in_b3   = (const float*)d_in[7];
    const float* act_w1  = (const float*)d_in[8];
    const float* act_b1  = (const float*)d_in[9];
    const float* act_w2  = (const float*)d_in[10];
    const float* act_b2  = (const float*)d_in[11];
    const float* act_w3  = (const float*)d_in[12];
    const float* act_b3  = (const float*)d_in[13];
    const float* out_w1  = (const float*)d_in[14];
    const float* out_b1  = (const float*)d_in[15];
    const float* out_w2  = (const float*)d_in[16];
    const float* out_b2  = (const float*)d_in[17];
    const float* out_w3  = (const float*)d_in[18];
    const float* out_b3  = (const float*)d_in[19];
    const float* sa_w_in = (const float*)d_in[20];
    const float* sa_b_in = (const float*)d_in[21];
    const float* sa_w_out= (const float*)d_in[22];
    const float* sa_b_out= (const float*)d_in[23];
    const float* ca_b_in = (const float*)d_in[25];
    const float* ca_w_out= (const float*)d_in[26];
    const float* ca_b_out= (const float*)d_in[27];
    const float* ff_w1   = (const float*)d_in[28];
    const float* ff_b1   = (const float*)d_in[29];
    const float* ff_w2   = (const float*)d_in[30];
    const float* ff_b2   = (const float*)d_in[31];
    const float* ln1_g   = (const float*)d_in[32];
    const float* ln1_b   = (const float*)d_in[33];
    const float* ln2_g   = (const float*)d_in[34];
    const float* ln2_b   = (const float*)d_in[35];
    const float* ln3_g   = (const float*)d_in[36];
    const float* ln3_b   = (const float*)d_in[37];
    const float* lnf_g   = (const float*)d_in[38];
    const float* lnf_b   = (const float*)d_in[39];

    const int MT = B_ * T_;          // 4092
    const int Mo = B_ * S_;          // 2048
    const int Ma = B_ * (S_ - 1);    // 2044

    char* base = (char*)d_ws;
    size_t used = 0;
    auto alloc = [&](size_t bytes) -> char* {
        char* r = base + used;
        used += (bytes + 255) & ~(size_t)255;
        return r;
    };
    typedef __hip_bfloat16 bf;
    bf* wi1  = (bf*)alloc((size_t)1024 * 64 * 2);
    bf* wi2  = (bf*)alloc((size_t)1024 * 1024 * 2);
    bf* wi3  = (bf*)alloc((size_t)1024 * 1024 * 2);
    bf* wa1  = (bf*)alloc((size_t)1024 * 32 * 2);
    bf* wa2  = (bf*)alloc((size_t)1024 * 1024 * 2);
    bf* wa3  = (bf*)alloc((size_t)1024 * 1024 * 2);
    bf* wo1  = (bf*)alloc((size_t)1024 * 1024 * 2);
    bf* wo2  = (bf*)alloc((size_t)1024 * 1024 * 2);
    bf* wo3  = (bf*)alloc((size_t)16 * 1024 * 2);
    bf* wsin = (bf*)alloc((size_t)L_ * 3072 * 1024 * 2);
    bf* wsout= (bf*)alloc((size_t)L_ * 1024 * 1024 * 2);
    bf* wf1  = (bf*)alloc((size_t)L_ * 4096 * 1024 * 2);
    bf* wf2  = (bf*)alloc((size_t)L_ * 1024 * 4096 * 2);
    bf* obs_bf = (bf*)alloc((size_t)Mo * 64 * 2);
    bf* act_bf = (bf*)alloc((size_t)Ma * 32 * 2);
    bf* x_bf   = (bf*)alloc((size_t)MT * D_ * 2);
    bf* attnb  = (bf*)alloc((size_t)MT * D_ * 2);
    bf* h1b    = (bf*)alloc((size_t)MT * D_ * 2);
    bf* h2b    = (bf*)alloc((size_t)MT * D_ * 2);
    char* shared_rg = alloc((size_t)MT * F_ * 2);   // qkvb | ffh | out-MLP partials
    bf* qkvb = (bf*)shared_rg;
    bf* ffh  = (bf*)shared_rg;
    bf* vt   = (bf*)alloc((size_t)B_ * 1024 * 1024 * 2);
    float* x       = (float*)alloc((size_t)MT * D_ * 4);
    // [y, obs_tok, act_tok] = contiguous 33,521,664 B = exactly 2*MT*D_*4:
    // reused as in-loop split-K partial buffer (all three dead in the loop).
    float* y       = (float*)alloc((size_t)MT * D_ * 4);
    float* obs_tok = (float*)alloc((size_t)Mo * D_ * 4);
    float* act_tok = (float*)alloc((size_t)Ma * D_ * 4);
    float* ca      = (float*)alloc((size_t)L_ * D_ * 4);
    float* ca_part = (float*)alloc((size_t)16 * L_ * D_ * 4);
    if (used > ws_size) return;
    float* part_loop = y;                 // 2*MT*D fp32 (SK<=2, in decoder loop)
    float* part_pre  = (float*)shared_rg; // pre-loop SK<=4 on Mo (spans shared_rg+vt)
    float* part_post = (float*)shared_rg; // post-loop, 2*MT*D exact fit

    auto tw = [&](const float* W, bf* Wt, int K, int N, int Kpad, int batch) {
        dim3 g((N + 31) / 32, (Kpad + 31) / 32, batch);
        transpose_w<<<g, 256, 0, stream>>>(W, Wt, K, N, Kpad);
    };
    auto gemm = [&](const bf* A, const bf* Wt, const float* bias,
                    float* Cf, bf* Cb, int M, int K, int N, int relu, int sk) {
        dim3 g((N + 63) / 64, (M + 127) / 128, sk);
        gemm_bf16<<<g, 256, 0, stream>>>(A, Wt, bias, Cf, Cb, M, K, N, relu, sk);
    };
    auto gemm_red = [&](const bf* A, const bf* Wt, const float* bias,
                        float* Cf, bf* Cb, int M, int K, int N, int relu, int sk,
                        float* part) {
        if (sk <= 1) { gemm(A, Wt, bias, Cf, Cb, M, K, N, relu, 1); return; }
        gemm(A, Wt, nullptr, part, nullptr, M, K, N, 0, sk);
        const size_t MN = (size_t)M * N;
        const int total4 = (int)(MN / 4);
        reduce_split<<<(total4 + 255) / 256, 256, 0, stream>>>(
            part, sk, MN, bias, N, total4, relu, Cf, Cb);
    };

    tw(in_w1,  wi1, 64,   1024, 64,   1);
    tw(in_w2,  wi2, 1024, 1024, 1024, 1);
    tw(in_w3,  wi3, 1024, 1024, 1024, 1);
    tw(act_w1, wa1, 16,   1024, 32,   1);
    tw(act_w2, wa2, 1024, 1024, 1024, 1);
    tw(act_w3, wa3, 1024, 1024, 1024, 1);
    tw(out_w1, wo1, 1024, 1024, 1024, 1);
    tw(out_w2, wo2, 1024, 1024, 1024, 1);
    tw(out_w3, wo3, 1024, 16,   1024, 1);
    tw(sa_w_in,  wsin,  1024, 3072, 1024, L_);
    tw(sa_w_out, wsout, 1024, 1024, 1024, L_);
    tw(ff_w1,    wf1,   1024, 4096, 1024, L_);
    tw(ff_w2,    wf2,   4096, 1024, 4096, L_);

    convert_pad<<<(Mo * 64 + 255) / 256, 256, 0, stream>>>(obs, obs_bf, Mo, 64, 64);
    convert_pad<<<(Ma * 32 + 255) / 256, 256, 0, stream>>>(act, act_bf, Ma, 16, 32);
    ca_part_kernel<<<dim3((L_ * D_) / 256, 16), 256, 0, stream>>>(ca_b_in, ca_w_out, ca_part);
    ca_reduce_kernel<<<(L_ * D_) / 256, 256, 0, stream>>>(ca_part, ca_b_out, ca);

    // ---- input MLPs (mid/out GEMMs SK=4 -> 1024 blocks; partials in shared_rg+vt) ----
    gemm(obs_bf, wi1, in_b1, nullptr, h1b, Mo, 64, D_, 1, 1);
    gemm_red(h1b, wi2, in_b2, nullptr, h2b, Mo, D_, D_, 1, 4, part_pre);
    gemm_red(h2b, wi3, in_b3, obs_tok, nullptr, Mo, D_, D_, 0, 4, part_pre);
    gemm(act_bf, wa1, act_b1, nullptr, h1b, Ma, 32, D_, 1, 1);
    gemm_red(h1b, wa2, act_b2, nullptr, h2b, Ma, D_, D_, 1, 4, part_pre);
    gemm_red(h2b, wa3, act_b3, act_tok, nullptr, Ma, D_, D_, 0, 4, part_pre);

    interleave_pe_kernel<<<MT, 256, 0, stream>>>(obs_tok, act_tok, x, x_bf);
    // obs_tok/act_tok/y now dead -> part_loop region live.

    // ---- decoder layers ----
    for (int l = 0; l < L_; ++l) {
        gemm(x_bf, wsin + (size_t)l * 3072 * 1024, sa_b_in + (size_t)l * 3 * D_,
             nullptr, qkvb, MT, D_, 3 * D_, 0, 1);                // 1536 blk, 6/CU
        v_transpose<<<dim3(32, 32, B_), 256, 0, stream>>>(qkvb, vt);
        attn_mfma<<<dim3(B_ * H_, 8), 256, 0, stream>>>(qkvb, vt, attnb);
        // proj SK=2 -> 1024 blk; partials consumed by fused double-LN
        gemm(attnb, wsout + (size_t)l * 1024 * 1024, nullptr,
             part_loop, nullptr, MT, D_, D_, 0, 2);
        add_ln2_kernel<<<MT, 256, 0, stream>>>(x, part_loop, 2, (size_t)MT * D_,
             sa_b_out + (size_t)l * D_, ca + (size_t)l * D_,
             ln1_g + (size_t)l * D_, ln1_b + (size_t)l * D_,
             ln2_g + (size_t)l * D_, ln2_b + (size_t)l * D_, x_bf);
        gemm(x_bf, wf1 + (size_t)l * 4096 * 1024, ff_b1 + (size_t)l * F_,
             nullptr, ffh, MT, D_, F_, 1, 1);                     // 2048 blk
        // FFN-down SK=2 -> 1024 blk; partials consumed by LN3
        gemm(ffh, wf2 + (size_t)l * 1024 * 4096, nullptr,
             part_loop, nullptr, MT, F_, D_, 0, 2);
        add_ln_kernel<<<MT, 256, 0, stream>>>(x, part_loop, 2, (size_t)MT * D_,
             ff_b2 + (size_t)l * D_,
             ln3_g + (size_t)l * D_, ln3_b + (size_t)l * D_, x_bf);
    }

    // ---- final norm + output MLP (shared_rg free again; exact 2*MT*D fit) ----
    add_ln_kernel<<<MT, 256, 0, stream>>>(x, nullptr, 0, 0, nullptr, lnf_g, lnf_b, x_bf);
    gemm_red(x_bf, wo1, out_b1, nullptr, h1b, MT, D_, D_, 1, 2, part_post);
    gemm_red(h1b,  wo2, out_b2, nullptr, h2b, MT, D_, D_, 1, 2, part_post);
    gemm_red(h2b,  wo3, out_b3, (float*)d_out, nullptr, MT, D_, 16, 0, 8, part_post);
}

// Round 13
// 1361.813 us; speedup vs baseline: 1.0910x; 1.0482x over previous
//
#include <hip/hip_runtime.h>
#include <hip/hip_bf16.h>
#include <cstdint>
#include <cstddef>

#define B_  4
#define S_  512
#define T_  1023
#define D_  1024
#define H_  16
#define DH_ 64
#define F_  4096
#define L_  4

typedef float f32x4 __attribute__((ext_vector_type(4)));
typedef __bf16 bf16x8 __attribute__((ext_vector_type(8)));

__device__ inline unsigned pack_bf2(float a, float b) {
    union { __hip_bfloat16 h; unsigned short u; } ua, ub;
    ua.h = __float2bfloat16(a); ub.h = __float2bfloat16(b);
    return (unsigned)ua.u | ((unsigned)ub.u << 16);
}

// ---------------------------------------------------------------------------
// bf16 MFMA GEMM, 128x64 tile + 3-buffer counted-vmcnt pipeline + split-K.
// (Round-9/12 proven optimum — unchanged.)
// ---------------------------------------------------------------------------
__global__ __launch_bounds__(256) void gemm_bf16(
    const __hip_bfloat16* __restrict__ A, const __hip_bfloat16* __restrict__ Wt,
    const float* __restrict__ bias,
    float* __restrict__ Cf, __hip_bfloat16* __restrict__ Cb,
    int M, int K, int N, int relu, int ksplit)
{
    __shared__ __align__(16) __hip_bfloat16 AsmB[3][128 * 32];
    __shared__ __align__(16) __hip_bfloat16 BsmB[3][64 * 32];
    const int tid  = threadIdx.x;
    const int lane = tid & 63;
    const int w    = tid >> 6;
    const int wr   = w >> 1, wc = w & 1;
    const int l15  = lane & 15, l4 = lane >> 4;

    const int gx = gridDim.x;
    int bid = blockIdx.y * gx + blockIdx.x;
    {
        const int nwg = gx * gridDim.y;
        const int q = nwg >> 3, r = nwg & 7;
        const int xcd = bid & 7, idx = bid >> 3;
        bid = (xcd < r ? xcd * (q + 1) : r * (q + 1) + (xcd - r) * q) + idx;
    }
    const int row0 = (bid / gx) * 128;
    const int col0 = (bid % gx) * 64;
    const int z = blockIdx.z;
    const int kslice = K / ksplit;
    const int kbase = z * kslice;

    f32x4 acc[4][2] = {};

    auto stage = [&](__hip_bfloat16* As, __hip_bfloat16* Bs, int kt) {
        auto* ldsA = (__attribute__((address_space(3))) char*)As;
        auto* ldsB = (__attribute__((address_space(3))) char*)Bs;
        #pragma unroll
        for (int half = 0; half < 2; ++half) {
            const int ch = half * 256 + tid;
            const int r  = ch >> 2;
            const int c  = (ch & 3) * 8;
            int gr = row0 + r; gr = (gr < M) ? gr : (M - 1);
            const __hip_bfloat16* srcA = A + (size_t)gr * K + kt + c;
            __builtin_amdgcn_global_load_lds(
                (const __attribute__((address_space(1))) unsigned*)srcA,
                (__attribute__((address_space(3))) unsigned*)(ldsA + (size_t)ch * 16),
                16, 0, 0);
        }
        {
            const int r = tid >> 2;
            const int c = (tid & 3) * 8;
            int gc = col0 + r; gc = (gc < N) ? gc : (N - 1);
            const __hip_bfloat16* srcB = Wt + (size_t)gc * K + kt + c;
            __builtin_amdgcn_global_load_lds(
                (const __attribute__((address_space(1))) unsigned*)srcB,
                (__attribute__((address_space(3))) unsigned*)(ldsB + (size_t)tid * 16),
                16, 0, 0);
        }
    };
    auto compute = [&](const __hip_bfloat16* As, const __hip_bfloat16* Bs) {
        const __hip_bfloat16* ab = As + (size_t)(wr * 64 + l15) * 32 + l4 * 8;
        const __hip_bfloat16* bb = Bs + (size_t)(wc * 32 + l15) * 32 + l4 * 8;
        bf16x8 af[4], bf[2];
        #pragma unroll
        for (int mi = 0; mi < 4; ++mi) af[mi] = *(const bf16x8*)(ab + mi * 16 * 32);
        #pragma unroll
        for (int nj = 0; nj < 2; ++nj) bf[nj] = *(const bf16x8*)(bb + nj * 16 * 32);
        #pragma unroll
        for (int mi = 0; mi < 4; ++mi)
            #pragma unroll
            for (int nj = 0; nj < 2; ++nj)
                acc[mi][nj] = __builtin_amdgcn_mfma_f32_16x16x32_bf16(
                    af[mi], bf[nj], acc[mi][nj], 0, 0, 0);
    };

    const int nk = kslice >> 5;
    __hip_bfloat16 *A0 = AsmB[0], *A1 = AsmB[1], *A2 = AsmB[2];
    __hip_bfloat16 *B0 = BsmB[0], *B1 = BsmB[1], *B2 = BsmB[2];
    stage(A0, B0, kbase);
    if (nk > 1) stage(A1, B1, kbase + 32);
    for (int t = 0; t < nk; ++t) {
        if (t + 1 < nk) {
            asm volatile("s_waitcnt vmcnt(3)" ::: "memory");
        } else {
            asm volatile("s_waitcnt vmcnt(0)" ::: "memory");
        }
        __builtin_amdgcn_s_barrier();
        if (t + 2 < nk) stage(A2, B2, kbase + (t + 2) * 32);
        compute(A0, B0);
        __hip_bfloat16* ta = A0; A0 = A1; A1 = A2; A2 = ta;
        __hip_bfloat16* tb = B0; B0 = B1; B1 = B2; B2 = tb;
    }

    if (ksplit > 1) {
        float* dst = Cf + (size_t)z * M * N;
        #pragma unroll
        for (int nj = 0; nj < 2; ++nj) {
            const int c = col0 + wc * 32 + nj * 16 + l15;
            if (c >= N) continue;
            #pragma unroll
            for (int mi = 0; mi < 4; ++mi)
                #pragma unroll
                for (int i = 0; i < 4; ++i) {
                    const int r = row0 + wr * 64 + mi * 16 + l4 * 4 + i;
                    if (r < M) dst[(size_t)r * N + c] = acc[mi][nj][i];
                }
        }
    } else {
        #pragma unroll
        for (int nj = 0; nj < 2; ++nj) {
            const int c = col0 + wc * 32 + nj * 16 + l15;
            if (c >= N) continue;
            const float bv = bias[c];
            #pragma unroll
            for (int mi = 0; mi < 4; ++mi)
                #pragma unroll
                for (int i = 0; i < 4; ++i) {
                    const int r = row0 + wr * 64 + mi * 16 + l4 * 4 + i;
                    if (r >= M) continue;
                    float v = acc[mi][nj][i] + bv;
                    if (relu) v = fmaxf(v, 0.f);
                    if (Cf) Cf[(size_t)r * N + c] = v;
                    if (Cb) Cb[(size_t)r * N + c] = __float2bfloat16(v);
                }
        }
    }
}

// ---------------------------------------------------------------------------
// Pair-batched GEMM for the independent obs/act MLP chains. Same proven
// 128x64-tile pipelined core; blockIdx.z = pair*sk + slice. N=1024.
// sk==1: bf16 out (bias+relu). sk==2: fp32 partials at part + (pair*sk+slice)
// * pstride (uniform stride = M0*N, M0 >= M1).
// ---------------------------------------------------------------------------
__global__ __launch_bounds__(256) void gemm_pair(
    const __hip_bfloat16* __restrict__ A0p, const __hip_bfloat16* __restrict__ A1p,
    const __hip_bfloat16* __restrict__ W0p, const __hip_bfloat16* __restrict__ W1p,
    const float* __restrict__ b0p, const float* __restrict__ b1p,
    __hip_bfloat16* __restrict__ Cb0, __hip_bfloat16* __restrict__ Cb1,
    float* __restrict__ part,
    int M0, int M1, int K0, int K1, int N, int relu, int sk)
{
    __shared__ __align__(16) __hip_bfloat16 AsmB[3][128 * 32];
    __shared__ __align__(16) __hip_bfloat16 BsmB[3][64 * 32];
    const int tid  = threadIdx.x;
    const int lane = tid & 63;
    const int w    = tid >> 6;
    const int wr   = w >> 1, wc = w & 1;
    const int l15  = lane & 15, l4 = lane >> 4;

    const int gx = gridDim.x;
    int bid = blockIdx.y * gx + blockIdx.x;
    {
        const int nwg = gx * gridDim.y;
        const int q = nwg >> 3, r = nwg & 7;
        const int xcd = bid & 7, idx = bid >> 3;
        bid = (xcd < r ? xcd * (q + 1) : r * (q + 1) + (xcd - r) * q) + idx;
    }
    const int row0 = (bid / gx) * 128;
    const int col0 = (bid % gx) * 64;

    const int z = blockIdx.z;
    const int pair  = z / sk;
    const int slice = z - pair * sk;
    const __hip_bfloat16* A  = pair ? A1p : A0p;
    const __hip_bfloat16* Wt = pair ? W1p : W0p;
    const float* bias        = pair ? b1p : b0p;
    const int M = pair ? M1 : M0;
    const int K = pair ? K1 : K0;
    const int kslice = K / sk;
    const int kbase = slice * kslice;

    f32x4 acc[4][2] = {};

    auto stage = [&](__hip_bfloat16* As, __hip_bfloat16* Bs, int kt) {
        auto* ldsA = (__attribute__((address_space(3))) char*)As;
        auto* ldsB = (__attribute__((address_space(3))) char*)Bs;
        #pragma unroll
        for (int half = 0; half < 2; ++half) {
            const int ch = half * 256 + tid;
            const int r  = ch >> 2;
            const int c  = (ch & 3) * 8;
            int gr = row0 + r; gr = (gr < M) ? gr : (M - 1);
            const __hip_bfloat16* srcA = A + (size_t)gr * K + kt + c;
            __builtin_amdgcn_global_load_lds(
                (const __attribute__((address_space(1))) unsigned*)srcA,
                (__attribute__((address_space(3))) unsigned*)(ldsA + (size_t)ch * 16),
                16, 0, 0);
        }
        {
            const int r = tid >> 2;
            const int c = (tid & 3) * 8;
            int gc = col0 + r; gc = (gc < N) ? gc : (N - 1);
            const __hip_bfloat16* srcB = Wt + (size_t)gc * K + kt + c;
            __builtin_amdgcn_global_load_lds(
                (const __attribute__((address_space(1))) unsigned*)srcB,
                (__attribute__((address_space(3))) unsigned*)(ldsB + (size_t)tid * 16),
                16, 0, 0);
        }
    };
    auto compute = [&](const __hip_bfloat16* As, const __hip_bfloat16* Bs) {
        const __hip_bfloat16* ab = As + (size_t)(wr * 64 + l15) * 32 + l4 * 8;
        const __hip_bfloat16* bb = Bs + (size_t)(wc * 32 + l15) * 32 + l4 * 8;
        bf16x8 af[4], bf[2];
        #pragma unroll
        for (int mi = 0; mi < 4; ++mi) af[mi] = *(const bf16x8*)(ab + mi * 16 * 32);
        #pragma unroll
        for (int nj = 0; nj < 2; ++nj) bf[nj] = *(const bf16x8*)(bb + nj * 16 * 32);
        #pragma unroll
        for (int mi = 0; mi < 4; ++mi)
            #pragma unroll
            for (int nj = 0; nj < 2; ++nj)
                acc[mi][nj] = __builtin_amdgcn_mfma_f32_16x16x32_bf16(
                    af[mi], bf[nj], acc[mi][nj], 0, 0, 0);
    };

    const int nk = kslice >> 5;
    __hip_bfloat16 *A0 = AsmB[0], *A1 = AsmB[1], *A2 = AsmB[2];
    __hip_bfloat16 *B0 = BsmB[0], *B1 = BsmB[1], *B2 = BsmB[2];
    stage(A0, B0, kbase);
    if (nk > 1) stage(A1, B1, kbase + 32);
    for (int t = 0; t < nk; ++t) {
        if (t + 1 < nk) {
            asm volatile("s_waitcnt vmcnt(3)" ::: "memory");
        } else {
            asm volatile("s_waitcnt vmcnt(0)" ::: "memory");
        }
        __builtin_amdgcn_s_barrier();
        if (t + 2 < nk) stage(A2, B2, kbase + (t + 2) * 32);
        compute(A0, B0);
        __hip_bfloat16* ta = A0; A0 = A1; A1 = A2; A2 = ta;
        __hip_bfloat16* tb = B0; B0 = B1; B1 = B2; B2 = tb;
    }

    if (sk > 1) {
        const size_t pstride = (size_t)M0 * N;
        float* dst = part + (size_t)(pair * sk + slice) * pstride;
        #pragma unroll
        for (int nj = 0; nj < 2; ++nj) {
            const int c = col0 + wc * 32 + nj * 16 + l15;
            #pragma unroll
            for (int mi = 0; mi < 4; ++mi)
                #pragma unroll
                for (int i = 0; i < 4; ++i) {
                    const int r = row0 + wr * 64 + mi * 16 + l4 * 4 + i;
                    if (r < M) dst[(size_t)r * N + c] = acc[mi][nj][i];
                }
        }
    } else {
        __hip_bfloat16* Cb = pair ? Cb1 : Cb0;
        #pragma unroll
        for (int nj = 0; nj < 2; ++nj) {
            const int c = col0 + wc * 32 + nj * 16 + l15;
            const float bv = bias[c];
            #pragma unroll
            for (int mi = 0; mi < 4; ++mi)
                #pragma unroll
                for (int i = 0; i < 4; ++i) {
                    const int r = row0 + wr * 64 + mi * 16 + l4 * 4 + i;
                    if (r >= M) continue;
                    float v = acc[mi][nj][i] + bv;
                    if (relu) v = fmaxf(v, 0.f);
                    Cb[(size_t)r * N + c] = __float2bfloat16(v);
                }
        }
    }
}

// Pair-batched split-K reduction. blockIdx.y = pair. Uniform pstride = M0*N.
__global__ __launch_bounds__(256) void reduce_pair(
    const float* __restrict__ part, size_t pstride, int sk,
    const float* __restrict__ b0p, const float* __restrict__ b1p,
    int M0, int M1, int N, int relu,
    __hip_bfloat16* __restrict__ ob0, __hip_bfloat16* __restrict__ ob1,
    float* __restrict__ of0, float* __restrict__ of1)
{
    const int pair = blockIdx.y;
    const int Mp = pair ? M1 : M0;
    const int idx4 = blockIdx.x * 256 + threadIdx.x;
    if (idx4 >= (Mp * N) / 4) return;
    const size_t base = (size_t)idx4 * 4;
    const int c = (int)(base & (size_t)(N - 1));
    const float* p0 = part + (size_t)(pair * sk) * pstride;
    float4 v = *(const float4*)(p0 + base);
    for (int s = 1; s < sk; ++s) {
        const float4 p = *(const float4*)(p0 + (size_t)s * pstride + base);
        v.x += p.x; v.y += p.y; v.z += p.z; v.w += p.w;
    }
    const float* bias = pair ? b1p : b0p;
    const float4 bv = *(const float4*)(bias + c);
    v.x += bv.x; v.y += bv.y; v.z += bv.z; v.w += bv.w;
    if (relu) {
        v.x = fmaxf(v.x, 0.f); v.y = fmaxf(v.y, 0.f);
        v.z = fmaxf(v.z, 0.f); v.w = fmaxf(v.w, 0.f);
    }
    __hip_bfloat16* ob = pair ? ob1 : ob0;
    float* of = pair ? of1 : of0;
    if (of) *(float4*)(of + base) = v;
    if (ob) {
        __hip_bfloat16* o = ob + base;
        o[0] = __float2bfloat16(v.x); o[1] = __float2bfloat16(v.y);
        o[2] = __float2bfloat16(v.z); o[3] = __float2bfloat16(v.w);
    }
}

// ---------------------------------------------------------------------------
// Split-K reduction (single, unchanged).
// ---------------------------------------------------------------------------
__global__ __launch_bounds__(256) void reduce_split(
    const float* __restrict__ part, int SK, size_t pstride,
    const float* __restrict__ bias, int N, int total4, int relu,
    float* __restrict__ outf, __hip_bfloat16* __restrict__ outb)
{
    const int idx4 = blockIdx.x * 256 + threadIdx.x;
    if (idx4 >= total4) return;
    const size_t base = (size_t)idx4 * 4;
    const int c = (int)(base & (size_t)(N - 1));
    float4 v = *(const float4*)(part + base);
    for (int s = 1; s < SK; ++s) {
        const float4 p = *(const float4*)(part + (size_t)s * pstride + base);
        v.x += p.x; v.y += p.y; v.z += p.z; v.w += p.w;
    }
    const float4 bv = *(const float4*)(bias + c);
    v.x += bv.x; v.y += bv.y; v.z += bv.z; v.w += bv.w;
    if (relu) {
        v.x = fmaxf(v.x, 0.f); v.y = fmaxf(v.y, 0.f);
        v.z = fmaxf(v.z, 0.f); v.w = fmaxf(v.w, 0.f);
    }
    if (outf) *(float4*)(outf + base) = v;
    if (outb) {
        __hip_bfloat16* o = outb + base;
        o[0] = __float2bfloat16(v.x); o[1] = __float2bfloat16(v.y);
        o[2] = __float2bfloat16(v.z); o[3] = __float2bfloat16(v.w);
    }
}

// ---------------------------------------------------------------------------
// Weight transpose+convert (generic, unchanged) + batched 1024x1024 variant.
// ---------------------------------------------------------------------------
__global__ __launch_bounds__(256) void transpose_w(
    const float* __restrict__ W, __hip_bfloat16* __restrict__ Wt,
    int K, int N, int Kpad)
{
    __shared__ float t[32][33];
    W  += (size_t)blockIdx.z * K * N;
    Wt += (size_t)blockIdx.z * N * Kpad;
    const int n0 = blockIdx.x * 32, k0 = blockIdx.y * 32;
    const int tx = threadIdx.x & 31, ty = threadIdx.x >> 5;
    #pragma unroll
    for (int i = 0; i < 4; ++i) {
        int r = ty + i * 8;
        int k = k0 + r, n = n0 + tx;
        t[r][tx] = (k < K && n < N) ? W[(size_t)k * N + n] : 0.f;
    }
    __syncthreads();
    #pragma unroll
    for (int i = 0; i < 4; ++i) {
        int r = ty + i * 8;
        int n = n0 + r, k = k0 + tx;
        if (n < N && k < Kpad) Wt[(size_t)n * Kpad + k] = __float2bfloat16(t[tx][r]);
    }
}

struct TW10 { const float* src[10]; __hip_bfloat16* dst[10]; };

// Ten 1024x1024 transposes in one launch (blockIdx.z selects).
__global__ __launch_bounds__(256) void transpose_w_b(TW10 p)
{
    __shared__ float t[32][33];
    const float* W = p.src[blockIdx.z];
    __hip_bfloat16* Wt = p.dst[blockIdx.z];
    const int n0 = blockIdx.x * 32, k0 = blockIdx.y * 32;
    const int tx = threadIdx.x & 31, ty = threadIdx.x >> 5;
    #pragma unroll
    for (int i = 0; i < 4; ++i) {
        int r = ty + i * 8;
        t[r][tx] = W[(size_t)(k0 + r) * 1024 + n0 + tx];
    }
    __syncthreads();
    #pragma unroll
    for (int i = 0; i < 4; ++i) {
        int r = ty + i * 8;
        Wt[(size_t)(n0 + r) * 1024 + k0 + tx] = __float2bfloat16(t[tx][r]);
    }
}

__global__ __launch_bounds__(256) void convert_pad(
    const float* __restrict__ in, __hip_bfloat16* __restrict__ out,
    int M, int Kin, int Kout)
{
    int idx = blockIdx.x * 256 + threadIdx.x;
    if (idx >= M * Kout) return;
    int r = idx / Kout, c = idx - r * Kout;
    out[idx] = __float2bfloat16(c < Kin ? in[(size_t)r * Kin + c] : 0.f);
}

// ---------------------------------------------------------------------------
// V transpose (unchanged).
// ---------------------------------------------------------------------------
__global__ __launch_bounds__(256) void v_transpose(
    const __hip_bfloat16* __restrict__ qkvb, __hip_bfloat16* __restrict__ vt)
{
    __shared__ __hip_bfloat16 tile[32][33];
    const int b  = blockIdx.z;
    const int c0 = blockIdx.x * 32;
    const int t0 = blockIdx.y * 32;
    const int tx = threadIdx.x & 31, ty = threadIdx.x >> 5;
    const __hip_bfloat16 z = __float2bfloat16(0.f);
    #pragma unroll
    for (int i = 0; i < 4; ++i) {
        const int tl = ty + i * 8;
        const int t = t0 + tl;
        tile[tl][tx] = (t < T_) ? qkvb[(size_t)(b * T_ + t) * 3072 + 2048 + c0 + tx] : z;
    }
    __syncthreads();
    #pragma unroll
    for (int i = 0; i < 4; ++i) {
        const int cl = ty + i * 8;
        const int t = t0 + tx;
        vt[((size_t)(b * 1024 + c0 + cl)) * 1024 + t] = (t < T_) ? tile[tx][cl] : z;
    }
}

// ---------------------------------------------------------------------------
// MFMA flash attention (unchanged from round 3 — proven).
// ---------------------------------------------------------------------------
__global__ __launch_bounds__(256) void attn_mfma(
    const __hip_bfloat16* __restrict__ qkvb,
    const __hip_bfloat16* __restrict__ vt,
    __hip_bfloat16* __restrict__ out)
{
    __shared__ __align__(16) __hip_bfloat16 Qs[2][128][32];
    __shared__ __align__(16) __hip_bfloat16 Ks[2][64][32];
    __shared__ __align__(16) __hip_bfloat16 Vs[2][64][32];
    __shared__ __align__(16) __hip_bfloat16 Ps[4][2][32][32];
    __shared__ float Lw[4][2][16];

    const int bh = blockIdx.x;
    const int b = bh >> 4, h = bh & 15;
    const int q0 = blockIdx.y * 128;
    const int tid = threadIdx.x;
    const int w = tid >> 6, lane = tid & 63;
    const int l15 = lane & 15, l4 = lane >> 4;
    const size_t ldq = 3 * D_;

    {
        #pragma unroll
        for (int c = 0; c < 2; ++c)
            #pragma unroll
            for (int it = 0; it < 2; ++it) {
                const int ch = it * 256 + tid;
                const int r = ch >> 2, cp = ch & 3;
                int qr = q0 + r; qr = (qr < T_) ? qr : (T_ - 1);
                const __hip_bfloat16* src = qkvb + (size_t)(b * T_ + qr) * ldq + h * 64 + c * 32 + cp * 8;
                __builtin_amdgcn_global_load_lds(
                    (const __attribute__((address_space(1))) unsigned*)src,
                    (__attribute__((address_space(3))) unsigned*)((__attribute__((address_space(3))) char*)&Qs[c][0][0] + ch * 16),
                    16, 0, 0);
            }
    }
    __syncthreads();
    bf16x8 qreg[2][2];
    #pragma unroll
    for (int qf = 0; qf < 2; ++qf)
        #pragma unroll
        for (int c = 0; c < 2; ++c)
            qreg[qf][c] = *(const bf16x8*)&Qs[c][w * 32 + qf * 16 + l15][l4 * 8];

    f32x4 of[2][4] = {};
    float lp[2] = {0.f, 0.f};
    const int qmaxw = q0 + w * 32 + 31;
    const int kend = (q0 + 128 < T_) ? (q0 + 128) : T_;

    for (int k0 = 0; k0 < kend; k0 += 64) {
        __syncthreads();
        {
            const int r = tid >> 2, cp = tid & 3;
            #pragma unroll
            for (int c = 0; c < 2; ++c) {
                int kr = k0 + r; kr = (kr < T_) ? kr : (T_ - 1);
                const __hip_bfloat16* srcK = qkvb + (size_t)(b * T_ + kr) * ldq + D_ + h * 64 + c * 32 + cp * 8;
                __builtin_amdgcn_global_load_lds(
                    (const __attribute__((address_space(1))) unsigned*)srcK,
                    (__attribute__((address_space(3))) unsigned*)((__attribute__((address_space(3))) char*)&Ks[c][0][0] + tid * 16),
                    16, 0, 0);
                const __hip_bfloat16* srcV = vt + ((size_t)(b * 1024 + h * 64 + r)) * 1024 + k0 + c * 32 + cp * 8;
                __builtin_amdgcn_global_load_lds(
                    (const __attribute__((address_space(1))) unsigned*)srcV,
                    (__attribute__((address_space(3))) unsigned*)((__attribute__((address_space(3))) char*)&Vs[c][0][0] + tid * 16),
                    16, 0, 0);
            }
        }
        __syncthreads();

        if (k0 <= qmaxw) {
            f32x4 sf[4][2] = {};
            #pragma unroll
            for (int c = 0; c < 2; ++c) {
                bf16x8 kf[4];
                #pragma unroll
                for (int kfr = 0; kfr < 4; ++kfr)
                    kf[kfr] = *(const bf16x8*)&Ks[c][kfr * 16 + l15][l4 * 8];
                #pragma unroll
                for (int kfr = 0; kfr < 4; ++kfr)
                    #pragma unroll
                    for (int qf = 0; qf < 2; ++qf)
                        sf[kfr][qf] = __builtin_amdgcn_mfma_f32_16x16x32_bf16(
                            kf[kfr], qreg[qf][c], sf[kfr][qf], 0, 0, 0);
            }
            const bool needmask = (k0 + 63) > (q0 + w * 32);
            #pragma unroll
            for (int kfr = 0; kfr < 4; ++kfr) {
                #pragma unroll
                for (int qf = 0; qf < 2; ++qf) {
                    const int qg = q0 + w * 32 + qf * 16 + l15;
                    float p[4];
                    #pragma unroll
                    for (int i = 0; i < 4; ++i) {
                        const int kg = k0 + kfr * 16 + l4 * 4 + i;
                        float pv = __expf(sf[kfr][qf][i] * 0.125f);
                        if (needmask && kg > qg) pv = 0.f;
                        p[i] = pv;
                        lp[qf] += pv;
                    }
                    unsigned* dst = (unsigned*)&Ps[w][kfr >> 1][qf * 16 + l15][(kfr & 1) * 16 + l4 * 4];
                    dst[0] = pack_bf2(p[0], p[1]);
                    dst[1] = pack_bf2(p[2], p[3]);
                }
            }
            #pragma unroll
            for (int kc = 0; kc < 2; ++kc) {
                bf16x8 pa[2], vb[4];
                #pragma unroll
                for (int qf = 0; qf < 2; ++qf)
                    pa[qf] = *(const bf16x8*)&Ps[w][kc][qf * 16 + l15][l4 * 8];
                #pragma unroll
                for (int df = 0; df < 4; ++df)
                    vb[df] = *(const bf16x8*)&Vs[kc][df * 16 + l15][l4 * 8];
                #pragma unroll
                for (int qf = 0; qf < 2; ++qf)
                    #pragma unroll
                    for (int df = 0; df < 4; ++df)
                        of[qf][df] = __builtin_amdgcn_mfma_f32_16x16x32_bf16(
                            pa[qf], vb[df], of[qf][df], 0, 0, 0);
            }
        }
    }

    #pragma unroll
    for (int qf = 0; qf < 2; ++qf) {
        float v = lp[qf];
        v += __shfl_xor(v, 16);
        v += __shfl_xor(v, 32);
        if (l4 == 0) Lw[w][qf][l15] = v;
    }
    __syncthreads();
    #pragma unroll
    for (int qf = 0; qf < 2; ++qf) {
        float inv[4];
        #pragma unroll
        for (int i = 0; i < 4; ++i) inv[i] = 1.f / Lw[w][qf][l4 * 4 + i];
        #pragma unroll
        for (int df = 0; df < 4; ++df) {
            #pragma unroll
            for (int i = 0; i < 4; ++i) {
                const int qg = q0 + w * 32 + qf * 16 + l4 * 4 + i;
                if (qg < T_)
                    out[(size_t)(b * T_ + qg) * D_ + h * 64 + df * 16 + l15] =
                        __float2bfloat16(of[qf][df][i] * inv[i]);
            }
        }
    }
}

// ---------------------------------------------------------------------------
// LN helpers (unchanged).
// ---------------------------------------------------------------------------
__device__ inline void block_ln_stats(float4 v, float& mu, float& inv,
                                      float* ws, float* ws2, float* mu_s, float* inv_s)
{
    const int tid = threadIdx.x;
    float s  = v.x + v.y + v.z + v.w;
    float s2 = v.x * v.x + v.y * v.y + v.z * v.z + v.w * v.w;
    #pragma unroll
    for (int off = 32; off; off >>= 1) {
        s  += __shfl_down(s, off);
        s2 += __shfl_down(s2, off);
    }
    const int wid = tid >> 6;
    if ((tid & 63) == 0) { ws[wid] = s; ws2[wid] = s2; }
    __syncthreads();
    if (tid == 0) {
        float S  = ws[0] + ws[1] + ws[2] + ws[3];
        float S2 = ws2[0] + ws2[1] + ws2[2] + ws2[3];
        float m = S * (1.f / (float)D_);
        float var = S2 * (1.f / (float)D_) - m * m;
        *mu_s = m;
        *inv_s = rsqrtf(var + 1e-5f);
    }
    __syncthreads();
    mu = *mu_s; inv = *inv_s;
}

__global__ __launch_bounds__(256) void add_ln_kernel(
    float* __restrict__ x, const float* __restrict__ p, int SK, size_t pstride,
    const float* __restrict__ pbias,
    const float* __restrict__ g, const float* __restrict__ beta,
    __hip_bfloat16* __restrict__ xb)
{
    const int row = blockIdx.x;
    const int tid = threadIdx.x;
    __shared__ float ws[4], ws2[4], mu_s, inv_s;
    float4* xr = reinterpret_cast<float4*>(x + (size_t)row * D_);
    float4 v = xr[tid];
    if (p) {
        for (int s = 0; s < SK; ++s) {
            const float4 wv = reinterpret_cast<const float4*>(
                p + (size_t)s * pstride + (size_t)row * D_)[tid];
            v.x += wv.x; v.y += wv.y; v.z += wv.z; v.w += wv.w;
        }
        if (pbias) {
            const float4 bv = reinterpret_cast<const float4*>(pbias)[tid];
            v.x += bv.x; v.y += bv.y; v.z += bv.z; v.w += bv.w;
        }
    }
    float mu, inv;
    block_ln_stats(v, mu, inv, ws, ws2, &mu_s, &inv_s);
    const float4 gg = reinterpret_cast<const float4*>(g)[tid];
    const float4 bb = reinterpret_cast<const float4*>(beta)[tid];
    float4 o;
    o.x = (v.x - mu) * inv * gg.x + bb.x;
    o.y = (v.y - mu) * inv * gg.y + bb.y;
    o.z = (v.z - mu) * inv * gg.z + bb.z;
    o.w = (v.w - mu) * inv * gg.w + bb.w;
    xr[tid] = o;
    if (xb) {
        __hip_bfloat16* xo = xb + (size_t)row * D_ + tid * 4;
        xo[0] = __float2bfloat16(o.x);
        xo[1] = __float2bfloat16(o.y);
        xo[2] = __float2bfloat16(o.z);
        xo[3] = __float2bfloat16(o.w);
    }
}

__global__ __launch_bounds__(256) void add_ln2_kernel(
    float* __restrict__ x, const float* __restrict__ p, int SK, size_t pstride,
    const float* __restrict__ pbias, const float* __restrict__ cav,
    const float* __restrict__ g1, const float* __restrict__ b1,
    const float* __restrict__ g2, const float* __restrict__ b2,
    __hip_bfloat16* __restrict__ xb)
{
    const int row = blockIdx.x;
    const int tid = threadIdx.x;
    __shared__ float ws[4], ws2[4], mu_s, inv_s;
    float4* xr = reinterpret_cast<float4*>(x + (size_t)row * D_);
    float4 v = xr[tid];
    for (int s = 0; s < SK; ++s) {
        const float4 wv = reinterpret_cast<const float4*>(
            p + (size_t)s * pstride + (size_t)row * D_)[tid];
        v.x += wv.x; v.y += wv.y; v.z += wv.z; v.w += wv.w;
    }
    if (pbias) {
        const float4 bv = reinterpret_cast<const float4*>(pbias)[tid];
        v.x += bv.x; v.y += bv.y; v.z += bv.z; v.w += bv.w;
    }
    float mu, inv;
    block_ln_stats(v, mu, inv, ws, ws2, &mu_s, &inv_s);
    const float4 g1v = reinterpret_cast<const float4*>(g1)[tid];
    const float4 b1v = reinterpret_cast<const float4*>(b1)[tid];
    const float4 cv  = reinterpret_cast<const float4*>(cav)[tid];
    float4 u;
    u.x = (v.x - mu) * inv * g1v.x + b1v.x + cv.x;
    u.y = (v.y - mu) * inv * g1v.y + b1v.y + cv.y;
    u.z = (v.z - mu) * inv * g1v.z + b1v.z + cv.z;
    u.w = (v.w - mu) * inv * g1v.w + b1v.w + cv.w;
    __syncthreads();
    float mu2, inv2;
    block_ln_stats(u, mu2, inv2, ws, ws2, &mu_s, &inv_s);
    const float4 g2v = reinterpret_cast<const float4*>(g2)[tid];
    const float4 b2v = reinterpret_cast<const float4*>(b2)[tid];
    float4 o;
    o.x = (u.x - mu2) * inv2 * g2v.x + b2v.x;
    o.y = (u.y - mu2) * inv2 * g2v.y + b2v.y;
    o.z = (u.z - mu2) * inv2 * g2v.z + b2v.z;
    o.w = (u.w - mu2) * inv2 * g2v.w + b2v.w;
    xr[tid] = o;
    __hip_bfloat16* xo = xb + (size_t)row * D_ + tid * 4;
    xo[0] = __float2bfloat16(o.x);
    xo[1] = __float2bfloat16(o.y);
    xo[2] = __float2bfloat16(o.z);
    xo[3] = __float2bfloat16(o.w);
}

__global__ __launch_bounds__(256) void interleave_pe_kernel(
    const float* __restrict__ obs_tok, const float* __restrict__ act_tok,
    float* __restrict__ x, __hip_bfloat16* __restrict__ xb)
{
    const int row = blockIdx.x;
    const int b = row / T_;
    const int t = row - b * T_;
    const float* src = (t & 1)
        ? (act_tok + (size_t)(b * (S_ - 1) + (t >> 1)) * D_)
        : (obs_tok + (size_t)(b * S_ + (t >> 1)) * D_);
    float* xr = x + (size_t)row * D_;
    __hip_bfloat16* xo = xb + (size_t)row * D_;
    #pragma unroll
    for (int k = 0; k < 4; ++k) {
        int d = threadIdx.x + k * 256;
        float ang = (float)b * expf(-(float)(d & ~1) * (9.210340371976184f / 1024.0f));
        float pe = (d & 1) ? cosf(ang) : sinf(ang);
        float v = src[d] + pe;
        xr[d] = v;
        xo[d] = __float2bfloat16(v);
    }
}

__global__ __launch_bounds__(256) void ca_part_kernel(
    const float* __restrict__ ca_b_in, const float* __restrict__ ca_w_out,
    float* __restrict__ part)
{
    const int idx = blockIdx.x * 256 + threadIdx.x;
    const int ks = blockIdx.y;
    const int l = idx >> 10, d = idx & 1023;
    const float* bv = ca_b_in + (size_t)l * 3 * D_ + 2 * D_ + ks * 64;
    const float* wp = ca_w_out + (size_t)l * D_ * D_ + (size_t)(ks * 64) * D_ + d;
    float s = 0.f;
    #pragma unroll 8
    for (int k = 0; k < 64; ++k) s = fmaf(bv[k], wp[(size_t)k * D_], s);
    part[(size_t)ks * (L_ * D_) + idx] = s;
}

__global__ __launch_bounds__(256) void ca_reduce_kernel(
    const float* __restrict__ part, const float* __restrict__ ca_b_out,
    float* __restrict__ out)
{
    const int idx = blockIdx.x * 256 + threadIdx.x;
    float s = ca_b_out[idx];
    #pragma unroll
    for (int ks = 0; ks < 16; ++ks) s += part[(size_t)ks * (L_ * D_) + idx];
    out[idx] = s;
}

// ---------------------------------------------------------------------------
extern "C" void kernel_launch(void* const* d_in, const int* in_sizes, int n_in,
                              void* d_out, int out_size, void* d_ws, size_t ws_size,
                              hipStream_t stream)
{
    const float* obs     = (const float*)d_in[0];
    const float* act     = (const float*)d_in[1];
    const float* in_w1   = (const float*)d_in[2];
    const float* in_b1   = (const float*)d_in[3];
    const float* in_w2   = (const float*)d_in[4];
    const float* in_b2   = (const float*)d_in[5];
    const float* in_w3   = (const float*)d_in[6];
    const float* in_b3   = (const float*)d_in[7];
    const float* act_w1  = (const float*)d_in[8];
    const float* act_b1  = (const float*)d_in[9];
    const float* act_w2  = (const float*)d_in[10];
    const float* act_b2  = (const float*)d_in[11];
    const float* act_w3  = (const float*)d_in[12];
    const float* act_b3  = (const float*)d_in[13];
    const float* out_w1  = (const float*)d_in[14];
    const float* out_b1  = (const float*)d_in[15];
    const float* out_w2  = (const float*)d_in[16];
    const float* out_b2  = (const float*)d_in[17];
    const float* out_w3  = (const float*)d_in[18];
    const float* out_b3  = (const float*)d_in[19];
    const float* sa_w_in = (const float*)d_in[20];
    const float* sa_b_in = (const float*)d_in[21];
    const float* sa_w_out= (const float*)d_in[22];
    const float* sa_b_out= (const float*)d_in[23];
    const float* ca_b_in = (const float*)d_in[25];
    const float* ca_w_out= (const float*)d_in[26];
    const float* ca_b_out= (const float*)d_in[27];
    const float* ff_w1   = (const float*)d_in[28];
    const float* ff_b1   = (const float*)d_in[29];
    const float* ff_w2   = (const float*)d_in[30];
    const float* ff_b2   = (const float*)d_in[31];
    const float* ln1_g   = (const float*)d_in[32];
    const float* ln1_b   = (const float*)d_in[33];
    const float* ln2_g   = (const float*)d_in[34];
    const float* ln2_b   = (const float*)d_in[35];
    const float* ln3_g   = (const float*)d_in[36];
    const float* ln3_b   = (const float*)d_in[37];
    const float* lnf_g   = (const float*)d_in[38];
    const float* lnf_b   = (const float*)d_in[39];

    const int MT = B_ * T_;          // 4092
    const int Mo = B_ * S_;          // 2048
    const int Ma = B_ * (S_ - 1);    // 2044

    char* base = (char*)d_ws;
    size_t used = 0;
    auto alloc = [&](size_t bytes) -> char* {
        char* r = base + used;
        used += (bytes + 255) & ~(size_t)255;
        return r;
    };
    typedef __hip_bfloat16 bf;
    bf* wi1  = (bf*)alloc((size_t)1024 * 64 * 2);
    bf* wi2  = (bf*)alloc((size_t)1024 * 1024 * 2);
    bf* wi3  = (bf*)alloc((size_t)1024 * 1024 * 2);
    bf* wa1  = (bf*)alloc((size_t)1024 * 32 * 2);
    bf* wa2  = (bf*)alloc((size_t)1024 * 1024 * 2);
    bf* wa3  = (bf*)alloc((size_t)1024 * 1024 * 2);
    bf* wo1  = (bf*)alloc((size_t)1024 * 1024 * 2);
    bf* wo2  = (bf*)alloc((size_t)1024 * 1024 * 2);
    bf* wo3  = (bf*)alloc((size_t)16 * 1024 * 2);
    bf* wsin = (bf*)alloc((size_t)L_ * 3072 * 1024 * 2);
    bf* wsout= (bf*)alloc((size_t)L_ * 1024 * 1024 * 2);
    bf* wf1  = (bf*)alloc((size_t)L_ * 4096 * 1024 * 2);
    bf* wf2  = (bf*)alloc((size_t)L_ * 1024 * 4096 * 2);
    bf* obs_bf = (bf*)alloc((size_t)Mo * 64 * 2);
    bf* act_bf = (bf*)alloc((size_t)Ma * 32 * 2);
    bf* x_bf   = (bf*)alloc((size_t)MT * D_ * 2);
    bf* attnb  = (bf*)alloc((size_t)MT * D_ * 2);
    bf* h1b    = (bf*)alloc((size_t)MT * D_ * 2);   // obs rows [0,Mo) | act rows [Mo,MT)
    bf* h2b    = (bf*)alloc((size_t)MT * D_ * 2);
    char* shared_rg = alloc((size_t)MT * F_ * 2);   // qkvb | ffh | partials
    bf* qkvb = (bf*)shared_rg;
    bf* ffh  = (bf*)shared_rg;
    bf* vt   = (bf*)alloc((size_t)B_ * 1024 * 1024 * 2);
    float* x       = (float*)alloc((size_t)MT * D_ * 4);
    float* y       = (float*)alloc((size_t)MT * D_ * 4);
    float* obs_tok = (float*)alloc((size_t)Mo * D_ * 4);
    float* act_tok = (float*)alloc((size_t)Ma * D_ * 4);
    float* ca      = (float*)alloc((size_t)L_ * D_ * 4);
    float* ca_part = (float*)alloc((size_t)16 * L_ * D_ * 4);
    if (used > ws_size) return;
    float* part_loop = y;                 // 2*MT*D fp32 (SK<=2, in decoder loop)
    float* part_pre  = (float*)shared_rg; // pre-loop pair-SK: 4 slices x Mo*D fp32
                                          // = 33.55MB <= shared_rg+vt span 41.9MB
    float* part_post = (float*)shared_rg; // post-loop, 2*MT*D exact fit

    auto tw = [&](const float* W, bf* Wt, int K, int N, int Kpad, int batch) {
        dim3 g((N + 31) / 32, (Kpad + 31) / 32, batch);
        transpose_w<<<g, 256, 0, stream>>>(W, Wt, K, N, Kpad);
    };
    auto gemm = [&](const bf* A, const bf* Wt, const float* bias,
                    float* Cf, bf* Cb, int M, int K, int N, int relu, int sk) {
        dim3 g((N + 63) / 64, (M + 127) / 128, sk);
        gemm_bf16<<<g, 256, 0, stream>>>(A, Wt, bias, Cf, Cb, M, K, N, relu, sk);
    };
    auto gemm_red = [&](const bf* A, const bf* Wt, const float* bias,
                        float* Cf, bf* Cb, int M, int K, int N, int relu, int sk,
                        float* part) {
        if (sk <= 1) { gemm(A, Wt, bias, Cf, Cb, M, K, N, relu, 1); return; }
        gemm(A, Wt, nullptr, part, nullptr, M, K, N, 0, sk);
        const size_t MN = (size_t)M * N;
        const int total4 = (int)(MN / 4);
        reduce_split<<<(total4 + 255) / 256, 256, 0, stream>>>(
            part, sk, MN, bias, N, total4, relu, Cf, Cb);
    };

    // ---- weight transposes: ten 1024x1024 batched into ONE launch ----
    {
        TW10 p;
        p.src[0] = in_w2;  p.dst[0] = wi2;
        p.src[1] = in_w3;  p.dst[1] = wi3;
        p.src[2] = act_w2; p.dst[2] = wa2;
        p.src[3] = act_w3; p.dst[3] = wa3;
        p.src[4] = out_w1; p.dst[4] = wo1;
        p.src[5] = out_w2; p.dst[5] = wo2;
        for (int l = 0; l < L_; ++l) {
            p.src[6 + l] = sa_w_out + (size_t)l * 1024 * 1024;
            p.dst[6 + l] = wsout + (size_t)l * 1024 * 1024;
        }
        transpose_w_b<<<dim3(32, 32, 10), 256, 0, stream>>>(p);
    }
    tw(in_w1,  wi1, 64,   1024, 64,   1);
    tw(act_w1, wa1, 16,   1024, 32,   1);
    tw(out_w3, wo3, 1024, 16,   1024, 1);
    tw(sa_w_in, wsin, 1024, 3072, 1024, L_);
    tw(ff_w1,   wf1,  1024, 4096, 1024, L_);
    tw(ff_w2,   wf2,  4096, 1024, 4096, L_);

    convert_pad<<<(Mo * 64 + 255) / 256, 256, 0, stream>>>(obs, obs_bf, Mo, 64, 64);
    convert_pad<<<(Ma * 32 + 255) / 256, 256, 0, stream>>>(act, act_bf, Ma, 16, 32);
    ca_part_kernel<<<dim3((L_ * D_) / 256, 16), 256, 0, stream>>>(ca_b_in, ca_w_out, ca_part);
    ca_reduce_kernel<<<(L_ * D_) / 256, 256, 0, stream>>>(ca_part, ca_b_out, ca);

    // ---- input MLPs: obs/act chains pair-batched (6 GEMMs + 4 reduces -> 3 + 2) ----
    const size_t MoD = (size_t)Mo * D_;
    // layer 1: K=64/32, sk=1 -> h1b (obs rows [0,Mo), act rows [Mo,MT))
    gemm_pair<<<dim3(16, 16, 2), 256, 0, stream>>>(
        obs_bf, act_bf, wi1, wa1, in_b1, act_b1,
        h1b, h1b + MoD, nullptr, Mo, Ma, 64, 32, D_, 1, 1);
    // layer 2: sk=2/pair -> part_pre (4 slices), reduce -> h2b
    gemm_pair<<<dim3(16, 16, 4), 256, 0, stream>>>(
        h1b, h1b + MoD, wi2, wa2, nullptr, nullptr,
        nullptr, nullptr, part_pre, Mo, Ma, D_, D_, D_, 0, 2);
    reduce_pair<<<dim3((int)(MoD / 4 + 255) / 256, 2), 256, 0, stream>>>(
        part_pre, MoD, 2, in_b2, act_b2, Mo, Ma, D_, 1,
        h2b, h2b + MoD, nullptr, nullptr);
    // layer 3: sk=2/pair -> part_pre, reduce -> obs_tok/act_tok (fp32)
    gemm_pair<<<dim3(16, 16, 4), 256, 0, stream>>>(
        h2b, h2b + MoD, wi3, wa3, nullptr, nullptr,
        nullptr, nullptr, part_pre, Mo, Ma, D_, D_, D_, 0, 2);
    reduce_pair<<<dim3((int)(MoD / 4 + 255) / 256, 2), 256, 0, stream>>>(
        part_pre, MoD, 2, in_b3, act_b3, Mo, Ma, D_, 0,
        nullptr, nullptr, obs_tok, act_tok);

    interleave_pe_kernel<<<MT, 256, 0, stream>>>(obs_tok, act_tok, x, x_bf);
    // obs_tok/act_tok/y now dead -> part_loop region live.

    // ---- decoder layers (unchanged from round 12) ----
    for (int l = 0; l < L_; ++l) {
        gemm(x_bf, wsin + (size_t)l * 3072 * 1024, sa_b_in + (size_t)l * 3 * D_,
             nullptr, qkvb, MT, D_, 3 * D_, 0, 1);                // 1536 blk
        v_transpose<<<dim3(32, 32, B_), 256, 0, stream>>>(qkvb, vt);
        attn_mfma<<<dim3(B_ * H_, 8), 256, 0, stream>>>(qkvb, vt, attnb);
        gemm(attnb, wsout + (size_t)l * 1024 * 1024, nullptr,
             part_loop, nullptr, MT, D_, D_, 0, 2);
        add_ln2_kernel<<<MT, 256, 0, stream>>>(x, part_loop, 2, (size_t)MT * D_,
             sa_b_out + (size_t)l * D_, ca + (size_t)l * D_,
             ln1_g + (size_t)l * D_, ln1_b + (size_t)l * D_,
             ln2_g + (size_t)l * D_, ln2_b + (size_t)l * D_, x_bf);
        gemm(x_bf, wf1 + (size_t)l * 4096 * 1024, ff_b1 + (size_t)l * F_,
             nullptr, ffh, MT, D_, F_, 1, 1);                     // 2048 blk
        gemm(ffh, wf2 + (size_t)l * 1024 * 4096, nullptr,
             part_loop, nullptr, MT, F_, D_, 0, 2);
        add_ln_kernel<<<MT, 256, 0, stream>>>(x, part_loop, 2, (size_t)MT * D_,
             ff_b2 + (size_t)l * D_,
             ln3_g + (size_t)l * D_, ln3_b + (size_t)l * D_, x_bf);
    }

    // ---- final norm + output MLP (unchanged) ----
    add_ln_kernel<<<MT, 256, 0, stream>>>(x, nullptr, 0, 0, nullptr, lnf_g, lnf_b, x_bf);
    gemm_red(x_bf, wo1, out_b1, nullptr, h1b, MT, D_, D_, 1, 2, part_post);
    gemm_red(h1b,  wo2, out_b2, nullptr, h2b, MT, D_, D_, 1, 2, part_post);
    gemm_red(h2b,  wo3, out_b3, (float*)d_out, nullptr, MT, D_, 16, 0, 8, part_post);
}

// Round 14
// 1324.748 us; speedup vs baseline: 1.1215x; 1.0280x over previous
//
#include <hip/hip_runtime.h>
#include <hip/hip_bf16.h>
#include <cstdint>
#include <cstddef>

#define B_  4
#define S_  512
#define T_  1023
#define D_  1024
#define H_  16
#define DH_ 64
#define F_  4096
#define L_  4

typedef float f32x4 __attribute__((ext_vector_type(4)));
typedef __bf16 bf16x8 __attribute__((ext_vector_type(8)));

__device__ inline unsigned pack_bf2(float a, float b) {
    union { __hip_bfloat16 h; unsigned short u; } ua, ub;
    ua.h = __float2bfloat16(a); ub.h = __float2bfloat16(b);
    return (unsigned)ua.u | ((unsigned)ub.u << 16);
}

// load 4 consecutive bf16 (8B, aligned) -> float4
__device__ inline float4 ld_bf4(const __hip_bfloat16* p) {
    const unsigned* u = (const unsigned*)p;
    const unsigned a = u[0], b = u[1];
    union { unsigned u; float f; } c0, c1, c2, c3;
    c0.u = (a & 0xffffu) << 16; c1.u = a & 0xffff0000u;
    c2.u = (b & 0xffffu) << 16; c3.u = b & 0xffff0000u;
    return make_float4(c0.f, c1.f, c2.f, c3.f);
}

// ---------------------------------------------------------------------------
// bf16 MFMA GEMM, 128x64 tile + 3-buffer counted-vmcnt pipeline + split-K.
// (Round-9/12 proven core.) ksplit>1: writes BF16 partials to Cb + z*M*N
// (halves partial traffic; consumer sums in fp32).
// ---------------------------------------------------------------------------
__global__ __launch_bounds__(256) void gemm_bf16(
    const __hip_bfloat16* __restrict__ A, const __hip_bfloat16* __restrict__ Wt,
    const float* __restrict__ bias,
    float* __restrict__ Cf, __hip_bfloat16* __restrict__ Cb,
    int M, int K, int N, int relu, int ksplit)
{
    __shared__ __align__(16) __hip_bfloat16 AsmB[3][128 * 32];
    __shared__ __align__(16) __hip_bfloat16 BsmB[3][64 * 32];
    const int tid  = threadIdx.x;
    const int lane = tid & 63;
    const int w    = tid >> 6;
    const int wr   = w >> 1, wc = w & 1;
    const int l15  = lane & 15, l4 = lane >> 4;

    const int gx = gridDim.x;
    int bid = blockIdx.y * gx + blockIdx.x;
    {
        const int nwg = gx * gridDim.y;
        const int q = nwg >> 3, r = nwg & 7;
        const int xcd = bid & 7, idx = bid >> 3;
        bid = (xcd < r ? xcd * (q + 1) : r * (q + 1) + (xcd - r) * q) + idx;
    }
    const int row0 = (bid / gx) * 128;
    const int col0 = (bid % gx) * 64;
    const int z = blockIdx.z;
    const int kslice = K / ksplit;
    const int kbase = z * kslice;

    f32x4 acc[4][2] = {};

    auto stage = [&](__hip_bfloat16* As, __hip_bfloat16* Bs, int kt) {
        auto* ldsA = (__attribute__((address_space(3))) char*)As;
        auto* ldsB = (__attribute__((address_space(3))) char*)Bs;
        #pragma unroll
        for (int half = 0; half < 2; ++half) {
            const int ch = half * 256 + tid;
            const int r  = ch >> 2;
            const int c  = (ch & 3) * 8;
            int gr = row0 + r; gr = (gr < M) ? gr : (M - 1);
            const __hip_bfloat16* srcA = A + (size_t)gr * K + kt + c;
            __builtin_amdgcn_global_load_lds(
                (const __attribute__((address_space(1))) unsigned*)srcA,
                (__attribute__((address_space(3))) unsigned*)(ldsA + (size_t)ch * 16),
                16, 0, 0);
        }
        {
            const int r = tid >> 2;
            const int c = (tid & 3) * 8;
            int gc = col0 + r; gc = (gc < N) ? gc : (N - 1);
            const __hip_bfloat16* srcB = Wt + (size_t)gc * K + kt + c;
            __builtin_amdgcn_global_load_lds(
                (const __attribute__((address_space(1))) unsigned*)srcB,
                (__attribute__((address_space(3))) unsigned*)(ldsB + (size_t)tid * 16),
                16, 0, 0);
        }
    };
    auto compute = [&](const __hip_bfloat16* As, const __hip_bfloat16* Bs) {
        const __hip_bfloat16* ab = As + (size_t)(wr * 64 + l15) * 32 + l4 * 8;
        const __hip_bfloat16* bb = Bs + (size_t)(wc * 32 + l15) * 32 + l4 * 8;
        bf16x8 af[4], bf[2];
        #pragma unroll
        for (int mi = 0; mi < 4; ++mi) af[mi] = *(const bf16x8*)(ab + mi * 16 * 32);
        #pragma unroll
        for (int nj = 0; nj < 2; ++nj) bf[nj] = *(const bf16x8*)(bb + nj * 16 * 32);
        #pragma unroll
        for (int mi = 0; mi < 4; ++mi)
            #pragma unroll
            for (int nj = 0; nj < 2; ++nj)
                acc[mi][nj] = __builtin_amdgcn_mfma_f32_16x16x32_bf16(
                    af[mi], bf[nj], acc[mi][nj], 0, 0, 0);
    };

    const int nk = kslice >> 5;
    __hip_bfloat16 *A0 = AsmB[0], *A1 = AsmB[1], *A2 = AsmB[2];
    __hip_bfloat16 *B0 = BsmB[0], *B1 = BsmB[1], *B2 = BsmB[2];
    stage(A0, B0, kbase);
    if (nk > 1) stage(A1, B1, kbase + 32);
    for (int t = 0; t < nk; ++t) {
        if (t + 1 < nk) {
            asm volatile("s_waitcnt vmcnt(3)" ::: "memory");
        } else {
            asm volatile("s_waitcnt vmcnt(0)" ::: "memory");
        }
        __builtin_amdgcn_s_barrier();
        if (t + 2 < nk) stage(A2, B2, kbase + (t + 2) * 32);
        compute(A0, B0);
        __hip_bfloat16* ta = A0; A0 = A1; A1 = A2; A2 = ta;
        __hip_bfloat16* tb = B0; B0 = B1; B1 = B2; B2 = tb;
    }

    // epilogue: C/D layout col = lane&15, row = (lane>>4)*4 + i  [m89-verified]
    if (ksplit > 1) {
        __hip_bfloat16* dst = Cb + (size_t)z * M * N;   // bf16 partials
        #pragma unroll
        for (int nj = 0; nj < 2; ++nj) {
            const int c = col0 + wc * 32 + nj * 16 + l15;
            if (c >= N) continue;
            #pragma unroll
            for (int mi = 0; mi < 4; ++mi)
                #pragma unroll
                for (int i = 0; i < 4; ++i) {
                    const int r = row0 + wr * 64 + mi * 16 + l4 * 4 + i;
                    if (r < M) dst[(size_t)r * N + c] = __float2bfloat16(acc[mi][nj][i]);
                }
        }
    } else {
        #pragma unroll
        for (int nj = 0; nj < 2; ++nj) {
            const int c = col0 + wc * 32 + nj * 16 + l15;
            if (c >= N) continue;
            const float bv = bias[c];
            #pragma unroll
            for (int mi = 0; mi < 4; ++mi)
                #pragma unroll
                for (int i = 0; i < 4; ++i) {
                    const int r = row0 + wr * 64 + mi * 16 + l4 * 4 + i;
                    if (r >= M) continue;
                    float v = acc[mi][nj][i] + bv;
                    if (relu) v = fmaxf(v, 0.f);
                    if (Cf) Cf[(size_t)r * N + c] = v;
                    if (Cb) Cb[(size_t)r * N + c] = __float2bfloat16(v);
                }
        }
    }
}

// ---------------------------------------------------------------------------
// Pair-batched GEMM (obs/act MLP chains). sk>1: bf16 partials.
// ---------------------------------------------------------------------------
__global__ __launch_bounds__(256) void gemm_pair(
    const __hip_bfloat16* __restrict__ A0p, const __hip_bfloat16* __restrict__ A1p,
    const __hip_bfloat16* __restrict__ W0p, const __hip_bfloat16* __restrict__ W1p,
    const float* __restrict__ b0p, const float* __restrict__ b1p,
    __hip_bfloat16* __restrict__ Cb0, __hip_bfloat16* __restrict__ Cb1,
    __hip_bfloat16* __restrict__ part,
    int M0, int M1, int K0, int K1, int N, int relu, int sk)
{
    __shared__ __align__(16) __hip_bfloat16 AsmB[3][128 * 32];
    __shared__ __align__(16) __hip_bfloat16 BsmB[3][64 * 32];
    const int tid  = threadIdx.x;
    const int lane = tid & 63;
    const int w    = tid >> 6;
    const int wr   = w >> 1, wc = w & 1;
    const int l15  = lane & 15, l4 = lane >> 4;

    const int gx = gridDim.x;
    int bid = blockIdx.y * gx + blockIdx.x;
    {
        const int nwg = gx * gridDim.y;
        const int q = nwg >> 3, r = nwg & 7;
        const int xcd = bid & 7, idx = bid >> 3;
        bid = (xcd < r ? xcd * (q + 1) : r * (q + 1) + (xcd - r) * q) + idx;
    }
    const int row0 = (bid / gx) * 128;
    const int col0 = (bid % gx) * 64;

    const int z = blockIdx.z;
    const int pair  = z / sk;
    const int slice = z - pair * sk;
    const __hip_bfloat16* A  = pair ? A1p : A0p;
    const __hip_bfloat16* Wt = pair ? W1p : W0p;
    const float* bias        = pair ? b1p : b0p;
    const int M = pair ? M1 : M0;
    const int K = pair ? K1 : K0;
    const int kslice = K / sk;
    const int kbase = slice * kslice;

    f32x4 acc[4][2] = {};

    auto stage = [&](__hip_bfloat16* As, __hip_bfloat16* Bs, int kt) {
        auto* ldsA = (__attribute__((address_space(3))) char*)As;
        auto* ldsB = (__attribute__((address_space(3))) char*)Bs;
        #pragma unroll
        for (int half = 0; half < 2; ++half) {
            const int ch = half * 256 + tid;
            const int r  = ch >> 2;
            const int c  = (ch & 3) * 8;
            int gr = row0 + r; gr = (gr < M) ? gr : (M - 1);
            const __hip_bfloat16* srcA = A + (size_t)gr * K + kt + c;
            __builtin_amdgcn_global_load_lds(
                (const __attribute__((address_space(1))) unsigned*)srcA,
                (__attribute__((address_space(3))) unsigned*)(ldsA + (size_t)ch * 16),
                16, 0, 0);
        }
        {
            const int r = tid >> 2;
            const int c = (tid & 3) * 8;
            int gc = col0 + r; gc = (gc < N) ? gc : (N - 1);
            const __hip_bfloat16* srcB = Wt + (size_t)gc * K + kt + c;
            __builtin_amdgcn_global_load_lds(
                (const __attribute__((address_space(1))) unsigned*)srcB,
                (__attribute__((address_space(3))) unsigned*)(ldsB + (size_t)tid * 16),
                16, 0, 0);
        }
    };
    auto compute = [&](const __hip_bfloat16* As, const __hip_bfloat16* Bs) {
        const __hip_bfloat16* ab = As + (size_t)(wr * 64 + l15) * 32 + l4 * 8;
        const __hip_bfloat16* bb = Bs + (size_t)(wc * 32 + l15) * 32 + l4 * 8;
        bf16x8 af[4], bf[2];
        #pragma unroll
        for (int mi = 0; mi < 4; ++mi) af[mi] = *(const bf16x8*)(ab + mi * 16 * 32);
        #pragma unroll
        for (int nj = 0; nj < 2; ++nj) bf[nj] = *(const bf16x8*)(bb + nj * 16 * 32);
        #pragma unroll
        for (int mi = 0; mi < 4; ++mi)
            #pragma unroll
            for (int nj = 0; nj < 2; ++nj)
                acc[mi][nj] = __builtin_amdgcn_mfma_f32_16x16x32_bf16(
                    af[mi], bf[nj], acc[mi][nj], 0, 0, 0);
    };

    const int nk = kslice >> 5;
    __hip_bfloat16 *A0 = AsmB[0], *A1 = AsmB[1], *A2 = AsmB[2];
    __hip_bfloat16 *B0 = BsmB[0], *B1 = BsmB[1], *B2 = BsmB[2];
    stage(A0, B0, kbase);
    if (nk > 1) stage(A1, B1, kbase + 32);
    for (int t = 0; t < nk; ++t) {
        if (t + 1 < nk) {
            asm volatile("s_waitcnt vmcnt(3)" ::: "memory");
        } else {
            asm volatile("s_waitcnt vmcnt(0)" ::: "memory");
        }
        __builtin_amdgcn_s_barrier();
        if (t + 2 < nk) stage(A2, B2, kbase + (t + 2) * 32);
        compute(A0, B0);
        __hip_bfloat16* ta = A0; A0 = A1; A1 = A2; A2 = ta;
        __hip_bfloat16* tb = B0; B0 = B1; B1 = B2; B2 = tb;
    }

    if (sk > 1) {
        const size_t pstride = (size_t)M0 * N;
        __hip_bfloat16* dst = part + (size_t)(pair * sk + slice) * pstride;
        #pragma unroll
        for (int nj = 0; nj < 2; ++nj) {
            const int c = col0 + wc * 32 + nj * 16 + l15;
            #pragma unroll
            for (int mi = 0; mi < 4; ++mi)
                #pragma unroll
                for (int i = 0; i < 4; ++i) {
                    const int r = row0 + wr * 64 + mi * 16 + l4 * 4 + i;
                    if (r < M) dst[(size_t)r * N + c] = __float2bfloat16(acc[mi][nj][i]);
                }
        }
    } else {
        __hip_bfloat16* Cb = pair ? Cb1 : Cb0;
        #pragma unroll
        for (int nj = 0; nj < 2; ++nj) {
            const int c = col0 + wc * 32 + nj * 16 + l15;
            const float bv = bias[c];
            #pragma unroll
            for (int mi = 0; mi < 4; ++mi)
                #pragma unroll
                for (int i = 0; i < 4; ++i) {
                    const int r = row0 + wr * 64 + mi * 16 + l4 * 4 + i;
                    if (r >= M) continue;
                    float v = acc[mi][nj][i] + bv;
                    if (relu) v = fmaxf(v, 0.f);
                    Cb[(size_t)r * N + c] = __float2bfloat16(v);
                }
        }
    }
}

// Pair-batched split-K reduction (bf16 partials, fp32 accumulate).
__global__ __launch_bounds__(256) void reduce_pair(
    const __hip_bfloat16* __restrict__ part, size_t pstride, int sk,
    const float* __restrict__ b0p, const float* __restrict__ b1p,
    int M0, int M1, int N, int relu,
    __hip_bfloat16* __restrict__ ob0, __hip_bfloat16* __restrict__ ob1,
    float* __restrict__ of0, float* __restrict__ of1)
{
    const int pair = blockIdx.y;
    const int Mp = pair ? M1 : M0;
    const int idx4 = blockIdx.x * 256 + threadIdx.x;
    if (idx4 >= (Mp * N) / 4) return;
    const size_t base = (size_t)idx4 * 4;
    const int c = (int)(base & (size_t)(N - 1));
    const __hip_bfloat16* p0 = part + (size_t)(pair * sk) * pstride;
    float4 v = ld_bf4(p0 + base);
    for (int s = 1; s < sk; ++s) {
        const float4 p = ld_bf4(p0 + (size_t)s * pstride + base);
        v.x += p.x; v.y += p.y; v.z += p.z; v.w += p.w;
    }
    const float* bias = pair ? b1p : b0p;
    const float4 bv = *(const float4*)(bias + c);
    v.x += bv.x; v.y += bv.y; v.z += bv.z; v.w += bv.w;
    if (relu) {
        v.x = fmaxf(v.x, 0.f); v.y = fmaxf(v.y, 0.f);
        v.z = fmaxf(v.z, 0.f); v.w = fmaxf(v.w, 0.f);
    }
    __hip_bfloat16* ob = pair ? ob1 : ob0;
    float* of = pair ? of1 : of0;
    if (of) *(float4*)(of + base) = v;
    if (ob) {
        __hip_bfloat16* o = ob + base;
        o[0] = __float2bfloat16(v.x); o[1] = __float2bfloat16(v.y);
        o[2] = __float2bfloat16(v.z); o[3] = __float2bfloat16(v.w);
    }
}

// ---------------------------------------------------------------------------
// Split-K reduction (single; bf16 partials, fp32 accumulate).
// ---------------------------------------------------------------------------
__global__ __launch_bounds__(256) void reduce_split(
    const __hip_bfloat16* __restrict__ part, int SK, size_t pstride,
    const float* __restrict__ bias, int N, int total4, int relu,
    float* __restrict__ outf, __hip_bfloat16* __restrict__ outb)
{
    const int idx4 = blockIdx.x * 256 + threadIdx.x;
    if (idx4 >= total4) return;
    const size_t base = (size_t)idx4 * 4;
    const int c = (int)(base & (size_t)(N - 1));
    float4 v = ld_bf4(part + base);
    for (int s = 1; s < SK; ++s) {
        const float4 p = ld_bf4(part + (size_t)s * pstride + base);
        v.x += p.x; v.y += p.y; v.z += p.z; v.w += p.w;
    }
    const float4 bv = *(const float4*)(bias + c);
    v.x += bv.x; v.y += bv.y; v.z += bv.z; v.w += bv.w;
    if (relu) {
        v.x = fmaxf(v.x, 0.f); v.y = fmaxf(v.y, 0.f);
        v.z = fmaxf(v.z, 0.f); v.w = fmaxf(v.w, 0.f);
    }
    if (outf) *(float4*)(outf + base) = v;
    if (outb) {
        __hip_bfloat16* o = outb + base;
        o[0] = __float2bfloat16(v.x); o[1] = __float2bfloat16(v.y);
        o[2] = __float2bfloat16(v.z); o[3] = __float2bfloat16(v.w);
    }
}

// ---------------------------------------------------------------------------
// Weight transpose+convert (generic + batched 1024x1024).
// ---------------------------------------------------------------------------
__global__ __launch_bounds__(256) void transpose_w(
    const float* __restrict__ W, __hip_bfloat16* __restrict__ Wt,
    int K, int N, int Kpad)
{
    __shared__ float t[32][33];
    W  += (size_t)blockIdx.z * K * N;
    Wt += (size_t)blockIdx.z * N * Kpad;
    const int n0 = blockIdx.x * 32, k0 = blockIdx.y * 32;
    const int tx = threadIdx.x & 31, ty = threadIdx.x >> 5;
    #pragma unroll
    for (int i = 0; i < 4; ++i) {
        int r = ty + i * 8;
        int k = k0 + r, n = n0 + tx;
        t[r][tx] = (k < K && n < N) ? W[(size_t)k * N + n] : 0.f;
    }
    __syncthreads();
    #pragma unroll
    for (int i = 0; i < 4; ++i) {
        int r = ty + i * 8;
        int n = n0 + r, k = k0 + tx;
        if (n < N && k < Kpad) Wt[(size_t)n * Kpad + k] = __float2bfloat16(t[tx][r]);
    }
}

struct TW10 { const float* src[10]; __hip_bfloat16* dst[10]; };

__global__ __launch_bounds__(256) void transpose_w_b(TW10 p)
{
    __shared__ float t[32][33];
    const float* W = p.src[blockIdx.z];
    __hip_bfloat16* Wt = p.dst[blockIdx.z];
    const int n0 = blockIdx.x * 32, k0 = blockIdx.y * 32;
    const int tx = threadIdx.x & 31, ty = threadIdx.x >> 5;
    #pragma unroll
    for (int i = 0; i < 4; ++i) {
        int r = ty + i * 8;
        t[r][tx] = W[(size_t)(k0 + r) * 1024 + n0 + tx];
    }
    __syncthreads();
    #pragma unroll
    for (int i = 0; i < 4; ++i) {
        int r = ty + i * 8;
        Wt[(size_t)(n0 + r) * 1024 + k0 + tx] = __float2bfloat16(t[tx][r]);
    }
}

__global__ __launch_bounds__(256) void convert_pad(
    const float* __restrict__ in, __hip_bfloat16* __restrict__ out,
    int M, int Kin, int Kout)
{
    int idx = blockIdx.x * 256 + threadIdx.x;
    if (idx >= M * Kout) return;
    int r = idx / Kout, c = idx - r * Kout;
    out[idx] = __float2bfloat16(c < Kin ? in[(size_t)r * Kin + c] : 0.f);
}

// ---------------------------------------------------------------------------
// V transpose (unchanged).
// ---------------------------------------------------------------------------
__global__ __launch_bounds__(256) void v_transpose(
    const __hip_bfloat16* __restrict__ qkvb, __hip_bfloat16* __restrict__ vt)
{
    __shared__ __hip_bfloat16 tile[32][33];
    const int b  = blockIdx.z;
    const int c0 = blockIdx.x * 32;
    const int t0 = blockIdx.y * 32;
    const int tx = threadIdx.x & 31, ty = threadIdx.x >> 5;
    const __hip_bfloat16 z = __float2bfloat16(0.f);
    #pragma unroll
    for (int i = 0; i < 4; ++i) {
        const int tl = ty + i * 8;
        const int t = t0 + tl;
        tile[tl][tx] = (t < T_) ? qkvb[(size_t)(b * T_ + t) * 3072 + 2048 + c0 + tx] : z;
    }
    __syncthreads();
    #pragma unroll
    for (int i = 0; i < 4; ++i) {
        const int cl = ty + i * 8;
        const int t = t0 + tx;
        vt[((size_t)(b * 1024 + c0 + cl)) * 1024 + t] = (t < T_) ? tile[tx][cl] : z;
    }
}

// ---------------------------------------------------------------------------
// MFMA flash attention (unchanged from round 3 — proven).
// ---------------------------------------------------------------------------
__global__ __launch_bounds__(256) void attn_mfma(
    const __hip_bfloat16* __restrict__ qkvb,
    const __hip_bfloat16* __restrict__ vt,
    __hip_bfloat16* __restrict__ out)
{
    __shared__ __align__(16) __hip_bfloat16 Qs[2][128][32];
    __shared__ __align__(16) __hip_bfloat16 Ks[2][64][32];
    __shared__ __align__(16) __hip_bfloat16 Vs[2][64][32];
    __shared__ __align__(16) __hip_bfloat16 Ps[4][2][32][32];
    __shared__ float Lw[4][2][16];

    const int bh = blockIdx.x;
    const int b = bh >> 4, h = bh & 15;
    const int q0 = blockIdx.y * 128;
    const int tid = threadIdx.x;
    const int w = tid >> 6, lane = tid & 63;
    const int l15 = lane & 15, l4 = lane >> 4;
    const size_t ldq = 3 * D_;

    {
        #pragma unroll
        for (int c = 0; c < 2; ++c)
            #pragma unroll
            for (int it = 0; it < 2; ++it) {
                const int ch = it * 256 + tid;
                const int r = ch >> 2, cp = ch & 3;
                int qr = q0 + r; qr = (qr < T_) ? qr : (T_ - 1);
                const __hip_bfloat16* src = qkvb + (size_t)(b * T_ + qr) * ldq + h * 64 + c * 32 + cp * 8;
                __builtin_amdgcn_global_load_lds(
                    (const __attribute__((address_space(1))) unsigned*)src,
                    (__attribute__((address_space(3))) unsigned*)((__attribute__((address_space(3))) char*)&Qs[c][0][0] + ch * 16),
                    16, 0, 0);
            }
    }
    __syncthreads();
    bf16x8 qreg[2][2];
    #pragma unroll
    for (int qf = 0; qf < 2; ++qf)
        #pragma unroll
        for (int c = 0; c < 2; ++c)
            qreg[qf][c] = *(const bf16x8*)&Qs[c][w * 32 + qf * 16 + l15][l4 * 8];

    f32x4 of[2][4] = {};
    float lp[2] = {0.f, 0.f};
    const int qmaxw = q0 + w * 32 + 31;
    const int kend = (q0 + 128 < T_) ? (q0 + 128) : T_;

    for (int k0 = 0; k0 < kend; k0 += 64) {
        __syncthreads();
        {
            const int r = tid >> 2, cp = tid & 3;
            #pragma unroll
            for (int c = 0; c < 2; ++c) {
                int kr = k0 + r; kr = (kr < T_) ? kr : (T_ - 1);
                const __hip_bfloat16* srcK = qkvb + (size_t)(b * T_ + kr) * ldq + D_ + h * 64 + c * 32 + cp * 8;
                __builtin_amdgcn_global_load_lds(
                    (const __attribute__((address_space(1))) unsigned*)srcK,
                    (__attribute__((address_space(3))) unsigned*)((__attribute__((address_space(3))) char*)&Ks[c][0][0] + tid * 16),
                    16, 0, 0);
                const __hip_bfloat16* srcV = vt + ((size_t)(b * 1024 + h * 64 + r)) * 1024 + k0 + c * 32 + cp * 8;
                __builtin_amdgcn_global_load_lds(
                    (const __attribute__((address_space(1))) unsigned*)srcV,
                    (__attribute__((address_space(3))) unsigned*)((__attribute__((address_space(3))) char*)&Vs[c][0][0] + tid * 16),
                    16, 0, 0);
            }
        }
        __syncthreads();

        if (k0 <= qmaxw) {
            f32x4 sf[4][2] = {};
            #pragma unroll
            for (int c = 0; c < 2; ++c) {
                bf16x8 kf[4];
                #pragma unroll
                for (int kfr = 0; kfr < 4; ++kfr)
                    kf[kfr] = *(const bf16x8*)&Ks[c][kfr * 16 + l15][l4 * 8];
                #pragma unroll
                for (int kfr = 0; kfr < 4; ++kfr)
                    #pragma unroll
                    for (int qf = 0; qf < 2; ++qf)
                        sf[kfr][qf] = __builtin_amdgcn_mfma_f32_16x16x32_bf16(
                            kf[kfr], qreg[qf][c], sf[kfr][qf], 0, 0, 0);
            }
            const bool needmask = (k0 + 63) > (q0 + w * 32);
            #pragma unroll
            for (int kfr = 0; kfr < 4; ++kfr) {
                #pragma unroll
                for (int qf = 0; qf < 2; ++qf) {
                    const int qg = q0 + w * 32 + qf * 16 + l15;
                    float p[4];
                    #pragma unroll
                    for (int i = 0; i < 4; ++i) {
                        const int kg = k0 + kfr * 16 + l4 * 4 + i;
                        float pv = __expf(sf[kfr][qf][i] * 0.125f);
                        if (needmask && kg > qg) pv = 0.f;
                        p[i] = pv;
                        lp[qf] += pv;
                    }
                    unsigned* dst = (unsigned*)&Ps[w][kfr >> 1][qf * 16 + l15][(kfr & 1) * 16 + l4 * 4];
                    dst[0] = pack_bf2(p[0], p[1]);
                    dst[1] = pack_bf2(p[2], p[3]);
                }
            }
            #pragma unroll
            for (int kc = 0; kc < 2; ++kc) {
                bf16x8 pa[2], vb[4];
                #pragma unroll
                for (int qf = 0; qf < 2; ++qf)
                    pa[qf] = *(const bf16x8*)&Ps[w][kc][qf * 16 + l15][l4 * 8];
                #pragma unroll
                for (int df = 0; df < 4; ++df)
                    vb[df] = *(const bf16x8*)&Vs[kc][df * 16 + l15][l4 * 8];
                #pragma unroll
                for (int qf = 0; qf < 2; ++qf)
                    #pragma unroll
                    for (int df = 0; df < 4; ++df)
                        of[qf][df] = __builtin_amdgcn_mfma_f32_16x16x32_bf16(
                            pa[qf], vb[df], of[qf][df], 0, 0, 0);
            }
        }
    }

    #pragma unroll
    for (int qf = 0; qf < 2; ++qf) {
        float v = lp[qf];
        v += __shfl_xor(v, 16);
        v += __shfl_xor(v, 32);
        if (l4 == 0) Lw[w][qf][l15] = v;
    }
    __syncthreads();
    #pragma unroll
    for (int qf = 0; qf < 2; ++qf) {
        float inv[4];
        #pragma unroll
        for (int i = 0; i < 4; ++i) inv[i] = 1.f / Lw[w][qf][l4 * 4 + i];
        #pragma unroll
        for (int df = 0; df < 4; ++df) {
            #pragma unroll
            for (int i = 0; i < 4; ++i) {
                const int qg = q0 + w * 32 + qf * 16 + l4 * 4 + i;
                if (qg < T_)
                    out[(size_t)(b * T_ + qg) * D_ + h * 64 + df * 16 + l15] =
                        __float2bfloat16(of[qf][df][i] * inv[i]);
            }
        }
    }
}

// ---------------------------------------------------------------------------
// LN helpers. Residual: SK bf16 partial slices + optional bias (fp32 sums).
// ---------------------------------------------------------------------------
__device__ inline void block_ln_stats(float4 v, float& mu, float& inv,
                                      float* ws, float* ws2, float* mu_s, float* inv_s)
{
    const int tid = threadIdx.x;
    float s  = v.x + v.y + v.z + v.w;
    float s2 = v.x * v.x + v.y * v.y + v.z * v.z + v.w * v.w;
    #pragma unroll
    for (int off = 32; off; off >>= 1) {
        s  += __shfl_down(s, off);
        s2 += __shfl_down(s2, off);
    }
    const int wid = tid >> 6;
    if ((tid & 63) == 0) { ws[wid] = s; ws2[wid] = s2; }
    __syncthreads();
    if (tid == 0) {
        float S  = ws[0] + ws[1] + ws[2] + ws[3];
        float S2 = ws2[0] + ws2[1] + ws2[2] + ws2[3];
        float m = S * (1.f / (float)D_);
        float var = S2 * (1.f / (float)D_) - m * m;
        *mu_s = m;
        *inv_s = rsqrtf(var + 1e-5f);
    }
    __syncthreads();
    mu = *mu_s; inv = *inv_s;
}

__global__ __launch_bounds__(256) void add_ln_kernel(
    float* __restrict__ x, const __hip_bfloat16* __restrict__ p, int SK, size_t pstride,
    const float* __restrict__ pbias,
    const float* __restrict__ g, const float* __restrict__ beta,
    __hip_bfloat16* __restrict__ xb)
{
    const int row = blockIdx.x;
    const int tid = threadIdx.x;
    __shared__ float ws[4], ws2[4], mu_s, inv_s;
    float4* xr = reinterpret_cast<float4*>(x + (size_t)row * D_);
    float4 v = xr[tid];
    if (p) {
        for (int s = 0; s < SK; ++s) {
            const float4 wv = ld_bf4(p + (size_t)s * pstride + (size_t)row * D_ + tid * 4);
            v.x += wv.x; v.y += wv.y; v.z += wv.z; v.w += wv.w;
        }
        if (pbias) {
            const float4 bv = reinterpret_cast<const float4*>(pbias)[tid];
            v.x += bv.x; v.y += bv.y; v.z += bv.z; v.w += bv.w;
        }
    }
    float mu, inv;
    block_ln_stats(v, mu, inv, ws, ws2, &mu_s, &inv_s);
    const float4 gg = reinterpret_cast<const float4*>(g)[tid];
    const float4 bb = reinterpret_cast<const float4*>(beta)[tid];
    float4 o;
    o.x = (v.x - mu) * inv * gg.x + bb.x;
    o.y = (v.y - mu) * inv * gg.y + bb.y;
    o.z = (v.z - mu) * inv * gg.z + bb.z;
    o.w = (v.w - mu) * inv * gg.w + bb.w;
    xr[tid] = o;
    if (xb) {
        __hip_bfloat16* xo = xb + (size_t)row * D_ + tid * 4;
        xo[0] = __float2bfloat16(o.x);
        xo[1] = __float2bfloat16(o.y);
        xo[2] = __float2bfloat16(o.z);
        xo[3] = __float2bfloat16(o.w);
    }
}

__global__ __launch_bounds__(256) void add_ln2_kernel(
    float* __restrict__ x, const __hip_bfloat16* __restrict__ p, int SK, size_t pstride,
    const float* __restrict__ pbias, const float* __restrict__ cav,
    const float* __restrict__ g1, const float* __restrict__ b1,
    const float* __restrict__ g2, const float* __restrict__ b2,
    __hip_bfloat16* __restrict__ xb)
{
    const int row = blockIdx.x;
    const int tid = threadIdx.x;
    __shared__ float ws[4], ws2[4], mu_s, inv_s;
    float4* xr = reinterpret_cast<float4*>(x + (size_t)row * D_);
    float4 v = xr[tid];
    for (int s = 0; s < SK; ++s) {
        const float4 wv = ld_bf4(p + (size_t)s * pstride + (size_t)row * D_ + tid * 4);
        v.x += wv.x; v.y += wv.y; v.z += wv.z; v.w += wv.w;
    }
    if (pbias) {
        const float4 bv = reinterpret_cast<const float4*>(pbias)[tid];
        v.x += bv.x; v.y += bv.y; v.z += bv.z; v.w += bv.w;
    }
    float mu, inv;
    block_ln_stats(v, mu, inv, ws, ws2, &mu_s, &inv_s);
    const float4 g1v = reinterpret_cast<const float4*>(g1)[tid];
    const float4 b1v = reinterpret_cast<const float4*>(b1)[tid];
    const float4 cv  = reinterpret_cast<const float4*>(cav)[tid];
    float4 u;
    u.x = (v.x - mu) * inv * g1v.x + b1v.x + cv.x;
    u.y = (v.y - mu) * inv * g1v.y + b1v.y + cv.y;
    u.z = (v.z - mu) * inv * g1v.z + b1v.z + cv.z;
    u.w = (v.w - mu) * inv * g1v.w + b1v.w + cv.w;
    __syncthreads();
    float mu2, inv2;
    block_ln_stats(u, mu2, inv2, ws, ws2, &mu_s, &inv_s);
    const float4 g2v = reinterpret_cast<const float4*>(g2)[tid];
    const float4 b2v = reinterpret_cast<const float4*>(b2)[tid];
    float4 o;
    o.x = (u.x - mu2) * inv2 * g2v.x + b2v.x;
    o.y = (u.y - mu2) * inv2 * g2v.y + b2v.y;
    o.z = (u.z - mu2) * inv2 * g2v.z + b2v.z;
    o.w = (u.w - mu2) * inv2 * g2v.w + b2v.w;
    xr[tid] = o;
    __hip_bfloat16* xo = xb + (size_t)row * D_ + tid * 4;
    xo[0] = __float2bfloat16(o.x);
    xo[1] = __float2bfloat16(o.y);
    xo[2] = __float2bfloat16(o.z);
    xo[3] = __float2bfloat16(o.w);
}

__global__ __launch_bounds__(256) void interleave_pe_kernel(
    const float* __restrict__ obs_tok, const float* __restrict__ act_tok,
    float* __restrict__ x, __hip_bfloat16* __restrict__ xb)
{
    const int row = blockIdx.x;
    const int b = row / T_;
    const int t = row - b * T_;
    const float* src = (t & 1)
        ? (act_tok + (size_t)(b * (S_ - 1) + (t >> 1)) * D_)
        : (obs_tok + (size_t)(b * S_ + (t >> 1)) * D_);
    float* xr = x + (size_t)row * D_;
    __hip_bfloat16* xo = xb + (size_t)row * D_;
    #pragma unroll
    for (int k = 0; k < 4; ++k) {
        int d = threadIdx.x + k * 256;
        float ang = (float)b * expf(-(float)(d & ~1) * (9.210340371976184f / 1024.0f));
        float pe = (d & 1) ? cosf(ang) : sinf(ang);
        float v = src[d] + pe;
        xr[d] = v;
        xo[d] = __float2bfloat16(v);
    }
}

__global__ __launch_bounds__(256) void ca_part_kernel(
    const float* __restrict__ ca_b_in, const float* __restrict__ ca_w_out,
    float* __restrict__ part)
{
    const int idx = blockIdx.x * 256 + threadIdx.x;
    const int ks = blockIdx.y;
    const int l = idx >> 10, d = idx & 1023;
    const float* bv = ca_b_in + (size_t)l * 3 * D_ + 2 * D_ + ks * 64;
    const float* wp = ca_w_out + (size_t)l * D_ * D_ + (size_t)(ks * 64) * D_ + d;
    float s = 0.f;
    #pragma unroll 8
    for (int k = 0; k < 64; ++k) s = fmaf(bv[k], wp[(size_t)k * D_], s);
    part[(size_t)ks * (L_ * D_) + idx] = s;
}

__global__ __launch_bounds__(256) void ca_reduce_kernel(
    const float* __restrict__ part, const float* __restrict__ ca_b_out,
    float* __restrict__ out)
{
    const int idx = blockIdx.x * 256 + threadIdx.x;
    float s = ca_b_out[idx];
    #pragma unroll
    for (int ks = 0; ks < 16; ++ks) s += part[(size_t)ks * (L_ * D_) + idx];
    out[idx] = s;
}

// ---------------------------------------------------------------------------
extern "C" void kernel_launch(void* const* d_in, const int* in_sizes, int n_in,
                              void* d_out, int out_size, void* d_ws, size_t ws_size,
                              hipStream_t stream)
{
    const float* obs     = (const float*)d_in[0];
    const float* act     = (const float*)d_in[1];
    const float* in_w1   = (const float*)d_in[2];
    const float* in_b1   = (const float*)d_in[3];
    const float* in_w2   = (const float*)d_in[4];
    const float* in_b2   = (const float*)d_in[5];
    const float* in_w3   = (const float*)d_in[6];
    const float* in_b3   = (const float*)d_in[7];
    const float* act_w1  = (const float*)d_in[8];
    const float* act_b1  = (const float*)d_in[9];
    const float* act_w2  = (const float*)d_in[10];
    const float* act_b2  = (const float*)d_in[11];
    const float* act_w3  = (const float*)d_in[12];
    const float* act_b3  = (const float*)d_in[13];
    const float* out_w1  = (const float*)d_in[14];
    const float* out_b1  = (const float*)d_in[15];
    const float* out_w2  = (const float*)d_in[16];
    const float* out_b2  = (const float*)d_in[17];
    const float* out_w3  = (const float*)d_in[18];
    const float* out_b3  = (const float*)d_in[19];
    const float* sa_w_in = (const float*)d_in[20];
    const float* sa_b_in = (const float*)d_in[21];
    const float* sa_w_out= (const float*)d_in[22];
    const float* sa_b_out= (const float*)d_in[23];
    const float* ca_b_in = (const float*)d_in[25];
    const float* ca_w_out= (const float*)d_in[26];
    const float* ca_b_out= (const float*)d_in[27];
    const float* ff_w1   = (const float*)d_in[28];
    const float* ff_b1   = (const float*)d_in[29];
    const float* ff_w2   = (const float*)d_in[30];
    const float* ff_b2   = (const float*)d_in[31];
    const float* ln1_g   = (const float*)d_in[32];
    const float* ln1_b   = (const float*)d_in[33];
    const float* ln2_g   = (const float*)d_in[34];
    const float* ln2_b   = (const float*)d_in[35];
    const float* ln3_g   = (const float*)d_in[36];
    const float* ln3_b   = (const float*)d_in[37];
    const float* lnf_g   = (const float*)d_in[38];
    const float* lnf_b   = (const float*)d_in[39];

    const int MT = B_ * T_;          // 4092
    const int Mo = B_ * S_;          // 2048
    const int Ma = B_ * (S_ - 1);    // 2044

    char* base = (char*)d_ws;
    size_t used = 0;
    auto alloc = [&](size_t bytes) -> char* {
        char* r = base + used;
        used += (bytes + 255) & ~(size_t)255;
        return r;
    };
    typedef __hip_bfloat16 bf;
    bf* wi1  = (bf*)alloc((size_t)1024 * 64 * 2);
    bf* wi2  = (bf*)alloc((size_t)1024 * 1024 * 2);
    bf* wi3  = (bf*)alloc((size_t)1024 * 1024 * 2);
    bf* wa1  = (bf*)alloc((size_t)1024 * 32 * 2);
    bf* wa2  = (bf*)alloc((size_t)1024 * 1024 * 2);
    bf* wa3  = (bf*)alloc((size_t)1024 * 1024 * 2);
    bf* wo1  = (bf*)alloc((size_t)1024 * 1024 * 2);
    bf* wo2  = (bf*)alloc((size_t)1024 * 1024 * 2);
    bf* wo3  = (bf*)alloc((size_t)16 * 1024 * 2);
    bf* wsin = (bf*)alloc((size_t)L_ * 3072 * 1024 * 2);
    bf* wsout= (bf*)alloc((size_t)L_ * 1024 * 1024 * 2);
    bf* wf1  = (bf*)alloc((size_t)L_ * 4096 * 1024 * 2);
    bf* wf2  = (bf*)alloc((size_t)L_ * 1024 * 4096 * 2);
    bf* obs_bf = (bf*)alloc((size_t)Mo * 64 * 2);
    bf* act_bf = (bf*)alloc((size_t)Ma * 32 * 2);
    bf* x_bf   = (bf*)alloc((size_t)MT * D_ * 2);
    bf* attnb  = (bf*)alloc((size_t)MT * D_ * 2);
    bf* h1b    = (bf*)alloc((size_t)MT * D_ * 2);   // obs rows [0,Mo) | act rows [Mo,MT)
    bf* h2b    = (bf*)alloc((size_t)MT * D_ * 2);
    char* shared_rg = alloc((size_t)MT * F_ * 2);   // qkvb | ffh | partials
    bf* qkvb = (bf*)shared_rg;
    bf* ffh  = (bf*)shared_rg;
    bf* vt   = (bf*)alloc((size_t)B_ * 1024 * 1024 * 2);
    float* x       = (float*)alloc((size_t)MT * D_ * 4);
    float* y       = (float*)alloc((size_t)MT * D_ * 4);
    float* obs_tok = (float*)alloc((size_t)Mo * D_ * 4);
    float* act_tok = (float*)alloc((size_t)Ma * D_ * 4);
    float* ca      = (float*)alloc((size_t)L_ * D_ * 4);
    float* ca_part = (float*)alloc((size_t)16 * L_ * D_ * 4);
    if (used > ws_size) return;
    // bf16 partial regions (halved): 2 slices x MT*D*2 = 16.7MB fits in y alone
    bf* part_loop = (bf*)y;
    bf* part_pre  = (bf*)shared_rg;   // 4 slices x Mo*D*2 = 16.7MB
    bf* part_post = (bf*)shared_rg;   // wo1/wo2: 2 x MT*D*2; wo3: 8 x MT*16*2

    auto tw = [&](const float* W, bf* Wt, int K, int N, int Kpad, int batch) {
        dim3 g((N + 31) / 32, (Kpad + 31) / 32, batch);
        transpose_w<<<g, 256, 0, stream>>>(W, Wt, K, N, Kpad);
    };
    auto gemm = [&](const bf* A, const bf* Wt, const float* bias,
                    float* Cf, bf* Cb, int M, int K, int N, int relu, int sk) {
        dim3 g((N + 63) / 64, (M + 127) / 128, sk);
        gemm_bf16<<<g, 256, 0, stream>>>(A, Wt, bias, Cf, Cb, M, K, N, relu, sk);
    };
    auto gemm_red = [&](const bf* A, const bf* Wt, const float* bias,
                        float* Cf, bf* Cb, int M, int K, int N, int relu, int sk,
                        bf* part) {
        if (sk <= 1) { gemm(A, Wt, bias, Cf, Cb, M, K, N, relu, 1); return; }
        gemm(A, Wt, nullptr, nullptr, part, M, K, N, 0, sk);
        const size_t MN = (size_t)M * N;
        const int total4 = (int)(MN / 4);
        reduce_split<<<(total4 + 255) / 256, 256, 0, stream>>>(
            part, sk, MN, bias, N, total4, relu, Cf, Cb);
    };

    // ---- weight transposes: ten 1024x1024 batched into ONE launch ----
    {
        TW10 p;
        p.src[0] = in_w2;  p.dst[0] = wi2;
        p.src[1] = in_w3;  p.dst[1] = wi3;
        p.src[2] = act_w2; p.dst[2] = wa2;
        p.src[3] = act_w3; p.dst[3] = wa3;
        p.src[4] = out_w1; p.dst[4] = wo1;
        p.src[5] = out_w2; p.dst[5] = wo2;
        for (int l = 0; l < L_; ++l) {
            p.src[6 + l] = sa_w_out + (size_t)l * 1024 * 1024;
            p.dst[6 + l] = wsout + (size_t)l * 1024 * 1024;
        }
        transpose_w_b<<<dim3(32, 32, 10), 256, 0, stream>>>(p);
    }
    tw(in_w1,  wi1, 64,   1024, 64,   1);
    tw(act_w1, wa1, 16,   1024, 32,   1);
    tw(out_w3, wo3, 1024, 16,   1024, 1);
    tw(sa_w_in, wsin, 1024, 3072, 1024, L_);
    tw(ff_w1,   wf1,  1024, 4096, 1024, L_);
    tw(ff_w2,   wf2,  4096, 1024, 4096, L_);

    convert_pad<<<(Mo * 64 + 255) / 256, 256, 0, stream>>>(obs, obs_bf, Mo, 64, 64);
    convert_pad<<<(Ma * 32 + 255) / 256, 256, 0, stream>>>(act, act_bf, Ma, 16, 32);
    ca_part_kernel<<<dim3((L_ * D_) / 256, 16), 256, 0, stream>>>(ca_b_in, ca_w_out, ca_part);
    ca_reduce_kernel<<<(L_ * D_) / 256, 256, 0, stream>>>(ca_part, ca_b_out, ca);

    // ---- input MLPs: pair-batched, bf16 partials ----
    const size_t MoD = (size_t)Mo * D_;
    gemm_pair<<<dim3(16, 16, 2), 256, 0, stream>>>(
        obs_bf, act_bf, wi1, wa1, in_b1, act_b1,
        h1b, h1b + MoD, nullptr, Mo, Ma, 64, 32, D_, 1, 1);
    gemm_pair<<<dim3(16, 16, 4), 256, 0, stream>>>(
        h1b, h1b + MoD, wi2, wa2, nullptr, nullptr,
        nullptr, nullptr, part_pre, Mo, Ma, D_, D_, D_, 0, 2);
    reduce_pair<<<dim3((int)(MoD / 4 + 255) / 256, 2), 256, 0, stream>>>(
        part_pre, MoD, 2, in_b2, act_b2, Mo, Ma, D_, 1,
        h2b, h2b + MoD, nullptr, nullptr);
    gemm_pair<<<dim3(16, 16, 4), 256, 0, stream>>>(
        h2b, h2b + MoD, wi3, wa3, nullptr, nullptr,
        nullptr, nullptr, part_pre, Mo, Ma, D_, D_, D_, 0, 2);
    reduce_pair<<<dim3((int)(MoD / 4 + 255) / 256, 2), 256, 0, stream>>>(
        part_pre, MoD, 2, in_b3, act_b3, Mo, Ma, D_, 0,
        nullptr, nullptr, obs_tok, act_tok);

    interleave_pe_kernel<<<MT, 256, 0, stream>>>(obs_tok, act_tok, x, x_bf);
    // obs_tok/act_tok/y now dead -> part_loop region live.

    // ---- decoder layers ----
    for (int l = 0; l < L_; ++l) {
        gemm(x_bf, wsin + (size_t)l * 3072 * 1024, sa_b_in + (size_t)l * 3 * D_,
             nullptr, qkvb, MT, D_, 3 * D_, 0, 1);                // 1536 blk
        v_transpose<<<dim3(32, 32, B_), 256, 0, stream>>>(qkvb, vt);
        attn_mfma<<<dim3(B_ * H_, 8), 256, 0, stream>>>(qkvb, vt, attnb);
        // proj SK=2 -> bf16 partials, consumed by fused double-LN
        gemm(attnb, wsout + (size_t)l * 1024 * 1024, nullptr,
             nullptr, part_loop, MT, D_, D_, 0, 2);
        add_ln2_kernel<<<MT, 256, 0, stream>>>(x, part_loop, 2, (size_t)MT * D_,
             sa_b_out + (size_t)l * D_, ca + (size_t)l * D_,
             ln1_g + (size_t)l * D_, ln1_b + (size_t)l * D_,
             ln2_g + (size_t)l * D_, ln2_b + (size_t)l * D_, x_bf);
        gemm(x_bf, wf1 + (size_t)l * 4096 * 1024, ff_b1 + (size_t)l * F_,
             nullptr, ffh, MT, D_, F_, 1, 1);                     // 2048 blk
        // FFN-down SK=2 -> bf16 partials, consumed by LN3
        gemm(ffh, wf2 + (size_t)l * 1024 * 4096, nullptr,
             nullptr, part_loop, MT, F_, D_, 0, 2);
        add_ln_kernel<<<MT, 256, 0, stream>>>(x, part_loop, 2, (size_t)MT * D_,
             ff_b2 + (size_t)l * D_,
             ln3_g + (size_t)l * D_, ln3_b + (size_t)l * D_, x_bf);
    }

    // ---- final norm + output MLP ----
    add_ln_kernel<<<MT, 256, 0, stream>>>(x, nullptr, 0, 0, nullptr, lnf_g, lnf_b, x_bf);
    gemm_red(x_bf, wo1, out_b1, nullptr, h1b, MT, D_, D_, 1, 2, part_post);
    gemm_red(h1b,  wo2, out_b2, nullptr, h2b, MT, D_, D_, 1, 2, part_post);
    gemm_red(h2b,  wo3, out_b3, (float*)d_out, nullptr, MT, D_, 16, 0, 8, part_post);
}